// Round 9
// baseline (361.370 us; speedup 1.0000x reference)
//
#include <hip/hip_runtime.h>
#include <hip/hip_bf16.h>

#define DIMX 1024
#define DSTATE 16
#define DCONV 4
#define DINNER 2048
#define DTRANK 64
#define BSZ 2
#define SEQL 1024
#define NROW (BSZ*SEQL)              // 2048
#define NPROJ (DTRANK + 2*DSTATE)    // 96
#define NCH2 64                      // scan chunks
#define CL2 16                       // chunk length (SEQL/NCH2)
#define G2SPLIT 16                   // GEMM2 split-K factor
#define G2KLEN (DINNER / G2SPLIT)    // 128
#define G4SPLIT 4                    // GEMM4 split-K factor

typedef __bf16 bf16x8 __attribute__((ext_vector_type(8)));
typedef float f32x4 __attribute__((ext_vector_type(4)));
typedef unsigned short ushort8_t __attribute__((ext_vector_type(8)));

#define LOG2E 1.44269504088896340736f

__device__ __forceinline__ float sigmoidf_(float x){ return 1.0f/(1.0f+__expf(-x)); }
__device__ __forceinline__ float fexp2(float x){ return __builtin_amdgcn_exp2f(x); }
__device__ __forceinline__ unsigned short f2bf(float f){
  union { float f; unsigned int i; } c; c.f = f;
  unsigned int r = (c.i + 0x7FFFu + ((c.i >> 16) & 1u)) >> 16;
  return (unsigned short)r;
}
__device__ __forceinline__ float bf2f(unsigned short u){
  union { unsigned int i; float f; } c; c.i = ((unsigned int)u) << 16; return c.f;
}

// async global->LDS, 16 B per lane; LDS dest = base + lane*16 (wave-uniform base)
__device__ __forceinline__ void gload16(const void* g, void* l){
  __builtin_amdgcn_global_load_lds(
      (const __attribute__((address_space(1))) unsigned int*)g,
      (__attribute__((address_space(3))) unsigned int*)l, 16, 0, 0);
}

// ---------------------------------------------------------------------------
// Transpose + cast: w (K x N, f32) -> wt (N x K, bf16). Grid (N/32, K/32).
// ---------------------------------------------------------------------------
__global__ __launch_bounds__(256) void transpose_cast_k(
    const float* __restrict__ w, unsigned short* __restrict__ wt, int K, int N)
{
  __shared__ unsigned short T[32][33];
  const int nT = blockIdx.x * 32, kT = blockIdx.y * 32;
  const int tx = threadIdx.x & 31, ty = threadIdx.x >> 5;
  #pragma unroll
  for (int i = 0; i < 4; i++) {
    const int k = kT + ty + i*8;
    T[tx][ty + i*8] = f2bf(w[(size_t)k * N + nT + tx]);
  }
  __syncthreads();
  #pragma unroll
  for (int i = 0; i < 4; i++) {
    const int n = nT + ty + i*8;
    wt[(size_t)n * K + kT + tx] = T[ty + i*8][tx];
  }
}

// ---------------------------------------------------------------------------
// Cast f32 -> bf16, vectorized.
// ---------------------------------------------------------------------------
__global__ __launch_bounds__(256) void cast_bf16_k(
    const float* __restrict__ in, unsigned short* __restrict__ outp, int n4)
{
  const int i = blockIdx.x * 256 + threadIdx.x;
  if (i >= n4) return;
  float4 v = *(const float4*)(in + (size_t)i * 4);
  ushort4 o;
  o.x = f2bf(v.x); o.y = f2bf(v.y); o.z = f2bf(v.z); o.w = f2bf(v.w);
  *(ushort4*)(outp + (size_t)i * 4) = o;
}

// ---------------------------------------------------------------------------
// m97-style bf16 MFMA GEMM: C = A(MxK bf16) @ BT^T (BT: NxK bf16).
// 128x128 tile, BK=32, 256 thr = 2x2 waves, 4x4 16x16x32 accs/wave.
// KCH>0: split-K via blockIdx.z. EPI: softplus(v+bias[col]). OUTBF: bf16 out.
// ---------------------------------------------------------------------------
template<int KCH, int EPI, int OUTBF>
__global__ __launch_bounds__(256) void gemm_bt_k(
    const unsigned short* __restrict__ A, int lda,
    const unsigned short* __restrict__ BT, int ldb,
    void* __restrict__ C0v, void* __restrict__ C1v, int splitN, int ldc,
    int M, int K, const float* __restrict__ bias)
{
  constexpr int BM = 128, BN = 128, BK = 32;
  __shared__ unsigned short As[BM*BK];
  __shared__ unsigned short Bs[BN*BK];

  const int tid = threadIdx.x;
  const int w = tid >> 6, lane = tid & 63;
  const int quad = lane >> 4, lrow = lane & 15;
  const int mOff = (w & 1) * 64, nOff = (w >> 1) * 64;
  const int rowTile = blockIdx.y * BM, colTile = blockIdx.x * BN;

  int kBeg = 0, kEnd = K;
  float* c0 = (float*)C0v; float* c1 = (float*)C1v;
  if constexpr (KCH > 0) {
    kBeg = blockIdx.z * KCH;
    kEnd = kBeg + KCH;
    c0 += (size_t)blockIdx.z * M * ldc;
    c1 += (size_t)blockIdx.z * M * ldc;
  }

  f32x4 acc[4][4] = {};

  const int srow = lane >> 2;
  const int sbyte = (lane & 3) * 16;
  unsigned short* aB0 = &As[(w*32     )*32];
  unsigned short* aB1 = &As[(w*32 + 16)*32];
  unsigned short* bB0 = &Bs[(w*32     )*32];
  unsigned short* bB1 = &Bs[(w*32 + 16)*32];

  for (int k0 = kBeg; k0 < kEnd; k0 += BK) {
    const char* aSrc = (const char*)(A  + (size_t)(rowTile + w*32 + srow)*lda + k0) + sbyte;
    const char* bSrc = (const char*)(BT + (size_t)(colTile + w*32 + srow)*ldb + k0) + sbyte;
    gload16(aSrc,                    aB0);
    gload16(aSrc + 16*(size_t)lda*2, aB1);
    gload16(bSrc,                    bB0);
    gload16(bSrc + 16*(size_t)ldb*2, bB1);
    __syncthreads();

    bf16x8 af[4], bfr[4];
    #pragma unroll
    for (int mi = 0; mi < 4; mi++)
      af[mi] = *(const bf16x8*)&As[(mOff + mi*16 + lrow)*32 + quad*8];
    #pragma unroll
    for (int ni = 0; ni < 4; ni++)
      bfr[ni] = *(const bf16x8*)&Bs[(nOff + ni*16 + lrow)*32 + quad*8];
    #pragma unroll
    for (int mi = 0; mi < 4; mi++)
      #pragma unroll
      for (int ni = 0; ni < 4; ni++)
        acc[mi][ni] = __builtin_amdgcn_mfma_f32_16x16x32_bf16(
            af[mi], bfr[ni], acc[mi][ni], 0, 0, 0);
    __syncthreads();
  }

  #pragma unroll
  for (int mi = 0; mi < 4; mi++) {
    #pragma unroll
    for (int ni = 0; ni < 4; ni++) {
      const int row = rowTile + mOff + mi*16 + quad*4;
      const int col = colTile + nOff + ni*16 + lrow;
      float* Cb = (col < splitN) ? c0 : c1;
      const int cc = (col < splitN) ? col : col - splitN;
      #pragma unroll
      for (int r = 0; r < 4; r++) {
        float v = acc[mi][ni][r];
        if constexpr (EPI) {
          v += bias[col];
          v = (v > 20.f) ? v : log1pf(__expf(v));
        }
        if constexpr (OUTBF)
          ((unsigned short*)C0v)[(size_t)(row + r) * ldc + cc] = f2bf(v);
        else
          Cb[(size_t)(row + r) * ldc + cc] = v;
      }
    }
  }
}

// ---------------------------------------------------------------------------
// Tiled f32 GEMM (GEMM2 split-K only).
// ---------------------------------------------------------------------------
template<int KCHUNK>
__global__ __launch_bounds__(256) void gemm_k(
    const float* __restrict__ Ap, int lda,
    const float* __restrict__ Bp, int ldb,
    float* __restrict__ Cp, int ldc,
    int M, int N, int K)
{
  __shared__ float As[16][64];
  __shared__ float Bs[16][64];
  const int tid = threadIdx.x;
  const int tx = tid & 15, ty = tid >> 4;
  const int rowTile = blockIdx.y * 64;
  const int colTile = blockIdx.x * 64;

  int kBeg = 0, kEnd = K;
  float* Cout = Cp;
  if constexpr (KCHUNK > 0) {
    kBeg = blockIdx.z * KCHUNK;
    kEnd = kBeg + KCHUNK;
    Cout += (size_t)blockIdx.z * M * ldc;
  }

  const int ar = tid >> 2;
  const int ak = (tid & 3) * 4;
  const int bk = tid >> 4;
  const int bn = (tid & 15) * 4;

  float acc[4][4] = {};

  for (int k0 = kBeg; k0 < kEnd; k0 += 16) {
    {
      const int r = rowTile + ar;
      float4 av = *(const float4*)(Ap + (size_t)r * lda + k0 + ak);
      As[ak+0][ar] = av.x; As[ak+1][ar] = av.y;
      As[ak+2][ar] = av.z; As[ak+3][ar] = av.w;
    }
    {
      const int kk = k0 + bk;
      const int c = colTile + bn;
      float4 bv;
      if (c + 3 < N) {
        bv = *(const float4*)(Bp + (size_t)kk * ldb + c);
      } else {
        bv.x = (c+0 < N) ? Bp[(size_t)kk*ldb + c+0] : 0.f;
        bv.y = (c+1 < N) ? Bp[(size_t)kk*ldb + c+1] : 0.f;
        bv.z = (c+2 < N) ? Bp[(size_t)kk*ldb + c+2] : 0.f;
        bv.w = (c+3 < N) ? Bp[(size_t)kk*ldb + c+3] : 0.f;
      }
      *(float4*)&Bs[bk][bn] = bv;
    }
    __syncthreads();
    #pragma unroll
    for (int kk = 0; kk < 16; kk++) {
      float4 a4 = *(const float4*)&As[kk][ty*4];
      float4 b4 = *(const float4*)&Bs[kk][tx*4];
      float a[4] = {a4.x, a4.y, a4.z, a4.w};
      float b[4] = {b4.x, b4.y, b4.z, b4.w};
      #pragma unroll
      for (int i = 0; i < 4; i++)
        #pragma unroll
        for (int j = 0; j < 4; j++)
          acc[i][j] += a[i] * b[j];
    }
    __syncthreads();
  }

  #pragma unroll
  for (int i = 0; i < 4; i++) {
    const int r = rowTile + ty*4 + i;
    #pragma unroll
    for (int j = 0; j < 4; j++) {
      const int c = colTile + tx*4 + j;
      if (c >= N) continue;
      Cout[(size_t)r*ldc + c] = acc[i][j];
    }
  }
}

// ---------------------------------------------------------------------------
// GEMM2 reduce: sum 16 partial slices -> xdbl f32; also emit dtr cols as bf16.
// ---------------------------------------------------------------------------
__global__ __launch_bounds__(256) void reduce_g2_k(
    const float* __restrict__ part, float* __restrict__ outp,
    unsigned short* __restrict__ dtr16)
{
  const int n4 = NROW*NPROJ/4;
  const int i = blockIdx.x * 256 + threadIdx.x;
  if (i >= n4) return;
  float4 s = *(const float4*)(part + (size_t)i * 4);
  #pragma unroll
  for (int z = 1; z < G2SPLIT; z++) {
    float4 v = *(const float4*)(part + (size_t)z * n4 * 4 + (size_t)i * 4);
    s.x += v.x; s.y += v.y; s.z += v.z; s.w += v.w;
  }
  *(float4*)(outp + (size_t)i * 4) = s;
  const int col = (i*4) % NPROJ, row = (i*4) / NPROJ;
  if (col < DTRANK) {
    ushort4 o;
    o.x = f2bf(s.x); o.y = f2bf(s.y); o.z = f2bf(s.z); o.w = f2bf(s.w);
    *(ushort4*)(dtr16 + (size_t)row * DTRANK + col) = o;
  }
}

// ---------------------------------------------------------------------------
// GEMM4 reduce: sum 4 partial slices -> out f32.
// ---------------------------------------------------------------------------
__global__ __launch_bounds__(256) void reduce_g4_k(
    const float* __restrict__ part, float* __restrict__ outp, int n4)
{
  const int i = blockIdx.x * 256 + threadIdx.x;
  if (i >= n4) return;
  float4 s = *(const float4*)(part + (size_t)i * 4);
  #pragma unroll
  for (int z = 1; z < G4SPLIT; z++) {
    float4 v = *(const float4*)(part + (size_t)z * n4 * 4 + (size_t)i * 4);
    s.x += v.x; s.y += v.y; s.z += v.z; s.w += v.w;
  }
  *(float4*)(outp + (size_t)i * 4) = s;
}

// ---------------------------------------------------------------------------
// Causal depthwise conv (width 4) + SiLU.
// ---------------------------------------------------------------------------
__global__ __launch_bounds__(256) void conv_silu_k(
    const float* __restrict__ xc,
    const float* __restrict__ conv_w,
    const float* __restrict__ conv_b,
    float* __restrict__ u)
{
  const int idx = blockIdx.x * 256 + threadIdx.x;
  if (idx >= NROW * DINNER) return;
  const int d = idx & (DINNER - 1);
  const int row = idx >> 11;
  const int l = row & (SEQL - 1);
  float acc = conv_b[d];
  #pragma unroll
  for (int k = 0; k < DCONV; k++) {
    const int ls = l + k - (DCONV - 1);
    if (ls >= 0)
      acc += xc[(size_t)(row + k - (DCONV - 1)) * DINNER + d] * conv_w[d*DCONV + k];
  }
  u[idx] = acc * sigmoidf_(acc);
}

// ---------------------------------------------------------------------------
// Chunked parallel scan — register-state layout: one lane owns one channel d,
// h[0..15] in VGPRs; B/C wave-uniform broadcast from LDS; no cross-lane ops.
// NCH2=64 chunks of CL2=16. Grid = BSZ*NCH2*(DINNER/256) = 1024 blocks.
// scan_a: unseeded chunk -> S (end state, 16 f32/lane) + sumd.
// scan_b: 64-step serial combine per (b,d,n) -> H chunk-start seeds.
// scan_c: seeded re-run + y = sum_n h*C + fused epilogue -> bf16 y.
// ---------------------------------------------------------------------------
__global__ __launch_bounds__(256) void scan_a(
    const unsigned short* __restrict__ delta16,
    const float* __restrict__ u,
    const float* __restrict__ xdbl,
    const float* __restrict__ A_log,
    float* __restrict__ S, float* __restrict__ sumd_g)
{
  const int bx = blockIdx.x;
  const int c  = bx & (NCH2-1);
  const int dg = (bx >> 6) & 7;
  const int b  = bx >> 9;
  const int dBase = dg * 256;
  const int tid = threadIdx.x;
  const int d = dBase + tid;

  __shared__ float dlt_s[CL2][256];
  __shared__ float du_s[CL2][256];
  __shared__ float bc_s[CL2][32];

  float A2[16];
  #pragma unroll
  for (int i = 0; i < 4; i++) {
    float4 al = *(const float4*)&A_log[(size_t)d*DSTATE + i*4];
    A2[i*4+0] = -__expf(al.x)*LOG2E;
    A2[i*4+1] = -__expf(al.y)*LOG2E;
    A2[i*4+2] = -__expf(al.z)*LOG2E;
    A2[i*4+3] = -__expf(al.w)*LOG2E;
  }

  const int r0 = tid >> 6;          // 0..3
  const int cj = (tid & 63) * 4;    // 0..252
  #pragma unroll
  for (int i = 0; i < 4; i++) {
    const int t = r0 + i*4;
    const size_t rowG = (size_t)(b*SEQL + c*CL2 + t);
    ushort4 dv = *(const ushort4*)&delta16[rowG*DINNER + dBase + cj];
    float4  uv = *(const float4*)&u[rowG*DINNER + dBase + cj];
    const float d0=bf2f(dv.x), d1=bf2f(dv.y), d2=bf2f(dv.z), d3=bf2f(dv.w);
    dlt_s[t][cj+0]=d0; dlt_s[t][cj+1]=d1; dlt_s[t][cj+2]=d2; dlt_s[t][cj+3]=d3;
    du_s[t][cj+0]=d0*uv.x; du_s[t][cj+1]=d1*uv.y;
    du_s[t][cj+2]=d2*uv.z; du_s[t][cj+3]=d3*uv.w;
  }
  if (tid < 128) {
    const int t = tid >> 3;
    const int cc = (tid & 7) * 4;
    const size_t rowG = (size_t)(b*SEQL + c*CL2 + t);
    *(float4*)&bc_s[t][cc] = *(const float4*)&xdbl[rowG*NPROJ + DTRANK + cc];
  }
  __syncthreads();

  float h[16];
  #pragma unroll
  for (int n = 0; n < 16; n++) h[n] = 0.f;
  float sd = 0.f;

  for (int t = 0; t < CL2; t++) {
    const float dlt = dlt_s[t][tid];
    const float du  = du_s[t][tid];
    sd += dlt;
    f32x4 bq[4];
    #pragma unroll
    for (int i = 0; i < 4; i++) bq[i] = *(const f32x4*)&bc_s[t][i*4];
    #pragma unroll
    for (int n = 0; n < 16; n++) {
      const float a = fexp2(dlt * A2[n]);
      h[n] = a * h[n] + du * bq[n>>2][n&3];
    }
  }

  const size_t base = ((size_t)(b*NCH2 + c) * DINNER + d) * DSTATE;
  #pragma unroll
  for (int i = 0; i < 4; i++) {
    f32x4 hv; hv[0]=h[i*4+0]; hv[1]=h[i*4+1]; hv[2]=h[i*4+2]; hv[3]=h[i*4+3];
    *(f32x4*)&S[base + i*4] = hv;
  }
  sumd_g[(size_t)(b*NCH2 + c) * DINNER + d] = sd;
}

__global__ __launch_bounds__(256) void scan_b(
    const float* __restrict__ S, const float* __restrict__ sumd_g,
    const float* __restrict__ A_log, float* __restrict__ H)
{
  const int idx = blockIdx.x * 256 + threadIdx.x;   // (b,d,n): 65536
  const int n = idx & 15, d = (idx >> 4) & (DINNER-1), b = idx >> 15;
  const float A2 = -__expf(A_log[(size_t)d*DSTATE + n]) * LOG2E;
  float h = 0.f;
  for (int c = 0; c < NCH2; c++) {
    const size_t pos = ((size_t)(b*NCH2 + c) * DINNER + d) * DSTATE + n;
    const float sd = sumd_g[(size_t)(b*NCH2 + c) * DINNER + d];
    H[pos] = h;
    h = fexp2(A2 * sd) * h + S[pos];
  }
}

__global__ __launch_bounds__(256) void scan_c(
    const unsigned short* __restrict__ delta16,
    const float* __restrict__ u,
    const float* __restrict__ Z,
    const float* __restrict__ xdbl,
    const float* __restrict__ A_log,
    const float* __restrict__ Dp,
    const float* __restrict__ H,
    unsigned short* __restrict__ Y)
{
  const int bx = blockIdx.x;
  const int c  = bx & (NCH2-1);
  const int dg = (bx >> 6) & 7;
  const int b  = bx >> 9;
  const int dBase = dg * 256;
  const int tid = threadIdx.x;
  const int d = dBase + tid;

  __shared__ float dlt_s[CL2][256];
  __shared__ float du_s[CL2][256];
  __shared__ float bc_s[CL2][32];

  float A2[16];
  #pragma unroll
  for (int i = 0; i < 4; i++) {
    float4 al = *(const float4*)&A_log[(size_t)d*DSTATE + i*4];
    A2[i*4+0] = -__expf(al.x)*LOG2E;
    A2[i*4+1] = -__expf(al.y)*LOG2E;
    A2[i*4+2] = -__expf(al.z)*LOG2E;
    A2[i*4+3] = -__expf(al.w)*LOG2E;
  }
  const float Dval = Dp[d];

  const int r0 = tid >> 6;
  const int cj = (tid & 63) * 4;
  #pragma unroll
  for (int i = 0; i < 4; i++) {
    const int t = r0 + i*4;
    const size_t rowG = (size_t)(b*SEQL + c*CL2 + t);
    ushort4 dv = *(const ushort4*)&delta16[rowG*DINNER + dBase + cj];
    float4  uv = *(const float4*)&u[rowG*DINNER + dBase + cj];
    const float d0=bf2f(dv.x), d1=bf2f(dv.y), d2=bf2f(dv.z), d3=bf2f(dv.w);
    dlt_s[t][cj+0]=d0; dlt_s[t][cj+1]=d1; dlt_s[t][cj+2]=d2; dlt_s[t][cj+3]=d3;
    du_s[t][cj+0]=d0*uv.x; du_s[t][cj+1]=d1*uv.y;
    du_s[t][cj+2]=d2*uv.z; du_s[t][cj+3]=d3*uv.w;
  }
  if (tid < 128) {
    const int t = tid >> 3;
    const int cc = (tid & 7) * 4;
    const size_t rowG = (size_t)(b*SEQL + c*CL2 + t);
    *(float4*)&bc_s[t][cc] = *(const float4*)&xdbl[rowG*NPROJ + DTRANK + cc];
  }

  // seed from H during staging window
  float h[16];
  {
    const size_t hb = ((size_t)(b*NCH2 + c) * DINNER + d) * DSTATE;
    #pragma unroll
    for (int i = 0; i < 4; i++) {
      f32x4 hv = *(const f32x4*)&H[hb + i*4];
      h[i*4+0]=hv[0]; h[i*4+1]=hv[1]; h[i*4+2]=hv[2]; h[i*4+3]=hv[3];
    }
  }
  __syncthreads();

  for (int t = 0; t < CL2; t++) {
    const float dlt = dlt_s[t][tid];
    const float du  = du_s[t][tid];
    f32x4 bq[4], cq[4];
    #pragma unroll
    for (int i = 0; i < 4; i++) {
      bq[i] = *(const f32x4*)&bc_s[t][i*4];
      cq[i] = *(const f32x4*)&bc_s[t][16 + i*4];
    }
    float y = 0.f;
    #pragma unroll
    for (int n = 0; n < 16; n++) {
      const float a = fexp2(dlt * A2[n]);
      h[n] = a * h[n] + du * bq[n>>2][n&3];
      y += h[n] * cq[n>>2][n&3];
    }
    const size_t rowG = (size_t)(b*SEQL + c*CL2 + t);
    const float uu = u[rowG*DINNER + d];
    const float zz = Z[rowG*DINNER + d];
    const float yy = (y + uu*Dval) * (zz * sigmoidf_(zz));
    Y[rowG*DINNER + d] = f2bf(yy);
  }
}

// ---------------------------------------------------------------------------
extern "C" void kernel_launch(void* const* d_in, const int* in_sizes, int n_in,
                              void* d_out, int out_size, void* d_ws, size_t ws_size,
                              hipStream_t stream) {
  const float* x         = (const float*)d_in[0];
  const float* in_proj_w = (const float*)d_in[2];
  const float* conv_w    = (const float*)d_in[3];
  const float* conv_b    = (const float*)d_in[4];
  const float* x_proj_w  = (const float*)d_in[5];
  const float* dt_proj_w = (const float*)d_in[6];
  const float* dt_proj_b = (const float*)d_in[7];
  const float* A_log     = (const float*)d_in[8];
  const float* Dp        = (const float*)d_in[9];
  const float* out_proj_w= (const float*)d_in[10];
  float* out = (float*)d_out;

  // ws: 256 MiB (harness fill evidence, R8). Proven low region unchanged:
  //  XC 16.78MB: xc f32 (GEMM1) -> conv reads -> g2part[0,12.58M) +
  //     dtwt/dtr16 tail -> yb bf16 [0,8.39M) (scan_c out, GEMM4 A)
  //  Z  16.78MB: z (GEMM1) -> scan_c reads -> GEMM4 partials 0-1
  //  u  16.78MB: xb bf16 (pre-GEMM1) -> u f32 (conv) -> GEMM4 partials 2-3
  //  xdbl 0.79MB
  //  W  16.78MB: [0,8.39M) w1t / delta16; [12.58,16.78M) w4t
  // New scan scratch in fresh high ws (no aliasing):
  //  S2 @ +72MiB (16.78MB) | H2 @ +96MiB (16.78MB) | sumd @ +120MiB (1.05MB)
  float* XC   = (float*)d_ws;
  float* Z    = XC + (size_t)NROW * DINNER;
  float* u    = Z  + (size_t)NROW * DINNER;
  float* xdbl = u  + (size_t)NROW * DINNER;
  char*  W    = (char*)(xdbl + (size_t)NROW * NPROJ);
  unsigned short* w1t     = (unsigned short*)W;
  unsigned short* delta16 = (unsigned short*)W;
  unsigned short* w4t     = (unsigned short*)(W + 12582912);
  unsigned short* xb      = (unsigned short*)u;     // bf16 x, dead before conv
  unsigned short* yb      = (unsigned short*)XC;    // bf16 y (scan_c out)
  float* g2part = XC;                               // [0, 12.58M)
  unsigned short* dtwt  = (unsigned short*)((char*)XC + 12582912);  // 256KB
  unsigned short* dtr16 = (unsigned short*)((char*)XC + 12582912 + 262144);
  float* g4part = Z;                                // 4 slices across Z+u
  float* S2   = (float*)((char*)d_ws + 75497472);   // +72 MiB
  float* H2   = (float*)((char*)d_ws + 100663296);  // +96 MiB
  float* sumd = (float*)((char*)d_ws + 125829120);  // +120 MiB

  dim3 blk(256);

  // pre-casts
  cast_bf16_k<<<dim3((NROW*DIMX/4)/256), blk, 0, stream>>>(x, xb, NROW*DIMX/4);
  transpose_cast_k<<<dim3((2*DINNER)/32, DIMX/32), blk, 0, stream>>>(
      in_proj_w, w1t, DIMX, 2*DINNER);
  transpose_cast_k<<<dim3(DIMX/32, DINNER/32), blk, 0, stream>>>(
      out_proj_w, w4t, DINNER, DIMX);

  // GEMM1 (MFMA): [xc|z] = x @ in_proj_w
  gemm_bt_k<0,0,0><<<dim3((2*DINNER)/128, NROW/128), blk, 0, stream>>>(
      xb, DIMX, w1t, DIMX, XC, Z, DINNER, DINNER, NROW, DIMX, nullptr);

  conv_silu_k<<<(NROW*DINNER)/256, blk, 0, stream>>>(XC, conv_w, conv_b, u);

  // dt_proj_w transpose (XC tail free after conv)
  transpose_cast_k<<<dim3(DINNER/32, DTRANK/32), blk, 0, stream>>>(
      dt_proj_w, dtwt, DTRANK, DINNER);

  // GEMM2 (f32, split-K 16) -> xdbl (+ dtr16 bf16 in reduce)
  gemm_k<G2KLEN><<<dim3((NPROJ+63)/64, NROW/64, G2SPLIT), blk, 0, stream>>>(
      u, DINNER, x_proj_w, NPROJ, g2part, NPROJ, NROW, NPROJ, DINNER);
  reduce_g2_k<<<dim3((NROW*NPROJ/4 + 255)/256), blk, 0, stream>>>(
      g2part, xdbl, dtr16);

  // GEMM3 (MFMA, K=64): delta16 = softplus(dtr16 @ dtwt^T + dt_proj_b), bf16
  gemm_bt_k<0,1,1><<<dim3(DINNER/128, NROW/128), blk, 0, stream>>>(
      dtr16, DTRANK, dtwt, DTRANK, delta16, delta16, 1<<30, DINNER,
      NROW, DTRANK, dt_proj_b);

  // chunked selective scan (register-state layout)
  scan_a<<<dim3(BSZ*NCH2*8), blk, 0, stream>>>(delta16, u, xdbl, A_log, S2, sumd);
  scan_b<<<dim3((BSZ*DINNER*DSTATE)/256), blk, 0, stream>>>(S2, sumd, A_log, H2);
  scan_c<<<dim3(BSZ*NCH2*8), blk, 0, stream>>>(
      delta16, u, Z, xdbl, A_log, Dp, H2, yb);

  // GEMM4 (MFMA, split-K 4): out = y @ out_proj_w
  gemm_bt_k<DINNER/G4SPLIT,0,0><<<dim3(DIMX/128, NROW/128, G4SPLIT), blk, 0, stream>>>(
      yb, DINNER, w4t, DINNER, g4part, g4part, 1<<30, DIMX, NROW, DINNER, nullptr);
  reduce_g4_k<<<dim3((NROW*DIMX/4 + 255)/256), blk, 0, stream>>>(
      g4part, out, NROW*DIMX/4);
}

// Round 10
// 281.046 us; speedup vs baseline: 1.2858x; 1.2858x over previous
//
#include <hip/hip_runtime.h>
#include <hip/hip_bf16.h>

#define DIMX 1024
#define DSTATE 16
#define DCONV 4
#define DINNER 2048
#define DTRANK 64
#define BSZ 2
#define SEQL 1024
#define NROW (BSZ*SEQL)              // 2048
#define NPROJ (DTRANK + 2*DSTATE)    // 96
#define NCH2 64                      // scan chunks
#define CL2 16                       // chunk length (SEQL/NCH2)
#define G2SPLIT 16                   // GEMM2 split-K factor
#define G2KLEN (DINNER / G2SPLIT)    // 128
#define G4SPLIT 4                    // GEMM4 split-K factor

typedef __bf16 bf16x8 __attribute__((ext_vector_type(8)));
typedef float f32x4 __attribute__((ext_vector_type(4)));
typedef unsigned short ushort8_t __attribute__((ext_vector_type(8)));

#define LOG2E 1.44269504088896340736f

__device__ __forceinline__ float sigmoidf_(float x){ return 1.0f/(1.0f+__expf(-x)); }
__device__ __forceinline__ float fexp2(float x){ return __builtin_amdgcn_exp2f(x); }
__device__ __forceinline__ unsigned short f2bf(float f){
  union { float f; unsigned int i; } c; c.f = f;
  unsigned int r = (c.i + 0x7FFFu + ((c.i >> 16) & 1u)) >> 16;
  return (unsigned short)r;
}
__device__ __forceinline__ float bf2f(unsigned short u){
  union { unsigned int i; float f; } c; c.i = ((unsigned int)u) << 16; return c.f;
}

// async global->LDS, 16 B per lane; LDS dest = base + lane*16 (wave-uniform base)
__device__ __forceinline__ void gload16(const void* g, void* l){
  __builtin_amdgcn_global_load_lds(
      (const __attribute__((address_space(1))) unsigned int*)g,
      (__attribute__((address_space(3))) unsigned int*)l, 16, 0, 0);
}

// ---------------------------------------------------------------------------
// Transpose + cast: w (K x N, f32) -> wt (N x K, bf16). Grid (N/32, K/32).
// ---------------------------------------------------------------------------
__global__ __launch_bounds__(256) void transpose_cast_k(
    const float* __restrict__ w, unsigned short* __restrict__ wt, int K, int N)
{
  __shared__ unsigned short T[32][33];
  const int nT = blockIdx.x * 32, kT = blockIdx.y * 32;
  const int tx = threadIdx.x & 31, ty = threadIdx.x >> 5;
  #pragma unroll
  for (int i = 0; i < 4; i++) {
    const int k = kT + ty + i*8;
    T[tx][ty + i*8] = f2bf(w[(size_t)k * N + nT + tx]);
  }
  __syncthreads();
  #pragma unroll
  for (int i = 0; i < 4; i++) {
    const int n = nT + ty + i*8;
    wt[(size_t)n * K + kT + tx] = T[ty + i*8][tx];
  }
}

// ---------------------------------------------------------------------------
// Cast f32 -> bf16, vectorized.
// ---------------------------------------------------------------------------
__global__ __launch_bounds__(256) void cast_bf16_k(
    const float* __restrict__ in, unsigned short* __restrict__ outp, int n4)
{
  const int i = blockIdx.x * 256 + threadIdx.x;
  if (i >= n4) return;
  float4 v = *(const float4*)(in + (size_t)i * 4);
  ushort4 o;
  o.x = f2bf(v.x); o.y = f2bf(v.y); o.z = f2bf(v.z); o.w = f2bf(v.w);
  *(ushort4*)(outp + (size_t)i * 4) = o;
}

// ---------------------------------------------------------------------------
// m97-style bf16 MFMA GEMM (GEMM1, GEMM4 only): C = A(MxK bf16) @ BT^T.
// 128x128 tile, BK=32, 256 thr = 2x2 waves, 4x4 16x16x32 accs/wave.
// KCH>0: split-K via blockIdx.z. C-write splits at col splitN -> C0/C1.
// ---------------------------------------------------------------------------
template<int KCH>
__global__ __launch_bounds__(256) void gemm_bt_k(
    const unsigned short* __restrict__ A, int lda,
    const unsigned short* __restrict__ BT, int ldb,
    float* __restrict__ C0, float* __restrict__ C1, int splitN, int ldc,
    int M, int K)
{
  constexpr int BM = 128, BN = 128, BK = 32;
  __shared__ unsigned short As[BM*BK];
  __shared__ unsigned short Bs[BN*BK];

  const int tid = threadIdx.x;
  const int w = tid >> 6, lane = tid & 63;
  const int quad = lane >> 4, lrow = lane & 15;
  const int mOff = (w & 1) * 64, nOff = (w >> 1) * 64;
  const int rowTile = blockIdx.y * BM, colTile = blockIdx.x * BN;

  int kBeg = 0, kEnd = K;
  float* c0 = C0; float* c1 = C1;
  if constexpr (KCH > 0) {
    kBeg = blockIdx.z * KCH;
    kEnd = kBeg + KCH;
    c0 += (size_t)blockIdx.z * M * ldc;
    c1 += (size_t)blockIdx.z * M * ldc;
  }

  f32x4 acc[4][4] = {};

  const int srow = lane >> 2;
  const int sbyte = (lane & 3) * 16;
  unsigned short* aB0 = &As[(w*32     )*32];
  unsigned short* aB1 = &As[(w*32 + 16)*32];
  unsigned short* bB0 = &Bs[(w*32     )*32];
  unsigned short* bB1 = &Bs[(w*32 + 16)*32];

  for (int k0 = kBeg; k0 < kEnd; k0 += BK) {
    const char* aSrc = (const char*)(A  + (size_t)(rowTile + w*32 + srow)*lda + k0) + sbyte;
    const char* bSrc = (const char*)(BT + (size_t)(colTile + w*32 + srow)*ldb + k0) + sbyte;
    gload16(aSrc,                    aB0);
    gload16(aSrc + 16*(size_t)lda*2, aB1);
    gload16(bSrc,                    bB0);
    gload16(bSrc + 16*(size_t)ldb*2, bB1);
    __syncthreads();

    bf16x8 af[4], bfr[4];
    #pragma unroll
    for (int mi = 0; mi < 4; mi++)
      af[mi] = *(const bf16x8*)&As[(mOff + mi*16 + lrow)*32 + quad*8];
    #pragma unroll
    for (int ni = 0; ni < 4; ni++)
      bfr[ni] = *(const bf16x8*)&Bs[(nOff + ni*16 + lrow)*32 + quad*8];
    #pragma unroll
    for (int mi = 0; mi < 4; mi++)
      #pragma unroll
      for (int ni = 0; ni < 4; ni++)
        acc[mi][ni] = __builtin_amdgcn_mfma_f32_16x16x32_bf16(
            af[mi], bfr[ni], acc[mi][ni], 0, 0, 0);
    __syncthreads();
  }

  #pragma unroll
  for (int mi = 0; mi < 4; mi++) {
    #pragma unroll
    for (int ni = 0; ni < 4; ni++) {
      const int row = rowTile + mOff + mi*16 + quad*4;
      const int col = colTile + nOff + ni*16 + lrow;
      float* Cb = (col < splitN) ? c0 : c1;
      const int cc = (col < splitN) ? col : col - splitN;
      #pragma unroll
      for (int r = 0; r < 4; r++)
        Cb[(size_t)(row + r) * ldc + cc] = acc[mi][ni][r];
    }
  }
}

// ---------------------------------------------------------------------------
// Tiled f32 GEMM (GEMM2 split-K only).
// ---------------------------------------------------------------------------
template<int KCHUNK>
__global__ __launch_bounds__(256) void gemm_k(
    const float* __restrict__ Ap, int lda,
    const float* __restrict__ Bp, int ldb,
    float* __restrict__ Cp, int ldc,
    int M, int N, int K)
{
  __shared__ float As[16][64];
  __shared__ float Bs[16][64];
  const int tid = threadIdx.x;
  const int tx = tid & 15, ty = tid >> 4;
  const int rowTile = blockIdx.y * 64;
  const int colTile = blockIdx.x * 64;

  int kBeg = 0, kEnd = K;
  float* Cout = Cp;
  if constexpr (KCHUNK > 0) {
    kBeg = blockIdx.z * KCHUNK;
    kEnd = kBeg + KCHUNK;
    Cout += (size_t)blockIdx.z * M * ldc;
  }

  const int ar = tid >> 2;
  const int ak = (tid & 3) * 4;
  const int bk = tid >> 4;
  const int bn = (tid & 15) * 4;

  float acc[4][4] = {};

  for (int k0 = kBeg; k0 < kEnd; k0 += 16) {
    {
      const int r = rowTile + ar;
      float4 av = *(const float4*)(Ap + (size_t)r * lda + k0 + ak);
      As[ak+0][ar] = av.x; As[ak+1][ar] = av.y;
      As[ak+2][ar] = av.z; As[ak+3][ar] = av.w;
    }
    {
      const int kk = k0 + bk;
      const int c = colTile + bn;
      float4 bv;
      if (c + 3 < N) {
        bv = *(const float4*)(Bp + (size_t)kk * ldb + c);
      } else {
        bv.x = (c+0 < N) ? Bp[(size_t)kk*ldb + c+0] : 0.f;
        bv.y = (c+1 < N) ? Bp[(size_t)kk*ldb + c+1] : 0.f;
        bv.z = (c+2 < N) ? Bp[(size_t)kk*ldb + c+2] : 0.f;
        bv.w = (c+3 < N) ? Bp[(size_t)kk*ldb + c+3] : 0.f;
      }
      *(float4*)&Bs[bk][bn] = bv;
    }
    __syncthreads();
    #pragma unroll
    for (int kk = 0; kk < 16; kk++) {
      float4 a4 = *(const float4*)&As[kk][ty*4];
      float4 b4 = *(const float4*)&Bs[kk][tx*4];
      float a[4] = {a4.x, a4.y, a4.z, a4.w};
      float b[4] = {b4.x, b4.y, b4.z, b4.w};
      #pragma unroll
      for (int i = 0; i < 4; i++)
        #pragma unroll
        for (int j = 0; j < 4; j++)
          acc[i][j] += a[i] * b[j];
    }
    __syncthreads();
  }

  #pragma unroll
  for (int i = 0; i < 4; i++) {
    const int r = rowTile + ty*4 + i;
    #pragma unroll
    for (int j = 0; j < 4; j++) {
      const int c = colTile + tx*4 + j;
      if (c >= N) continue;
      Cout[(size_t)r*ldc + c] = acc[i][j];
    }
  }
}

// ---------------------------------------------------------------------------
// GEMM3 (dedicated VALU kernel): delta16[row,d] =
//   bf16(softplus(dot(xdbl[row,0:64], dtwt[d,0:64]) + bias[d])).
// K=64 fully staged once; 64x64 tile, 4x4 micro-tile, ushort4 stores.
// Grid (32, 32) = 1024 blocks. LDS 34 KB -> 4 blocks/CU.
// ---------------------------------------------------------------------------
__global__ __launch_bounds__(256) void gemm3_k(
    const float* __restrict__ xdbl,
    const unsigned short* __restrict__ dtwt,
    const float* __restrict__ bias,
    unsigned short* __restrict__ delta16)
{
  __shared__ float As[64][68];   // [k][row], pad 64->68
  __shared__ float Bs[64][68];   // [k][col]
  const int tid = threadIdx.x;
  const int tx = tid & 15, ty = tid >> 4;
  const int rowTile = blockIdx.y * 64;
  const int colTile = blockIdx.x * 64;

  const int ar = tid >> 2;          // 0..63
  const int ak = (tid & 3) * 4;     // 0,4,8,12

  #pragma unroll
  for (int kc = 0; kc < 4; kc++) {
    const int kk = kc*16 + ak;
    float4 av = *(const float4*)(xdbl + (size_t)(rowTile + ar) * NPROJ + kk);
    As[kk+0][ar] = av.x; As[kk+1][ar] = av.y;
    As[kk+2][ar] = av.z; As[kk+3][ar] = av.w;
    ushort4 bv = *(const ushort4*)(dtwt + (size_t)(colTile + ar) * DTRANK + kk);
    Bs[kk+0][ar] = bf2f(bv.x); Bs[kk+1][ar] = bf2f(bv.y);
    Bs[kk+2][ar] = bf2f(bv.z); Bs[kk+3][ar] = bf2f(bv.w);
  }
  __syncthreads();

  float acc[4][4] = {};
  #pragma unroll 8
  for (int k = 0; k < DTRANK; k++) {
    float4 a4 = *(const float4*)&As[k][ty*4];
    float4 b4 = *(const float4*)&Bs[k][tx*4];
    float a[4] = {a4.x, a4.y, a4.z, a4.w};
    float b[4] = {b4.x, b4.y, b4.z, b4.w};
    #pragma unroll
    for (int i = 0; i < 4; i++)
      #pragma unroll
      for (int j = 0; j < 4; j++)
        acc[i][j] += a[i] * b[j];
  }

  float4 bb = *(const float4*)(bias + colTile + tx*4);
  const float bvv[4] = {bb.x, bb.y, bb.z, bb.w};
  #pragma unroll
  for (int i = 0; i < 4; i++) {
    const int r = rowTile + ty*4 + i;
    ushort4 o;
    float vv[4];
    #pragma unroll
    for (int j = 0; j < 4; j++) {
      float v = acc[i][j] + bvv[j];
      vv[j] = (v > 20.f) ? v : log1pf(__expf(v));
    }
    o.x = f2bf(vv[0]); o.y = f2bf(vv[1]); o.z = f2bf(vv[2]); o.w = f2bf(vv[3]);
    *(ushort4*)(delta16 + (size_t)r * DINNER + colTile + tx*4) = o;
  }
}

// ---------------------------------------------------------------------------
// GEMM2 reduce: sum 16 partial slices -> xdbl f32.
// ---------------------------------------------------------------------------
__global__ __launch_bounds__(256) void reduce_g2_k(
    const float* __restrict__ part, float* __restrict__ outp)
{
  const int n4 = NROW*NPROJ/4;
  const int i = blockIdx.x * 256 + threadIdx.x;
  if (i >= n4) return;
  float4 s = *(const float4*)(part + (size_t)i * 4);
  #pragma unroll
  for (int z = 1; z < G2SPLIT; z++) {
    float4 v = *(const float4*)(part + (size_t)z * n4 * 4 + (size_t)i * 4);
    s.x += v.x; s.y += v.y; s.z += v.z; s.w += v.w;
  }
  *(float4*)(outp + (size_t)i * 4) = s;
}

// ---------------------------------------------------------------------------
// GEMM4 reduce: sum 4 partial slices -> out f32.
// ---------------------------------------------------------------------------
__global__ __launch_bounds__(256) void reduce_g4_k(
    const float* __restrict__ part, float* __restrict__ outp, int n4)
{
  const int i = blockIdx.x * 256 + threadIdx.x;
  if (i >= n4) return;
  float4 s = *(const float4*)(part + (size_t)i * 4);
  #pragma unroll
  for (int z = 1; z < G4SPLIT; z++) {
    float4 v = *(const float4*)(part + (size_t)z * n4 * 4 + (size_t)i * 4);
    s.x += v.x; s.y += v.y; s.z += v.z; s.w += v.w;
  }
  *(float4*)(outp + (size_t)i * 4) = s;
}

// ---------------------------------------------------------------------------
// Causal depthwise conv (width 4) + SiLU.
// ---------------------------------------------------------------------------
__global__ __launch_bounds__(256) void conv_silu_k(
    const float* __restrict__ xc,
    const float* __restrict__ conv_w,
    const float* __restrict__ conv_b,
    float* __restrict__ u)
{
  const int idx = blockIdx.x * 256 + threadIdx.x;
  if (idx >= NROW * DINNER) return;
  const int d = idx & (DINNER - 1);
  const int row = idx >> 11;
  const int l = row & (SEQL - 1);
  float acc = conv_b[d];
  #pragma unroll
  for (int k = 0; k < DCONV; k++) {
    const int ls = l + k - (DCONV - 1);
    if (ls >= 0)
      acc += xc[(size_t)(row + k - (DCONV - 1)) * DINNER + d] * conv_w[d*DCONV + k];
  }
  u[idx] = acc * sigmoidf_(acc);
}

// ---------------------------------------------------------------------------
// Chunked parallel scan — register-state layout (R9-verified correct).
// ---------------------------------------------------------------------------
__global__ __launch_bounds__(256) void scan_a(
    const unsigned short* __restrict__ delta16,
    const float* __restrict__ u,
    const float* __restrict__ xdbl,
    const float* __restrict__ A_log,
    float* __restrict__ S, float* __restrict__ sumd_g)
{
  const int bx = blockIdx.x;
  const int c  = bx & (NCH2-1);
  const int dg = (bx >> 6) & 7;
  const int b  = bx >> 9;
  const int dBase = dg * 256;
  const int tid = threadIdx.x;
  const int d = dBase + tid;

  __shared__ float dlt_s[CL2][256];
  __shared__ float du_s[CL2][256];
  __shared__ float bc_s[CL2][32];

  float A2[16];
  #pragma unroll
  for (int i = 0; i < 4; i++) {
    float4 al = *(const float4*)&A_log[(size_t)d*DSTATE + i*4];
    A2[i*4+0] = -__expf(al.x)*LOG2E;
    A2[i*4+1] = -__expf(al.y)*LOG2E;
    A2[i*4+2] = -__expf(al.z)*LOG2E;
    A2[i*4+3] = -__expf(al.w)*LOG2E;
  }

  const int r0 = tid >> 6;
  const int cj = (tid & 63) * 4;
  #pragma unroll
  for (int i = 0; i < 4; i++) {
    const int t = r0 + i*4;
    const size_t rowG = (size_t)(b*SEQL + c*CL2 + t);
    ushort4 dv = *(const ushort4*)&delta16[rowG*DINNER + dBase + cj];
    float4  uv = *(const float4*)&u[rowG*DINNER + dBase + cj];
    const float d0=bf2f(dv.x), d1=bf2f(dv.y), d2=bf2f(dv.z), d3=bf2f(dv.w);
    dlt_s[t][cj+0]=d0; dlt_s[t][cj+1]=d1; dlt_s[t][cj+2]=d2; dlt_s[t][cj+3]=d3;
    du_s[t][cj+0]=d0*uv.x; du_s[t][cj+1]=d1*uv.y;
    du_s[t][cj+2]=d2*uv.z; du_s[t][cj+3]=d3*uv.w;
  }
  if (tid < 128) {
    const int t = tid >> 3;
    const int cc = (tid & 7) * 4;
    const size_t rowG = (size_t)(b*SEQL + c*CL2 + t);
    *(float4*)&bc_s[t][cc] = *(const float4*)&xdbl[rowG*NPROJ + DTRANK + cc];
  }
  __syncthreads();

  float h[16];
  #pragma unroll
  for (int n = 0; n < 16; n++) h[n] = 0.f;
  float sd = 0.f;

  for (int t = 0; t < CL2; t++) {
    const float dlt = dlt_s[t][tid];
    const float du  = du_s[t][tid];
    sd += dlt;
    f32x4 bq[4];
    #pragma unroll
    for (int i = 0; i < 4; i++) bq[i] = *(const f32x4*)&bc_s[t][i*4];
    #pragma unroll
    for (int n = 0; n < 16; n++) {
      const float a = fexp2(dlt * A2[n]);
      h[n] = a * h[n] + du * bq[n>>2][n&3];
    }
  }

  const size_t base = ((size_t)(b*NCH2 + c) * DINNER + d) * DSTATE;
  #pragma unroll
  for (int i = 0; i < 4; i++) {
    f32x4 hv; hv[0]=h[i*4+0]; hv[1]=h[i*4+1]; hv[2]=h[i*4+2]; hv[3]=h[i*4+3];
    *(f32x4*)&S[base + i*4] = hv;
  }
  sumd_g[(size_t)(b*NCH2 + c) * DINNER + d] = sd;
}

__global__ __launch_bounds__(256) void scan_b(
    const float* __restrict__ S, const float* __restrict__ sumd_g,
    const float* __restrict__ A_log, float* __restrict__ H)
{
  const int idx = blockIdx.x * 256 + threadIdx.x;   // (b,d,n): 65536
  const int n = idx & 15, d = (idx >> 4) & (DINNER-1), b = idx >> 15;
  const float A2 = -__expf(A_log[(size_t)d*DSTATE + n]) * LOG2E;
  float h = 0.f;
  for (int c = 0; c < NCH2; c++) {
    const size_t pos = ((size_t)(b*NCH2 + c) * DINNER + d) * DSTATE + n;
    const float sd = sumd_g[(size_t)(b*NCH2 + c) * DINNER + d];
    H[pos] = h;
    h = fexp2(A2 * sd) * h + S[pos];
  }
}

__global__ __launch_bounds__(256) void scan_c(
    const unsigned short* __restrict__ delta16,
    const float* __restrict__ u,
    const float* __restrict__ Z,
    const float* __restrict__ xdbl,
    const float* __restrict__ A_log,
    const float* __restrict__ Dp,
    const float* __restrict__ H,
    unsigned short* __restrict__ Y)
{
  const int bx = blockIdx.x;
  const int c  = bx & (NCH2-1);
  const int dg = (bx >> 6) & 7;
  const int b  = bx >> 9;
  const int dBase = dg * 256;
  const int tid = threadIdx.x;
  const int d = dBase + tid;

  __shared__ float dlt_s[CL2][256];
  __shared__ float du_s[CL2][256];
  __shared__ float bc_s[CL2][32];

  float A2[16];
  #pragma unroll
  for (int i = 0; i < 4; i++) {
    float4 al = *(const float4*)&A_log[(size_t)d*DSTATE + i*4];
    A2[i*4+0] = -__expf(al.x)*LOG2E;
    A2[i*4+1] = -__expf(al.y)*LOG2E;
    A2[i*4+2] = -__expf(al.z)*LOG2E;
    A2[i*4+3] = -__expf(al.w)*LOG2E;
  }
  const float Dval = Dp[d];

  const int r0 = tid >> 6;
  const int cj = (tid & 63) * 4;
  #pragma unroll
  for (int i = 0; i < 4; i++) {
    const int t = r0 + i*4;
    const size_t rowG = (size_t)(b*SEQL + c*CL2 + t);
    ushort4 dv = *(const ushort4*)&delta16[rowG*DINNER + dBase + cj];
    float4  uv = *(const float4*)&u[rowG*DINNER + dBase + cj];
    const float d0=bf2f(dv.x), d1=bf2f(dv.y), d2=bf2f(dv.z), d3=bf2f(dv.w);
    dlt_s[t][cj+0]=d0; dlt_s[t][cj+1]=d1; dlt_s[t][cj+2]=d2; dlt_s[t][cj+3]=d3;
    du_s[t][cj+0]=d0*uv.x; du_s[t][cj+1]=d1*uv.y;
    du_s[t][cj+2]=d2*uv.z; du_s[t][cj+3]=d3*uv.w;
  }
  if (tid < 128) {
    const int t = tid >> 3;
    const int cc = (tid & 7) * 4;
    const size_t rowG = (size_t)(b*SEQL + c*CL2 + t);
    *(float4*)&bc_s[t][cc] = *(const float4*)&xdbl[rowG*NPROJ + DTRANK + cc];
  }

  float h[16];
  {
    const size_t hb = ((size_t)(b*NCH2 + c) * DINNER + d) * DSTATE;
    #pragma unroll
    for (int i = 0; i < 4; i++) {
      f32x4 hv = *(const f32x4*)&H[hb + i*4];
      h[i*4+0]=hv[0]; h[i*4+1]=hv[1]; h[i*4+2]=hv[2]; h[i*4+3]=hv[3];
    }
  }
  __syncthreads();

  for (int t = 0; t < CL2; t++) {
    const float dlt = dlt_s[t][tid];
    const float du  = du_s[t][tid];
    f32x4 bq[4], cq[4];
    #pragma unroll
    for (int i = 0; i < 4; i++) {
      bq[i] = *(const f32x4*)&bc_s[t][i*4];
      cq[i] = *(const f32x4*)&bc_s[t][16 + i*4];
    }
    float y = 0.f;
    #pragma unroll
    for (int n = 0; n < 16; n++) {
      const float a = fexp2(dlt * A2[n]);
      h[n] = a * h[n] + du * bq[n>>2][n&3];
      y += h[n] * cq[n>>2][n&3];
    }
    const size_t rowG = (size_t)(b*SEQL + c*CL2 + t);
    const float uu = u[rowG*DINNER + d];
    const float zz = Z[rowG*DINNER + d];
    const float yy = (y + uu*Dval) * (zz * sigmoidf_(zz));
    Y[rowG*DINNER + d] = f2bf(yy);
  }
}

// ---------------------------------------------------------------------------
extern "C" void kernel_launch(void* const* d_in, const int* in_sizes, int n_in,
                              void* d_out, int out_size, void* d_ws, size_t ws_size,
                              hipStream_t stream) {
  const float* x         = (const float*)d_in[0];
  const float* in_proj_w = (const float*)d_in[2];
  const float* conv_w    = (const float*)d_in[3];
  const float* conv_b    = (const float*)d_in[4];
  const float* x_proj_w  = (const float*)d_in[5];
  const float* dt_proj_w = (const float*)d_in[6];
  const float* dt_proj_b = (const float*)d_in[7];
  const float* A_log     = (const float*)d_in[8];
  const float* Dp        = (const float*)d_in[9];
  const float* out_proj_w= (const float*)d_in[10];
  float* out = (float*)d_out;

  // ws layout (256 MiB total, fill evidence R8). Low region as R8/R9:
  //  XC 16.78MB: xc f32 (GEMM1) -> conv reads -> g2part[0,12.58M) + dtwt tail
  //             -> yb bf16 [0,8.39M) (scan_c out, GEMM4 A)
  //  Z  16.78MB: z (GEMM1) -> scan_c reads -> GEMM4 partials 0-1
  //  u  16.78MB: xb bf16 (pre-GEMM1) -> u f32 (conv) -> GEMM4 partials 2-3
  //  xdbl 0.79MB
  //  W  16.78MB: [0,8.39M) w1t / delta16; [12.58,16.78M) w4t
  //  High scratch: S2 @ +72MiB | H2 @ +96MiB | sumd @ +120MiB
  float* XC   = (float*)d_ws;
  float* Z    = XC + (size_t)NROW * DINNER;
  float* u    = Z  + (size_t)NROW * DINNER;
  float* xdbl = u  + (size_t)NROW * DINNER;
  char*  W    = (char*)(xdbl + (size_t)NROW * NPROJ);
  unsigned short* w1t     = (unsigned short*)W;
  unsigned short* delta16 = (unsigned short*)W;
  unsigned short* w4t     = (unsigned short*)(W + 12582912);
  unsigned short* xb      = (unsigned short*)u;     // bf16 x, dead before conv
  unsigned short* yb      = (unsigned short*)XC;    // bf16 y (scan_c out)
  float* g2part = XC;                               // [0, 12.58M)
  unsigned short* dtwt = (unsigned short*)((char*)XC + 12582912);  // 256KB
  float* g4part = Z;                                // 4 slices across Z+u
  float* S2   = (float*)((char*)d_ws + 75497472);   // +72 MiB
  float* H2   = (float*)((char*)d_ws + 100663296);  // +96 MiB
  float* sumd = (float*)((char*)d_ws + 125829120);  // +120 MiB

  dim3 blk(256);

  // pre-casts
  cast_bf16_k<<<dim3((NROW*DIMX/4)/256), blk, 0, stream>>>(x, xb, NROW*DIMX/4);
  transpose_cast_k<<<dim3((2*DINNER)/32, DIMX/32), blk, 0, stream>>>(
      in_proj_w, w1t, DIMX, 2*DINNER);
  transpose_cast_k<<<dim3(DIMX/32, DINNER/32), blk, 0, stream>>>(
      out_proj_w, w4t, DINNER, DIMX);

  // GEMM1 (MFMA): [xc|z] = x @ in_proj_w
  gemm_bt_k<0><<<dim3((2*DINNER)/128, NROW/128), blk, 0, stream>>>(
      xb, DIMX, w1t, DIMX, XC, Z, DINNER, DINNER, NROW, DIMX);

  conv_silu_k<<<(NROW*DINNER)/256, blk, 0, stream>>>(XC, conv_w, conv_b, u);

  // dt_proj_w transpose (XC tail free after conv)
  transpose_cast_k<<<dim3(DINNER/32, DTRANK/32), blk, 0, stream>>>(
      dt_proj_w, dtwt, DTRANK, DINNER);

  // GEMM2 (f32, split-K 16) -> xdbl
  gemm_k<G2KLEN><<<dim3((NPROJ+63)/64, NROW/64, G2SPLIT), blk, 0, stream>>>(
      u, DINNER, x_proj_w, NPROJ, g2part, NPROJ, NROW, NPROJ, DINNER);
  reduce_g2_k<<<dim3((NROW*NPROJ/4 + 255)/256), blk, 0, stream>>>(g2part, xdbl);

  // GEMM3 (dedicated VALU kernel): delta16 = softplus(dtr @ dtwt^T + b), bf16
  gemm3_k<<<dim3(DINNER/64, NROW/64), blk, 0, stream>>>(
      xdbl, dtwt, dt_proj_b, delta16);

  // chunked selective scan (register-state layout)
  scan_a<<<dim3(BSZ*NCH2*8), blk, 0, stream>>>(delta16, u, xdbl, A_log, S2, sumd);
  scan_b<<<dim3((BSZ*DINNER*DSTATE)/256), blk, 0, stream>>>(S2, sumd, A_log, H2);
  scan_c<<<dim3(BSZ*NCH2*8), blk, 0, stream>>>(
      delta16, u, Z, xdbl, A_log, Dp, H2, yb);

  // GEMM4 (MFMA, split-K 4): out = y @ out_proj_w
  gemm_bt_k<DINNER/G4SPLIT><<<dim3(DIMX/128, NROW/128, G4SPLIT), blk, 0, stream>>>(
      yb, DINNER, w4t, DINNER, g4part, g4part, 1<<30, DIMX, NROW, DINNER);
  reduce_g4_k<<<dim3((NROW*DIMX/4 + 255)/256), blk, 0, stream>>>(
      g4part, out, NROW*DIMX/4);
}

// Round 11
// 277.514 us; speedup vs baseline: 1.3022x; 1.0127x over previous
//
#include <hip/hip_runtime.h>
#include <hip/hip_bf16.h>

#define DIMX 1024
#define DSTATE 16
#define DCONV 4
#define DINNER 2048
#define DTRANK 64
#define BSZ 2
#define SEQL 1024
#define NROW (BSZ*SEQL)              // 2048
#define NPROJ (DTRANK + 2*DSTATE)    // 96
#define NCH2 64                      // scan chunks
#define CL2 16                       // chunk length (SEQL/NCH2)
#define G2SPLIT 8                    // GEMM2 split-K factor
#define G2KLEN (DINNER / G2SPLIT)    // 256
#define G4SPLIT 4                    // GEMM4 split-K factor

typedef __bf16 bf16x8 __attribute__((ext_vector_type(8)));
typedef float f32x4 __attribute__((ext_vector_type(4)));
typedef unsigned short ushort8_t __attribute__((ext_vector_type(8)));

#define LOG2E 1.44269504088896340736f

__device__ __forceinline__ float sigmoidf_(float x){ return 1.0f/(1.0f+__expf(-x)); }
__device__ __forceinline__ float fexp2(float x){ return __builtin_amdgcn_exp2f(x); }
__device__ __forceinline__ unsigned short f2bf(float f){
  union { float f; unsigned int i; } c; c.f = f;
  unsigned int r = (c.i + 0x7FFFu + ((c.i >> 16) & 1u)) >> 16;
  return (unsigned short)r;
}
__device__ __forceinline__ float bf2f(unsigned short u){
  union { unsigned int i; float f; } c; c.i = ((unsigned int)u) << 16; return c.f;
}

// async global->LDS, 16 B per lane; LDS dest = base + lane*16 (wave-uniform base)
__device__ __forceinline__ void gload16(const void* g, void* l){
  __builtin_amdgcn_global_load_lds(
      (const __attribute__((address_space(1))) unsigned int*)g,
      (__attribute__((address_space(3))) unsigned int*)l, 16, 0, 0);
}

// ---------------------------------------------------------------------------
// Fused prep: grid-sectioned. [0,2048): cast x->xb. Then 3 transposes:
// w1 (1024x4096)->w1t, w4 (2048x1024)->w4t, dtw (64x2048)->dtwt.
// ---------------------------------------------------------------------------
__global__ __launch_bounds__(256) void prep_k(
    const float* __restrict__ x, unsigned short* __restrict__ xb,
    const float* __restrict__ w1, unsigned short* __restrict__ w1t,
    const float* __restrict__ w4, unsigned short* __restrict__ w4t,
    const float* __restrict__ dtw, unsigned short* __restrict__ dtwt)
{
  __shared__ unsigned short T[32][33];
  int blk = blockIdx.x;
  if (blk < 2048) {                      // cast: 2048*256 threads x float4
    const int i = blk*256 + threadIdx.x;
    float4 v = *(const float4*)(x + (size_t)i * 4);
    ushort4 o;
    o.x = f2bf(v.x); o.y = f2bf(v.y); o.z = f2bf(v.z); o.w = f2bf(v.w);
    *(ushort4*)(xb + (size_t)i * 4) = o;
    return;
  }
  blk -= 2048;
  const float* w; unsigned short* wt; int K, N, nT, kT;
  if (blk < 4096) {                      // w1t: N=4096,K=1024 grid 128x32
    w = w1; wt = w1t; K = 1024; N = 4096;
    nT = (blk & 127) * 32; kT = (blk >> 7) * 32;
  } else if (blk < 4096 + 2048) {        // w4t: N=1024,K=2048 grid 32x64
    blk -= 4096;
    w = w4; wt = w4t; K = 2048; N = 1024;
    nT = (blk & 31) * 32; kT = (blk >> 5) * 32;
  } else {                               // dtwt: N=2048,K=64 grid 64x2
    blk -= 6144;
    w = dtw; wt = dtwt; K = 64; N = 2048;
    nT = (blk & 63) * 32; kT = (blk >> 6) * 32;
  }
  const int tx = threadIdx.x & 31, ty = threadIdx.x >> 5;
  #pragma unroll
  for (int i = 0; i < 4; i++)
    T[tx][ty + i*8] = f2bf(w[(size_t)(kT + ty + i*8) * N + nT + tx]);
  __syncthreads();
  #pragma unroll
  for (int i = 0; i < 4; i++)
    wt[(size_t)(nT + ty + i*8) * K + kT + tx] = T[ty + i*8][tx];
}

// ---------------------------------------------------------------------------
// GEMM1 (bf16 dual-output clone): [xcb|zb] = A @ BT^T, bf16 stores.
// Same proven 128x128 BK=32 global_load_lds structure.
// ---------------------------------------------------------------------------
__global__ __launch_bounds__(256) void gemm1_bf2_k(
    const unsigned short* __restrict__ A, int lda,
    const unsigned short* __restrict__ BT, int ldb,
    unsigned short* __restrict__ X0, unsigned short* __restrict__ X1,
    int splitN, int ldc, int K)
{
  constexpr int BM = 128, BN = 128, BK = 32;
  __shared__ unsigned short As[BM*BK];
  __shared__ unsigned short Bs[BN*BK];

  const int tid = threadIdx.x;
  const int w = tid >> 6, lane = tid & 63;
  const int quad = lane >> 4, lrow = lane & 15;
  const int mOff = (w & 1) * 64, nOff = (w >> 1) * 64;
  const int rowTile = blockIdx.y * BM, colTile = blockIdx.x * BN;

  f32x4 acc[4][4] = {};

  const int srow = lane >> 2;
  const int sbyte = (lane & 3) * 16;
  unsigned short* aB0 = &As[(w*32     )*32];
  unsigned short* aB1 = &As[(w*32 + 16)*32];
  unsigned short* bB0 = &Bs[(w*32     )*32];
  unsigned short* bB1 = &Bs[(w*32 + 16)*32];

  for (int k0 = 0; k0 < K; k0 += BK) {
    const char* aSrc = (const char*)(A  + (size_t)(rowTile + w*32 + srow)*lda + k0) + sbyte;
    const char* bSrc = (const char*)(BT + (size_t)(colTile + w*32 + srow)*ldb + k0) + sbyte;
    gload16(aSrc,                    aB0);
    gload16(aSrc + 16*(size_t)lda*2, aB1);
    gload16(bSrc,                    bB0);
    gload16(bSrc + 16*(size_t)ldb*2, bB1);
    __syncthreads();

    bf16x8 af[4], bfr[4];
    #pragma unroll
    for (int mi = 0; mi < 4; mi++)
      af[mi] = *(const bf16x8*)&As[(mOff + mi*16 + lrow)*32 + quad*8];
    #pragma unroll
    for (int ni = 0; ni < 4; ni++)
      bfr[ni] = *(const bf16x8*)&Bs[(nOff + ni*16 + lrow)*32 + quad*8];
    #pragma unroll
    for (int mi = 0; mi < 4; mi++)
      #pragma unroll
      for (int ni = 0; ni < 4; ni++)
        acc[mi][ni] = __builtin_amdgcn_mfma_f32_16x16x32_bf16(
            af[mi], bfr[ni], acc[mi][ni], 0, 0, 0);
    __syncthreads();
  }

  #pragma unroll
  for (int mi = 0; mi < 4; mi++) {
    #pragma unroll
    for (int ni = 0; ni < 4; ni++) {
      const int row = rowTile + mOff + mi*16 + quad*4;
      const int col = colTile + nOff + ni*16 + lrow;
      unsigned short* Cb = (col < splitN) ? X0 : X1;
      const int cc = (col < splitN) ? col : col - splitN;
      #pragma unroll
      for (int r = 0; r < 4; r++)
        Cb[(size_t)(row + r) * ldc + cc] = f2bf(acc[mi][ni][r]);
    }
  }
}

// ---------------------------------------------------------------------------
// GEMM4 (R10-proven, unchanged): f32 split-K partials.
// ---------------------------------------------------------------------------
template<int KCH>
__global__ __launch_bounds__(256) void gemm_bt_k(
    const unsigned short* __restrict__ A, int lda,
    const unsigned short* __restrict__ BT, int ldb,
    float* __restrict__ C0, float* __restrict__ C1, int splitN, int ldc,
    int M, int K)
{
  constexpr int BM = 128, BN = 128, BK = 32;
  __shared__ unsigned short As[BM*BK];
  __shared__ unsigned short Bs[BN*BK];

  const int tid = threadIdx.x;
  const int w = tid >> 6, lane = tid & 63;
  const int quad = lane >> 4, lrow = lane & 15;
  const int mOff = (w & 1) * 64, nOff = (w >> 1) * 64;
  const int rowTile = blockIdx.y * BM, colTile = blockIdx.x * BN;

  int kBeg = 0, kEnd = K;
  float* c0 = C0; float* c1 = C1;
  if constexpr (KCH > 0) {
    kBeg = blockIdx.z * KCH;
    kEnd = kBeg + KCH;
    c0 += (size_t)blockIdx.z * M * ldc;
    c1 += (size_t)blockIdx.z * M * ldc;
  }

  f32x4 acc[4][4] = {};

  const int srow = lane >> 2;
  const int sbyte = (lane & 3) * 16;
  unsigned short* aB0 = &As[(w*32     )*32];
  unsigned short* aB1 = &As[(w*32 + 16)*32];
  unsigned short* bB0 = &Bs[(w*32     )*32];
  unsigned short* bB1 = &Bs[(w*32 + 16)*32];

  for (int k0 = kBeg; k0 < kEnd; k0 += BK) {
    const char* aSrc = (const char*)(A  + (size_t)(rowTile + w*32 + srow)*lda + k0) + sbyte;
    const char* bSrc = (const char*)(BT + (size_t)(colTile + w*32 + srow)*ldb + k0) + sbyte;
    gload16(aSrc,                    aB0);
    gload16(aSrc + 16*(size_t)lda*2, aB1);
    gload16(bSrc,                    bB0);
    gload16(bSrc + 16*(size_t)ldb*2, bB1);
    __syncthreads();

    bf16x8 af[4], bfr[4];
    #pragma unroll
    for (int mi = 0; mi < 4; mi++)
      af[mi] = *(const bf16x8*)&As[(mOff + mi*16 + lrow)*32 + quad*8];
    #pragma unroll
    for (int ni = 0; ni < 4; ni++)
      bfr[ni] = *(const bf16x8*)&Bs[(nOff + ni*16 + lrow)*32 + quad*8];
    #pragma unroll
    for (int mi = 0; mi < 4; mi++)
      #pragma unroll
      for (int ni = 0; ni < 4; ni++)
        acc[mi][ni] = __builtin_amdgcn_mfma_f32_16x16x32_bf16(
            af[mi], bfr[ni], acc[mi][ni], 0, 0, 0);
    __syncthreads();
  }

  #pragma unroll
  for (int mi = 0; mi < 4; mi++) {
    #pragma unroll
    for (int ni = 0; ni < 4; ni++) {
      const int row = rowTile + mOff + mi*16 + quad*4;
      const int col = colTile + nOff + ni*16 + lrow;
      float* Cb = (col < splitN) ? c0 : c1;
      const int cc = (col < splitN) ? col : col - splitN;
      #pragma unroll
      for (int r = 0; r < 4; r++)
        Cb[(size_t)(row + r) * ldc + cc] = acc[mi][ni][r];
    }
  }
}

// ---------------------------------------------------------------------------
// Tiled f32 GEMM (GEMM2 split-K only).
// ---------------------------------------------------------------------------
template<int KCHUNK>
__global__ __launch_bounds__(256) void gemm_k(
    const float* __restrict__ Ap, int lda,
    const float* __restrict__ Bp, int ldb,
    float* __restrict__ Cp, int ldc,
    int M, int N, int K)
{
  __shared__ float As[16][64];
  __shared__ float Bs[16][64];
  const int tid = threadIdx.x;
  const int tx = tid & 15, ty = tid >> 4;
  const int rowTile = blockIdx.y * 64;
  const int colTile = blockIdx.x * 64;

  int kBeg = 0, kEnd = K;
  float* Cout = Cp;
  if constexpr (KCHUNK > 0) {
    kBeg = blockIdx.z * KCHUNK;
    kEnd = kBeg + KCHUNK;
    Cout += (size_t)blockIdx.z * M * ldc;
  }

  const int ar = tid >> 2;
  const int ak = (tid & 3) * 4;
  const int bk = tid >> 4;
  const int bn = (tid & 15) * 4;

  float acc[4][4] = {};

  for (int k0 = kBeg; k0 < kEnd; k0 += 16) {
    {
      const int r = rowTile + ar;
      float4 av = *(const float4*)(Ap + (size_t)r * lda + k0 + ak);
      As[ak+0][ar] = av.x; As[ak+1][ar] = av.y;
      As[ak+2][ar] = av.z; As[ak+3][ar] = av.w;
    }
    {
      const int kk = k0 + bk;
      const int c = colTile + bn;
      float4 bv;
      if (c + 3 < N) {
        bv = *(const float4*)(Bp + (size_t)kk * ldb + c);
      } else {
        bv.x = (c+0 < N) ? Bp[(size_t)kk*ldb + c+0] : 0.f;
        bv.y = (c+1 < N) ? Bp[(size_t)kk*ldb + c+1] : 0.f;
        bv.z = (c+2 < N) ? Bp[(size_t)kk*ldb + c+2] : 0.f;
        bv.w = (c+3 < N) ? Bp[(size_t)kk*ldb + c+3] : 0.f;
      }
      *(float4*)&Bs[bk][bn] = bv;
    }
    __syncthreads();
    #pragma unroll
    for (int kk = 0; kk < 16; kk++) {
      float4 a4 = *(const float4*)&As[kk][ty*4];
      float4 b4 = *(const float4*)&Bs[kk][tx*4];
      float a[4] = {a4.x, a4.y, a4.z, a4.w};
      float b[4] = {b4.x, b4.y, b4.z, b4.w};
      #pragma unroll
      for (int i = 0; i < 4; i++)
        #pragma unroll
        for (int j = 0; j < 4; j++)
          acc[i][j] += a[i] * b[j];
    }
    __syncthreads();
  }

  #pragma unroll
  for (int i = 0; i < 4; i++) {
    const int r = rowTile + ty*4 + i;
    #pragma unroll
    for (int j = 0; j < 4; j++) {
      const int c = colTile + tx*4 + j;
      if (c >= N) continue;
      Cout[(size_t)r*ldc + c] = acc[i][j];
    }
  }
}

// ---------------------------------------------------------------------------
// GEMM3 (VALU): delta16 = bf16(softplus(xdbl[:,0:64] @ dtwt^T + bias)).
// ---------------------------------------------------------------------------
__global__ __launch_bounds__(256) void gemm3_k(
    const float* __restrict__ xdbl,
    const unsigned short* __restrict__ dtwt,
    const float* __restrict__ bias,
    unsigned short* __restrict__ delta16)
{
  __shared__ float As[64][68];
  __shared__ float Bs[64][68];
  const int tid = threadIdx.x;
  const int tx = tid & 15, ty = tid >> 4;
  const int rowTile = blockIdx.y * 64;
  const int colTile = blockIdx.x * 64;

  const int ar = tid >> 2;
  const int ak = (tid & 3) * 4;

  #pragma unroll
  for (int kc = 0; kc < 4; kc++) {
    const int kk = kc*16 + ak;
    float4 av = *(const float4*)(xdbl + (size_t)(rowTile + ar) * NPROJ + kk);
    As[kk+0][ar] = av.x; As[kk+1][ar] = av.y;
    As[kk+2][ar] = av.z; As[kk+3][ar] = av.w;
    ushort4 bv = *(const ushort4*)(dtwt + (size_t)(colTile + ar) * DTRANK + kk);
    Bs[kk+0][ar] = bf2f(bv.x); Bs[kk+1][ar] = bf2f(bv.y);
    Bs[kk+2][ar] = bf2f(bv.z); Bs[kk+3][ar] = bf2f(bv.w);
  }
  __syncthreads();

  float acc[4][4] = {};
  #pragma unroll 8
  for (int k = 0; k < DTRANK; k++) {
    float4 a4 = *(const float4*)&As[k][ty*4];
    float4 b4 = *(const float4*)&Bs[k][tx*4];
    float a[4] = {a4.x, a4.y, a4.z, a4.w};
    float b[4] = {b4.x, b4.y, b4.z, b4.w};
    #pragma unroll
    for (int i = 0; i < 4; i++)
      #pragma unroll
      for (int j = 0; j < 4; j++)
        acc[i][j] += a[i] * b[j];
  }

  float4 bb = *(const float4*)(bias + colTile + tx*4);
  const float bvv[4] = {bb.x, bb.y, bb.z, bb.w};
  #pragma unroll
  for (int i = 0; i < 4; i++) {
    const int r = rowTile + ty*4 + i;
    ushort4 o;
    float vv[4];
    #pragma unroll
    for (int j = 0; j < 4; j++) {
      float v = acc[i][j] + bvv[j];
      vv[j] = (v > 20.f) ? v : log1pf(__expf(v));
    }
    o.x = f2bf(vv[0]); o.y = f2bf(vv[1]); o.z = f2bf(vv[2]); o.w = f2bf(vv[3]);
    *(ushort4*)(delta16 + (size_t)r * DINNER + colTile + tx*4) = o;
  }
}

// ---------------------------------------------------------------------------
// Reduces.
// ---------------------------------------------------------------------------
__global__ __launch_bounds__(256) void reduce_g2_k(
    const float* __restrict__ part, float* __restrict__ outp)
{
  const int n4 = NROW*NPROJ/4;
  const int i = blockIdx.x * 256 + threadIdx.x;
  if (i >= n4) return;
  float4 s = *(const float4*)(part + (size_t)i * 4);
  #pragma unroll
  for (int z = 1; z < G2SPLIT; z++) {
    float4 v = *(const float4*)(part + (size_t)z * n4 * 4 + (size_t)i * 4);
    s.x += v.x; s.y += v.y; s.z += v.z; s.w += v.w;
  }
  *(float4*)(outp + (size_t)i * 4) = s;
}

__global__ __launch_bounds__(256) void reduce_g4_k(
    const float* __restrict__ part, float* __restrict__ outp, int n4)
{
  const int i = blockIdx.x * 256 + threadIdx.x;
  if (i >= n4) return;
  float4 s = *(const float4*)(part + (size_t)i * 4);
  #pragma unroll
  for (int z = 1; z < G4SPLIT; z++) {
    float4 v = *(const float4*)(part + (size_t)z * n4 * 4 + (size_t)i * 4);
    s.x += v.x; s.y += v.y; s.z += v.z; s.w += v.w;
  }
  *(float4*)(outp + (size_t)i * 4) = s;
}

// ---------------------------------------------------------------------------
// Conv (width 4) + SiLU: read bf16 xcb, write u f32 (GEMM2) + ub bf16 (scan).
// ---------------------------------------------------------------------------
__global__ __launch_bounds__(256) void conv_silu_k(
    const unsigned short* __restrict__ xcb,
    const float* __restrict__ conv_w,
    const float* __restrict__ conv_b,
    float* __restrict__ u, unsigned short* __restrict__ ub)
{
  const int idx = blockIdx.x * 256 + threadIdx.x;
  if (idx >= NROW * DINNER) return;
  const int d = idx & (DINNER - 1);
  const int row = idx >> 11;
  const int l = row & (SEQL - 1);
  float acc = conv_b[d];
  #pragma unroll
  for (int k = 0; k < DCONV; k++) {
    const int ls = l + k - (DCONV - 1);
    if (ls >= 0)
      acc += bf2f(xcb[(size_t)(row + k - (DCONV - 1)) * DINNER + d]) * conv_w[d*DCONV + k];
  }
  const float v = acc * sigmoidf_(acc);
  u[idx] = v;
  ub[idx] = f2bf(v);
}

// ---------------------------------------------------------------------------
// Scan: register-resident inputs (coalesced per-t loads, no big LDS staging).
// One lane owns channel d, h[16] in VGPRs. B/C broadcast from 2 KB LDS.
// ---------------------------------------------------------------------------
__global__ __launch_bounds__(256) void scan_a(
    const unsigned short* __restrict__ delta16,
    const unsigned short* __restrict__ ub,
    const float* __restrict__ xdbl,
    const float* __restrict__ A_log,
    float* __restrict__ S, float* __restrict__ sumd_g)
{
  const int bx = blockIdx.x;
  const int c  = bx & (NCH2-1);
  const int dg = (bx >> 6) & 7;
  const int b  = bx >> 9;
  const int d = dg * 256 + threadIdx.x;
  const size_t row0 = (size_t)(b*SEQL + c*CL2);

  __shared__ float bc_s[CL2][32];
  if (threadIdx.x < 128) {
    const int t = threadIdx.x >> 3;
    const int cc = (threadIdx.x & 7) * 4;
    *(float4*)&bc_s[t][cc] = *(const float4*)&xdbl[(row0 + t)*NPROJ + DTRANK + cc];
  }

  float A2[16];
  #pragma unroll
  for (int i = 0; i < 4; i++) {
    float4 al = *(const float4*)&A_log[(size_t)d*DSTATE + i*4];
    A2[i*4+0] = -__expf(al.x)*LOG2E; A2[i*4+1] = -__expf(al.y)*LOG2E;
    A2[i*4+2] = -__expf(al.z)*LOG2E; A2[i*4+3] = -__expf(al.w)*LOG2E;
  }

  float dlt[CL2], uu[CL2];
  #pragma unroll
  for (int t = 0; t < CL2; t++) {
    dlt[t] = bf2f(delta16[(row0 + t)*DINNER + d]);
    uu[t]  = bf2f(ub[(row0 + t)*DINNER + d]);
  }
  __syncthreads();

  float h[16];
  #pragma unroll
  for (int n = 0; n < 16; n++) h[n] = 0.f;
  float sd = 0.f;

  #pragma unroll
  for (int t = 0; t < CL2; t++) {
    const float du = dlt[t] * uu[t];
    sd += dlt[t];
    f32x4 bq[4];
    #pragma unroll
    for (int i = 0; i < 4; i++) bq[i] = *(const f32x4*)&bc_s[t][i*4];
    #pragma unroll
    for (int n = 0; n < 16; n++) {
      const float a = fexp2(dlt[t] * A2[n]);
      h[n] = a * h[n] + du * bq[n>>2][n&3];
    }
  }

  const size_t base = ((size_t)(b*NCH2 + c) * DINNER + d) * DSTATE;
  #pragma unroll
  for (int i = 0; i < 4; i++) {
    f32x4 hv; hv[0]=h[i*4+0]; hv[1]=h[i*4+1]; hv[2]=h[i*4+2]; hv[3]=h[i*4+3];
    *(f32x4*)&S[base + i*4] = hv;
  }
  sumd_g[(size_t)(b*NCH2 + c) * DINNER + d] = sd;
}

__global__ __launch_bounds__(256) void scan_b(
    const float* __restrict__ S, const float* __restrict__ sumd_g,
    const float* __restrict__ A_log, float* __restrict__ H)
{
  const int idx = blockIdx.x * 256 + threadIdx.x;   // (b,d,n): 65536
  const int n = idx & 15, d = (idx >> 4) & (DINNER-1), b = idx >> 15;
  const float A2 = -__expf(A_log[(size_t)d*DSTATE + n]) * LOG2E;
  float h = 0.f;
  for (int c = 0; c < NCH2; c++) {
    const size_t pos = ((size_t)(b*NCH2 + c) * DINNER + d) * DSTATE + n;
    const float sd = sumd_g[(size_t)(b*NCH2 + c) * DINNER + d];
    H[pos] = h;
    h = fexp2(A2 * sd) * h + S[pos];
  }
}

__global__ __launch_bounds__(256) void scan_c(
    const unsigned short* __restrict__ delta16,
    const unsigned short* __restrict__ ub,
    const unsigned short* __restrict__ zb,
    const float* __restrict__ xdbl,
    const float* __restrict__ A_log,
    const float* __restrict__ Dp,
    const float* __restrict__ H,
    unsigned short* __restrict__ Y)
{
  const int bx = blockIdx.x;
  const int c  = bx & (NCH2-1);
  const int dg = (bx >> 6) & 7;
  const int b  = bx >> 9;
  const int d = dg * 256 + threadIdx.x;
  const size_t row0 = (size_t)(b*SEQL + c*CL2);

  __shared__ float bc_s[CL2][32];
  if (threadIdx.x < 128) {
    const int t = threadIdx.x >> 3;
    const int cc = (threadIdx.x & 7) * 4;
    *(float4*)&bc_s[t][cc] = *(const float4*)&xdbl[(row0 + t)*NPROJ + DTRANK + cc];
  }

  float A2[16];
  #pragma unroll
  for (int i = 0; i < 4; i++) {
    float4 al = *(const float4*)&A_log[(size_t)d*DSTATE + i*4];
    A2[i*4+0] = -__expf(al.x)*LOG2E; A2[i*4+1] = -__expf(al.y)*LOG2E;
    A2[i*4+2] = -__expf(al.z)*LOG2E; A2[i*4+3] = -__expf(al.w)*LOG2E;
  }
  const float Dval = Dp[d];

  float dlt[CL2], uu[CL2], zz[CL2];
  #pragma unroll
  for (int t = 0; t < CL2; t++) {
    dlt[t] = bf2f(delta16[(row0 + t)*DINNER + d]);
    uu[t]  = bf2f(ub[(row0 + t)*DINNER + d]);
    zz[t]  = bf2f(zb[(row0 + t)*DINNER + d]);
  }

  float h[16];
  {
    const size_t hb = ((size_t)(b*NCH2 + c) * DINNER + d) * DSTATE;
    #pragma unroll
    for (int i = 0; i < 4; i++) {
      f32x4 hv = *(const f32x4*)&H[hb + i*4];
      h[i*4+0]=hv[0]; h[i*4+1]=hv[1]; h[i*4+2]=hv[2]; h[i*4+3]=hv[3];
    }
  }
  __syncthreads();

  #pragma unroll
  for (int t = 0; t < CL2; t++) {
    const float du = dlt[t] * uu[t];
    f32x4 bq[4], cq[4];
    #pragma unroll
    for (int i = 0; i < 4; i++) {
      bq[i] = *(const f32x4*)&bc_s[t][i*4];
      cq[i] = *(const f32x4*)&bc_s[t][16 + i*4];
    }
    float y = 0.f;
    #pragma unroll
    for (int n = 0; n < 16; n++) {
      const float a = fexp2(dlt[t] * A2[n]);
      h[n] = a * h[n] + du * bq[n>>2][n&3];
      y += h[n] * cq[n>>2][n&3];
    }
    const float yy = (y + uu[t]*Dval) * (zz[t] * sigmoidf_(zz[t]));
    Y[(row0 + t)*DINNER + d] = f2bf(yy);
  }
}

// ---------------------------------------------------------------------------
extern "C" void kernel_launch(void* const* d_in, const int* in_sizes, int n_in,
                              void* d_out, int out_size, void* d_ws, size_t ws_size,
                              hipStream_t stream) {
  const float* x         = (const float*)d_in[0];
  const float* in_proj_w = (const float*)d_in[2];
  const float* conv_w    = (const float*)d_in[3];
  const float* conv_b    = (const float*)d_in[4];
  const float* x_proj_w  = (const float*)d_in[5];
  const float* dt_proj_w = (const float*)d_in[6];
  const float* dt_proj_b = (const float*)d_in[7];
  const float* A_log     = (const float*)d_in[8];
  const float* Dp        = (const float*)d_in[9];
  const float* out_proj_w= (const float*)d_in[10];
  float* out = (float*)d_out;

  // ws: 256 MiB (fill evidence R8). Non-aliased layout except XC region:
  //  XC [0,17M): xcb bf16 (GEMM1 out, dead after conv) -> g2part (6.3M)
  //              -> yb bf16 (scan_c out, GEMM4 A)
  char* B = (char*)d_ws;
  unsigned short* xcb  = (unsigned short*)B;
  float*          g2part = (float*)B;
  unsigned short* yb   = (unsigned short*)B;
  float* u    = (float*)(B + (17ll<<20));
  float* xdbl = (float*)(B + (34ll<<20));
  unsigned short* delta16 = (unsigned short*)(B + (35ll<<20));
  unsigned short* w1t  = (unsigned short*)(B + (44ll<<20));
  unsigned short* w4t  = (unsigned short*)(B + (53ll<<20));
  unsigned short* dtwt = (unsigned short*)(B + (58ll<<20));
  unsigned short* xb   = (unsigned short*)(B + (59ll<<20));
  float* S2   = (float*)(B + (72ll<<20));
  float* H2   = (float*)(B + (90ll<<20));
  float* sumd = (float*)(B + (108ll<<20));
  unsigned short* zb = (unsigned short*)(B + (110ll<<20));
  unsigned short* ub = (unsigned short*)(B + (119ll<<20));
  float* g4part = (float*)(B + (128ll<<20));

  dim3 blk(256);

  // fused prep: cast x->xb, transpose+cast w1/w4/dtw
  prep_k<<<dim3(2048 + 4096 + 2048 + 128), blk, 0, stream>>>(
      x, xb, in_proj_w, w1t, out_proj_w, w4t, dt_proj_w, dtwt);

  // GEMM1 (MFMA): [xcb|zb] = x @ in_proj_w, bf16 out
  gemm1_bf2_k<<<dim3((2*DINNER)/128, NROW/128), blk, 0, stream>>>(
      xb, DIMX, w1t, DIMX, xcb, zb, DINNER, DINNER, DIMX);

  // conv + silu -> u f32 + ub bf16
  conv_silu_k<<<(NROW*DINNER)/256, blk, 0, stream>>>(xcb, conv_w, conv_b, u, ub);

  // GEMM2 (f32, split-K 8) -> xdbl
  gemm_k<G2KLEN><<<dim3((NPROJ+63)/64, NROW/64, G2SPLIT), blk, 0, stream>>>(
      u, DINNER, x_proj_w, NPROJ, g2part, NPROJ, NROW, NPROJ, DINNER);
  reduce_g2_k<<<dim3((NROW*NPROJ/4 + 255)/256), blk, 0, stream>>>(g2part, xdbl);

  // GEMM3 (VALU): delta16 = softplus(dtr @ dtwt^T + b), bf16
  gemm3_k<<<dim3(DINNER/64, NROW/64), blk, 0, stream>>>(
      xdbl, dtwt, dt_proj_b, delta16);

  // chunked selective scan (register-resident inputs)
  scan_a<<<dim3(BSZ*NCH2*8), blk, 0, stream>>>(delta16, ub, xdbl, A_log, S2, sumd);
  scan_b<<<dim3((BSZ*DINNER*DSTATE)/256), blk, 0, stream>>>(S2, sumd, A_log, H2);
  scan_c<<<dim3(BSZ*NCH2*8), blk, 0, stream>>>(
      delta16, ub, zb, xdbl, A_log, Dp, H2, yb);

  // GEMM4 (MFMA, split-K 4): out = y @ out_proj_w
  gemm_bt_k<DINNER/G4SPLIT><<<dim3(DIMX/128, NROW/128, G4SPLIT), blk, 0, stream>>>(
      yb, DINNER, w4t, DINNER, g4part, g4part, 1<<30, DIMX, NROW, DINNER);
  reduce_g4_k<<<dim3((NROW*DIMX/4 + 255)/256), blk, 0, stream>>>(
      g4part, out, NROW*DIMX/4);
}

// Round 12
// 276.565 us; speedup vs baseline: 1.3066x; 1.0034x over previous
//
#include <hip/hip_runtime.h>
#include <hip/hip_bf16.h>

#define DIMX 1024
#define DSTATE 16
#define DCONV 4
#define DINNER 2048
#define DTRANK 64
#define BSZ 2
#define SEQL 1024
#define NROW (BSZ*SEQL)              // 2048
#define NPROJ (DTRANK + 2*DSTATE)    // 96
#define NCH2 64                      // scan chunks
#define CL2 16                       // chunk length (SEQL/NCH2)
#define G2SPLIT 16                   // GEMM2 split-K factor
#define G2KLEN (DINNER / G2SPLIT)    // 128
#define G4SPLIT 4                    // GEMM4 split-K factor

typedef __bf16 bf16x8 __attribute__((ext_vector_type(8)));
typedef float f32x4 __attribute__((ext_vector_type(4)));
typedef unsigned short ushort8_t __attribute__((ext_vector_type(8)));

#define LOG2E 1.44269504088896340736f

__device__ __forceinline__ float sigmoidf_(float x){ return 1.0f/(1.0f+__expf(-x)); }
__device__ __forceinline__ float fexp2(float x){ return __builtin_amdgcn_exp2f(x); }
__device__ __forceinline__ unsigned short f2bf(float f){
  union { float f; unsigned int i; } c; c.f = f;
  unsigned int r = (c.i + 0x7FFFu + ((c.i >> 16) & 1u)) >> 16;
  return (unsigned short)r;
}
__device__ __forceinline__ float bf2f(unsigned short u){
  union { unsigned int i; float f; } c; c.i = ((unsigned int)u) << 16; return c.f;
}

// async global->LDS, 16 B per lane; LDS dest = base + lane*16 (wave-uniform base)
__device__ __forceinline__ void gload16(const void* g, void* l){
  __builtin_amdgcn_global_load_lds(
      (const __attribute__((address_space(1))) unsigned int*)g,
      (__attribute__((address_space(3))) unsigned int*)l, 16, 0, 0);
}

// ---------------------------------------------------------------------------
// Fused prep (grid-sectioned):
//  [0,2048): cast x->xb
//  [2048,6144): w1 (1024x4096) -> w1t
//  [6144,8192): w4 (2048x1024) -> w4t
//  [8192,8320): dtw (64x2048) -> dtwt
//  [8320,8512): xpw (2048x96) -> xpwt rows 0..95
//  [8512,8576): zero-fill xpwt rows 96..127
// ---------------------------------------------------------------------------
__global__ __launch_bounds__(256) void prep_k(
    const float* __restrict__ x, unsigned short* __restrict__ xb,
    const float* __restrict__ w1, unsigned short* __restrict__ w1t,
    const float* __restrict__ w4, unsigned short* __restrict__ w4t,
    const float* __restrict__ dtw, unsigned short* __restrict__ dtwt,
    const float* __restrict__ xpw, unsigned short* __restrict__ xpwt)
{
  __shared__ unsigned short T[32][33];
  int blk = blockIdx.x;
  if (blk < 2048) {                      // cast
    const int i = blk*256 + threadIdx.x;
    float4 v = *(const float4*)(x + (size_t)i * 4);
    ushort4 o;
    o.x = f2bf(v.x); o.y = f2bf(v.y); o.z = f2bf(v.z); o.w = f2bf(v.w);
    *(ushort4*)(xb + (size_t)i * 4) = o;
    return;
  }
  blk -= 2048;
  if (blk >= 6464) {                     // zero-pad xpwt rows 96..127
    blk -= 6464;
    const int i = blk*256 + threadIdx.x; // 16384 ushort4 total
    *(ushort4*)(xpwt + (size_t)96*DINNER + (size_t)i*4) = make_ushort4(0,0,0,0);
    return;
  }
  const float* w; unsigned short* wt; int K, N, nT, kT;
  if (blk < 4096) {                      // w1t: N=4096,K=1024 grid 128x32
    w = w1; wt = w1t; K = 1024; N = 4096;
    nT = (blk & 127) * 32; kT = (blk >> 7) * 32;
  } else if (blk < 6144) {               // w4t: N=1024,K=2048 grid 32x64
    blk -= 4096;
    w = w4; wt = w4t; K = 2048; N = 1024;
    nT = (blk & 31) * 32; kT = (blk >> 5) * 32;
  } else if (blk < 6272) {               // dtwt: N=2048,K=64 grid 64x2
    blk -= 6144;
    w = dtw; wt = dtwt; K = 64; N = 2048;
    nT = (blk & 63) * 32; kT = (blk >> 6) * 32;
  } else {                               // xpwt: N=96,K=2048 grid 3x64
    blk -= 6272;
    w = xpw; wt = xpwt; K = 2048; N = 96;
    nT = (blk % 3) * 32; kT = (blk / 3) * 32;
  }
  const int tx = threadIdx.x & 31, ty = threadIdx.x >> 5;
  #pragma unroll
  for (int i = 0; i < 4; i++)
    T[tx][ty + i*8] = f2bf(w[(size_t)(kT + ty + i*8) * N + nT + tx]);
  __syncthreads();
  #pragma unroll
  for (int i = 0; i < 4; i++)
    wt[(size_t)(nT + ty + i*8) * K + kT + tx] = T[ty + i*8][tx];
}

// ---------------------------------------------------------------------------
// GEMM1 (bf16 dual-output, R11-proven): [xcb|zb] = A @ BT^T, bf16 stores.
// ---------------------------------------------------------------------------
__global__ __launch_bounds__(256) void gemm1_bf2_k(
    const unsigned short* __restrict__ A, int lda,
    const unsigned short* __restrict__ BT, int ldb,
    unsigned short* __restrict__ X0, unsigned short* __restrict__ X1,
    int splitN, int ldc, int K)
{
  constexpr int BM = 128, BN = 128, BK = 32;
  __shared__ unsigned short As[BM*BK];
  __shared__ unsigned short Bs[BN*BK];

  const int tid = threadIdx.x;
  const int w = tid >> 6, lane = tid & 63;
  const int quad = lane >> 4, lrow = lane & 15;
  const int mOff = (w & 1) * 64, nOff = (w >> 1) * 64;
  const int rowTile = blockIdx.y * BM, colTile = blockIdx.x * BN;

  f32x4 acc[4][4] = {};

  const int srow = lane >> 2;
  const int sbyte = (lane & 3) * 16;
  unsigned short* aB0 = &As[(w*32     )*32];
  unsigned short* aB1 = &As[(w*32 + 16)*32];
  unsigned short* bB0 = &Bs[(w*32     )*32];
  unsigned short* bB1 = &Bs[(w*32 + 16)*32];

  for (int k0 = 0; k0 < K; k0 += BK) {
    const char* aSrc = (const char*)(A  + (size_t)(rowTile + w*32 + srow)*lda + k0) + sbyte;
    const char* bSrc = (const char*)(BT + (size_t)(colTile + w*32 + srow)*ldb + k0) + sbyte;
    gload16(aSrc,                    aB0);
    gload16(aSrc + 16*(size_t)lda*2, aB1);
    gload16(bSrc,                    bB0);
    gload16(bSrc + 16*(size_t)ldb*2, bB1);
    __syncthreads();

    bf16x8 af[4], bfr[4];
    #pragma unroll
    for (int mi = 0; mi < 4; mi++)
      af[mi] = *(const bf16x8*)&As[(mOff + mi*16 + lrow)*32 + quad*8];
    #pragma unroll
    for (int ni = 0; ni < 4; ni++)
      bfr[ni] = *(const bf16x8*)&Bs[(nOff + ni*16 + lrow)*32 + quad*8];
    #pragma unroll
    for (int mi = 0; mi < 4; mi++)
      #pragma unroll
      for (int ni = 0; ni < 4; ni++)
        acc[mi][ni] = __builtin_amdgcn_mfma_f32_16x16x32_bf16(
            af[mi], bfr[ni], acc[mi][ni], 0, 0, 0);
    __syncthreads();
  }

  #pragma unroll
  for (int mi = 0; mi < 4; mi++) {
    #pragma unroll
    for (int ni = 0; ni < 4; ni++) {
      const int row = rowTile + mOff + mi*16 + quad*4;
      const int col = colTile + nOff + ni*16 + lrow;
      unsigned short* Cb = (col < splitN) ? X0 : X1;
      const int cc = (col < splitN) ? col : col - splitN;
      #pragma unroll
      for (int r = 0; r < 4; r++)
        Cb[(size_t)(row + r) * ldc + cc] = f2bf(acc[mi][ni][r]);
    }
  }
}

// ---------------------------------------------------------------------------
// GEMM2 (MFMA, split-K 16, atomic epilogue): xdbl(+)= ub @ xpwt^T cols<96.
// Grid (NROW/128, G2SPLIT). xdbl pre-zeroed by memset node.
// ---------------------------------------------------------------------------
__global__ __launch_bounds__(256) void gemm2_k(
    const unsigned short* __restrict__ A,    // ub: NROW x DINNER bf16
    const unsigned short* __restrict__ BT,   // xpwt: 128 x DINNER bf16
    float* __restrict__ xdbl)                // NROW x 96 f32 (atomic)
{
  constexpr int BM = 128, BK = 32;
  __shared__ unsigned short As[BM*BK];
  __shared__ unsigned short Bs[128*BK];

  const int tid = threadIdx.x;
  const int w = tid >> 6, lane = tid & 63;
  const int quad = lane >> 4, lrow = lane & 15;
  const int mOff = (w & 1) * 64, nOff = (w >> 1) * 64;
  const int rowTile = blockIdx.x * BM;
  const int kBeg = blockIdx.y * G2KLEN;

  f32x4 acc[4][4] = {};

  const int srow = lane >> 2;
  const int sbyte = (lane & 3) * 16;
  unsigned short* aB0 = &As[(w*32     )*32];
  unsigned short* aB1 = &As[(w*32 + 16)*32];
  unsigned short* bB0 = &Bs[(w*32     )*32];
  unsigned short* bB1 = &Bs[(w*32 + 16)*32];

  for (int k0 = kBeg; k0 < kBeg + G2KLEN; k0 += BK) {
    const char* aSrc = (const char*)(A  + (size_t)(rowTile + w*32 + srow)*DINNER + k0) + sbyte;
    const char* bSrc = (const char*)(BT + (size_t)(w*32 + srow)*DINNER + k0) + sbyte;
    gload16(aSrc,                       aB0);
    gload16(aSrc + 16*(size_t)DINNER*2, aB1);
    gload16(bSrc,                       bB0);
    gload16(bSrc + 16*(size_t)DINNER*2, bB1);
    __syncthreads();

    bf16x8 af[4], bfr[4];
    #pragma unroll
    for (int mi = 0; mi < 4; mi++)
      af[mi] = *(const bf16x8*)&As[(mOff + mi*16 + lrow)*32 + quad*8];
    #pragma unroll
    for (int ni = 0; ni < 4; ni++)
      bfr[ni] = *(const bf16x8*)&Bs[(nOff + ni*16 + lrow)*32 + quad*8];
    #pragma unroll
    for (int mi = 0; mi < 4; mi++)
      #pragma unroll
      for (int ni = 0; ni < 4; ni++)
        acc[mi][ni] = __builtin_amdgcn_mfma_f32_16x16x32_bf16(
            af[mi], bfr[ni], acc[mi][ni], 0, 0, 0);
    __syncthreads();
  }

  #pragma unroll
  for (int mi = 0; mi < 4; mi++) {
    #pragma unroll
    for (int ni = 0; ni < 4; ni++) {
      const int row = rowTile + mOff + mi*16 + quad*4;
      const int col = nOff + ni*16 + lrow;
      if (col >= NPROJ) continue;
      #pragma unroll
      for (int r = 0; r < 4; r++)
        atomicAdd(xdbl + (size_t)(row + r) * NPROJ + col, acc[mi][ni][r]);
    }
  }
}

// ---------------------------------------------------------------------------
// GEMM4 (MFMA, split-K 4, atomic epilogue): out(+)= yb @ w4t^T.
// out pre-zeroed by memset node.
// ---------------------------------------------------------------------------
__global__ __launch_bounds__(256) void gemm4_k(
    const unsigned short* __restrict__ A,   // yb: NROW x DINNER bf16
    const unsigned short* __restrict__ BT,  // w4t: DIMX x DINNER bf16
    float* __restrict__ outp)               // NROW x DIMX f32 (atomic)
{
  constexpr int BM = 128, BN = 128, BK = 32;
  constexpr int KCH = DINNER / G4SPLIT;
  __shared__ unsigned short As[BM*BK];
  __shared__ unsigned short Bs[BN*BK];

  const int tid = threadIdx.x;
  const int w = tid >> 6, lane = tid & 63;
  const int quad = lane >> 4, lrow = lane & 15;
  const int mOff = (w & 1) * 64, nOff = (w >> 1) * 64;
  const int rowTile = blockIdx.y * BM, colTile = blockIdx.x * BN;
  const int kBeg = blockIdx.z * KCH;

  f32x4 acc[4][4] = {};

  const int srow = lane >> 2;
  const int sbyte = (lane & 3) * 16;
  unsigned short* aB0 = &As[(w*32     )*32];
  unsigned short* aB1 = &As[(w*32 + 16)*32];
  unsigned short* bB0 = &Bs[(w*32     )*32];
  unsigned short* bB1 = &Bs[(w*32 + 16)*32];

  for (int k0 = kBeg; k0 < kBeg + KCH; k0 += BK) {
    const char* aSrc = (const char*)(A  + (size_t)(rowTile + w*32 + srow)*DINNER + k0) + sbyte;
    const char* bSrc = (const char*)(BT + (size_t)(colTile + w*32 + srow)*DINNER + k0) + sbyte;
    gload16(aSrc,                       aB0);
    gload16(aSrc + 16*(size_t)DINNER*2, aB1);
    gload16(bSrc,                       bB0);
    gload16(bSrc + 16*(size_t)DINNER*2, bB1);
    __syncthreads();

    bf16x8 af[4], bfr[4];
    #pragma unroll
    for (int mi = 0; mi < 4; mi++)
      af[mi] = *(const bf16x8*)&As[(mOff + mi*16 + lrow)*32 + quad*8];
    #pragma unroll
    for (int ni = 0; ni < 4; ni++)
      bfr[ni] = *(const bf16x8*)&Bs[(nOff + ni*16 + lrow)*32 + quad*8];
    #pragma unroll
    for (int mi = 0; mi < 4; mi++)
      #pragma unroll
      for (int ni = 0; ni < 4; ni++)
        acc[mi][ni] = __builtin_amdgcn_mfma_f32_16x16x32_bf16(
            af[mi], bfr[ni], acc[mi][ni], 0, 0, 0);
    __syncthreads();
  }

  #pragma unroll
  for (int mi = 0; mi < 4; mi++) {
    #pragma unroll
    for (int ni = 0; ni < 4; ni++) {
      const int row = rowTile + mOff + mi*16 + quad*4;
      const int col = colTile + nOff + ni*16 + lrow;
      #pragma unroll
      for (int r = 0; r < 4; r++)
        atomicAdd(outp + (size_t)(row + r) * DIMX + col, acc[mi][ni][r]);
    }
  }
}

// ---------------------------------------------------------------------------
// GEMM3 (VALU): delta16 = bf16(softplus(xdbl[:,0:64] @ dtwt^T + bias)).
// ---------------------------------------------------------------------------
__global__ __launch_bounds__(256) void gemm3_k(
    const float* __restrict__ xdbl,
    const unsigned short* __restrict__ dtwt,
    const float* __restrict__ bias,
    unsigned short* __restrict__ delta16)
{
  __shared__ float As[64][68];
  __shared__ float Bs[64][68];
  const int tid = threadIdx.x;
  const int tx = tid & 15, ty = tid >> 4;
  const int rowTile = blockIdx.y * 64;
  const int colTile = blockIdx.x * 64;

  const int ar = tid >> 2;
  const int ak = (tid & 3) * 4;

  #pragma unroll
  for (int kc = 0; kc < 4; kc++) {
    const int kk = kc*16 + ak;
    float4 av = *(const float4*)(xdbl + (size_t)(rowTile + ar) * NPROJ + kk);
    As[kk+0][ar] = av.x; As[kk+1][ar] = av.y;
    As[kk+2][ar] = av.z; As[kk+3][ar] = av.w;
    ushort4 bv = *(const ushort4*)(dtwt + (size_t)(colTile + ar) * DTRANK + kk);
    Bs[kk+0][ar] = bf2f(bv.x); Bs[kk+1][ar] = bf2f(bv.y);
    Bs[kk+2][ar] = bf2f(bv.z); Bs[kk+3][ar] = bf2f(bv.w);
  }
  __syncthreads();

  float acc[4][4] = {};
  #pragma unroll 8
  for (int k = 0; k < DTRANK; k++) {
    float4 a4 = *(const float4*)&As[k][ty*4];
    float4 b4 = *(const float4*)&Bs[k][tx*4];
    float a[4] = {a4.x, a4.y, a4.z, a4.w};
    float b[4] = {b4.x, b4.y, b4.z, b4.w};
    #pragma unroll
    for (int i = 0; i < 4; i++)
      #pragma unroll
      for (int j = 0; j < 4; j++)
        acc[i][j] += a[i] * b[j];
  }

  float4 bb = *(const float4*)(bias + colTile + tx*4);
  const float bvv[4] = {bb.x, bb.y, bb.z, bb.w};
  #pragma unroll
  for (int i = 0; i < 4; i++) {
    const int r = rowTile + ty*4 + i;
    ushort4 o;
    float vv[4];
    #pragma unroll
    for (int j = 0; j < 4; j++) {
      float v = acc[i][j] + bvv[j];
      vv[j] = (v > 20.f) ? v : log1pf(__expf(v));
    }
    o.x = f2bf(vv[0]); o.y = f2bf(vv[1]); o.z = f2bf(vv[2]); o.w = f2bf(vv[3]);
    *(ushort4*)(delta16 + (size_t)r * DINNER + colTile + tx*4) = o;
  }
}

// ---------------------------------------------------------------------------
// Conv (width 4) + SiLU: read bf16 xcb, write ub bf16 only.
// ---------------------------------------------------------------------------
__global__ __launch_bounds__(256) void conv_silu_k(
    const unsigned short* __restrict__ xcb,
    const float* __restrict__ conv_w,
    const float* __restrict__ conv_b,
    unsigned short* __restrict__ ub)
{
  const int idx = blockIdx.x * 256 + threadIdx.x;
  if (idx >= NROW * DINNER) return;
  const int d = idx & (DINNER - 1);
  const int row = idx >> 11;
  const int l = row & (SEQL - 1);
  float acc = conv_b[d];
  #pragma unroll
  for (int k = 0; k < DCONV; k++) {
    const int ls = l + k - (DCONV - 1);
    if (ls >= 0)
      acc += bf2f(xcb[(size_t)(row + k - (DCONV - 1)) * DINNER + d]) * conv_w[d*DCONV + k];
  }
  const float v = acc * sigmoidf_(acc);
  ub[idx] = f2bf(v);
}

// ---------------------------------------------------------------------------
// Scan (R11-proven register-state version).
// ---------------------------------------------------------------------------
__global__ __launch_bounds__(256) void scan_a(
    const unsigned short* __restrict__ delta16,
    const unsigned short* __restrict__ ub,
    const float* __restrict__ xdbl,
    const float* __restrict__ A_log,
    float* __restrict__ S, float* __restrict__ sumd_g)
{
  const int bx = blockIdx.x;
  const int c  = bx & (NCH2-1);
  const int dg = (bx >> 6) & 7;
  const int b  = bx >> 9;
  const int d = dg * 256 + threadIdx.x;
  const size_t row0 = (size_t)(b*SEQL + c*CL2);

  __shared__ float bc_s[CL2][32];
  if (threadIdx.x < 128) {
    const int t = threadIdx.x >> 3;
    const int cc = (threadIdx.x & 7) * 4;
    *(float4*)&bc_s[t][cc] = *(const float4*)&xdbl[(row0 + t)*NPROJ + DTRANK + cc];
  }

  float A2[16];
  #pragma unroll
  for (int i = 0; i < 4; i++) {
    float4 al = *(const float4*)&A_log[(size_t)d*DSTATE + i*4];
    A2[i*4+0] = -__expf(al.x)*LOG2E; A2[i*4+1] = -__expf(al.y)*LOG2E;
    A2[i*4+2] = -__expf(al.z)*LOG2E; A2[i*4+3] = -__expf(al.w)*LOG2E;
  }

  float dlt[CL2], uu[CL2];
  #pragma unroll
  for (int t = 0; t < CL2; t++) {
    dlt[t] = bf2f(delta16[(row0 + t)*DINNER + d]);
    uu[t]  = bf2f(ub[(row0 + t)*DINNER + d]);
  }
  __syncthreads();

  float h[16];
  #pragma unroll
  for (int n = 0; n < 16; n++) h[n] = 0.f;
  float sd = 0.f;

  #pragma unroll
  for (int t = 0; t < CL2; t++) {
    const float du = dlt[t] * uu[t];
    sd += dlt[t];
    f32x4 bq[4];
    #pragma unroll
    for (int i = 0; i < 4; i++) bq[i] = *(const f32x4*)&bc_s[t][i*4];
    #pragma unroll
    for (int n = 0; n < 16; n++) {
      const float a = fexp2(dlt[t] * A2[n]);
      h[n] = a * h[n] + du * bq[n>>2][n&3];
    }
  }

  const size_t base = ((size_t)(b*NCH2 + c) * DINNER + d) * DSTATE;
  #pragma unroll
  for (int i = 0; i < 4; i++) {
    f32x4 hv; hv[0]=h[i*4+0]; hv[1]=h[i*4+1]; hv[2]=h[i*4+2]; hv[3]=h[i*4+3];
    *(f32x4*)&S[base + i*4] = hv;
  }
  sumd_g[(size_t)(b*NCH2 + c) * DINNER + d] = sd;
}

__global__ __launch_bounds__(256) void scan_b(
    const float* __restrict__ S, const float* __restrict__ sumd_g,
    const float* __restrict__ A_log, float* __restrict__ H)
{
  const int idx = blockIdx.x * 256 + threadIdx.x;   // (b,d,n): 65536
  const int n = idx & 15, d = (idx >> 4) & (DINNER-1), b = idx >> 15;
  const float A2 = -__expf(A_log[(size_t)d*DSTATE + n]) * LOG2E;
  float h = 0.f;
  for (int c = 0; c < NCH2; c++) {
    const size_t pos = ((size_t)(b*NCH2 + c) * DINNER + d) * DSTATE + n;
    const float sd = sumd_g[(size_t)(b*NCH2 + c) * DINNER + d];
    H[pos] = h;
    h = fexp2(A2 * sd) * h + S[pos];
  }
}

__global__ __launch_bounds__(256) void scan_c(
    const unsigned short* __restrict__ delta16,
    const unsigned short* __restrict__ ub,
    const unsigned short* __restrict__ zb,
    const float* __restrict__ xdbl,
    const float* __restrict__ A_log,
    const float* __restrict__ Dp,
    const float* __restrict__ H,
    unsigned short* __restrict__ Y)
{
  const int bx = blockIdx.x;
  const int c  = bx & (NCH2-1);
  const int dg = (bx >> 6) & 7;
  const int b  = bx >> 9;
  const int d = dg * 256 + threadIdx.x;
  const size_t row0 = (size_t)(b*SEQL + c*CL2);

  __shared__ float bc_s[CL2][32];
  if (threadIdx.x < 128) {
    const int t = threadIdx.x >> 3;
    const int cc = (threadIdx.x & 7) * 4;
    *(float4*)&bc_s[t][cc] = *(const float4*)&xdbl[(row0 + t)*NPROJ + DTRANK + cc];
  }

  float A2[16];
  #pragma unroll
  for (int i = 0; i < 4; i++) {
    float4 al = *(const float4*)&A_log[(size_t)d*DSTATE + i*4];
    A2[i*4+0] = -__expf(al.x)*LOG2E; A2[i*4+1] = -__expf(al.y)*LOG2E;
    A2[i*4+2] = -__expf(al.z)*LOG2E; A2[i*4+3] = -__expf(al.w)*LOG2E;
  }
  const float Dval = Dp[d];

  float dlt[CL2], uu[CL2], zz[CL2];
  #pragma unroll
  for (int t = 0; t < CL2; t++) {
    dlt[t] = bf2f(delta16[(row0 + t)*DINNER + d]);
    uu[t]  = bf2f(ub[(row0 + t)*DINNER + d]);
    zz[t]  = bf2f(zb[(row0 + t)*DINNER + d]);
  }

  float h[16];
  {
    const size_t hb = ((size_t)(b*NCH2 + c) * DINNER + d) * DSTATE;
    #pragma unroll
    for (int i = 0; i < 4; i++) {
      f32x4 hv = *(const f32x4*)&H[hb + i*4];
      h[i*4+0]=hv[0]; h[i*4+1]=hv[1]; h[i*4+2]=hv[2]; h[i*4+3]=hv[3];
    }
  }
  __syncthreads();

  #pragma unroll
  for (int t = 0; t < CL2; t++) {
    const float du = dlt[t] * uu[t];
    f32x4 bq[4], cq[4];
    #pragma unroll
    for (int i = 0; i < 4; i++) {
      bq[i] = *(const f32x4*)&bc_s[t][i*4];
      cq[i] = *(const f32x4*)&bc_s[t][16 + i*4];
    }
    float y = 0.f;
    #pragma unroll
    for (int n = 0; n < 16; n++) {
      const float a = fexp2(dlt[t] * A2[n]);
      h[n] = a * h[n] + du * bq[n>>2][n&3];
      y += h[n] * cq[n>>2][n&3];
    }
    const float yy = (y + uu[t]*Dval) * (zz[t] * sigmoidf_(zz[t]));
    Y[(row0 + t)*DINNER + d] = f2bf(yy);
  }
}

// ---------------------------------------------------------------------------
extern "C" void kernel_launch(void* const* d_in, const int* in_sizes, int n_in,
                              void* d_out, int out_size, void* d_ws, size_t ws_size,
                              hipStream_t stream) {
  const float* x         = (const float*)d_in[0];
  const float* in_proj_w = (const float*)d_in[2];
  const float* conv_w    = (const float*)d_in[3];
  const float* conv_b    = (const float*)d_in[4];
  const float* x_proj_w  = (const float*)d_in[5];
  const float* dt_proj_w = (const float*)d_in[6];
  const float* dt_proj_b = (const float*)d_in[7];
  const float* A_log     = (const float*)d_in[8];
  const float* Dp        = (const float*)d_in[9];
  const float* out_proj_w= (const float*)d_in[10];
  float* out = (float*)d_out;

  // ws: 256 MiB. Regions (only xcb/yb share [0,8.4M), sequentially dead):
  char* B = (char*)d_ws;
  unsigned short* xcb  = (unsigned short*)B;          // [0, 8.4M) GEMM1 out
  unsigned short* yb   = (unsigned short*)B;          // scan_c out (xcb dead)
  float* xdbl = (float*)(B + (34ll<<20));             // 0.79M (atomic target)
  unsigned short* delta16 = (unsigned short*)(B + (35ll<<20));
  unsigned short* w1t  = (unsigned short*)(B + (44ll<<20));
  unsigned short* w4t  = (unsigned short*)(B + (53ll<<20));
  unsigned short* dtwt = (unsigned short*)(B + (58ll<<20));
  unsigned short* xb   = (unsigned short*)(B + (59ll<<20));
  unsigned short* xpwt = (unsigned short*)(B + (64ll<<20));  // 128x2048 bf16
  float* S2   = (float*)(B + (72ll<<20));
  float* H2   = (float*)(B + (90ll<<20));
  float* sumd = (float*)(B + (108ll<<20));
  unsigned short* zb = (unsigned short*)(B + (110ll<<20));
  unsigned short* ub = (unsigned short*)(B + (119ll<<20));

  dim3 blk(256);

  // zero atomic targets (memset nodes; required every call — re-poisoned)
  hipMemsetAsync(xdbl, 0, (size_t)NROW * NPROJ * 4, stream);
  hipMemsetAsync(out, 0, (size_t)NROW * DIMX * 4, stream);

  // fused prep: cast x, transpose+cast w1/w4/dtw/xpw (+pad)
  prep_k<<<dim3(2048 + 4096 + 2048 + 128 + 192 + 64), blk, 0, stream>>>(
      x, xb, in_proj_w, w1t, out_proj_w, w4t, dt_proj_w, dtwt, x_proj_w, xpwt);

  // GEMM1 (MFMA): [xcb|zb] = x @ in_proj_w, bf16 out
  gemm1_bf2_k<<<dim3((2*DINNER)/128, NROW/128), blk, 0, stream>>>(
      xb, DIMX, w1t, DIMX, xcb, zb, DINNER, DINNER, DIMX);

  // conv + silu -> ub bf16
  conv_silu_k<<<(NROW*DINNER)/256, blk, 0, stream>>>(xcb, conv_w, conv_b, ub);

  // GEMM2 (MFMA, split-K 16, atomic) -> xdbl
  gemm2_k<<<dim3(NROW/128, G2SPLIT), blk, 0, stream>>>(ub, xpwt, xdbl);

  // GEMM3 (VALU): delta16 = softplus(dtr @ dtwt^T + b), bf16
  gemm3_k<<<dim3(DINNER/64, NROW/64), blk, 0, stream>>>(
      xdbl, dtwt, dt_proj_b, delta16);

  // chunked selective scan
  scan_a<<<dim3(BSZ*NCH2*8), blk, 0, stream>>>(delta16, ub, xdbl, A_log, S2, sumd);
  scan_b<<<dim3((BSZ*DINNER*DSTATE)/256), blk, 0, stream>>>(S2, sumd, A_log, H2);
  scan_c<<<dim3(BSZ*NCH2*8), blk, 0, stream>>>(
      delta16, ub, zb, xdbl, A_log, Dp, H2, yb);

  // GEMM4 (MFMA, split-K 4, atomic) -> out
  gemm4_k<<<dim3(DIMX/128, NROW/128, G4SPLIT), blk, 0, stream>>>(yb, w4t, out);
}

// Round 13
// 265.105 us; speedup vs baseline: 1.3631x; 1.0432x over previous
//
#include <hip/hip_runtime.h>
#include <hip/hip_bf16.h>

#define DIMX 1024
#define DSTATE 16
#define DCONV 4
#define DINNER 2048
#define DTRANK 64
#define BSZ 2
#define SEQL 1024
#define NROW (BSZ*SEQL)              // 2048
#define NPROJ (DTRANK + 2*DSTATE)    // 96
#define NCH2 64                      // scan chunks
#define CL2 16                       // chunk length (SEQL/NCH2)
#define G2SPLIT 16                   // GEMM2 split-K factor
#define G2KLEN (DINNER / G2SPLIT)    // 128
#define G4SPLIT 4                    // GEMM4 split-K factor

typedef __bf16 bf16x8 __attribute__((ext_vector_type(8)));
typedef float f32x4 __attribute__((ext_vector_type(4)));
typedef unsigned short ushort8_t __attribute__((ext_vector_type(8)));

#define LOG2E 1.44269504088896340736f

__device__ __forceinline__ float sigmoidf_(float x){ return 1.0f/(1.0f+__expf(-x)); }
__device__ __forceinline__ float fexp2(float x){ return __builtin_amdgcn_exp2f(x); }
__device__ __forceinline__ unsigned short f2bf(float f){
  union { float f; unsigned int i; } c; c.f = f;
  unsigned int r = (c.i + 0x7FFFu + ((c.i >> 16) & 1u)) >> 16;
  return (unsigned short)r;
}
__device__ __forceinline__ float bf2f(unsigned short u){
  union { unsigned int i; float f; } c; c.i = ((unsigned int)u) << 16; return c.f;
}

// async global->LDS, 16 B per lane; LDS dest = base + lane*16 (wave-uniform base)
__device__ __forceinline__ void gload16(const void* g, void* l){
  __builtin_amdgcn_global_load_lds(
      (const __attribute__((address_space(1))) unsigned int*)g,
      (__attribute__((address_space(3))) unsigned int*)l, 16, 0, 0);
}

// ---------------------------------------------------------------------------
// Fused prep (grid-sectioned) — unchanged from R12.
// ---------------------------------------------------------------------------
__global__ __launch_bounds__(256) void prep_k(
    const float* __restrict__ x, unsigned short* __restrict__ xb,
    const float* __restrict__ w1, unsigned short* __restrict__ w1t,
    const float* __restrict__ w4, unsigned short* __restrict__ w4t,
    const float* __restrict__ dtw, unsigned short* __restrict__ dtwt,
    const float* __restrict__ xpw, unsigned short* __restrict__ xpwt)
{
  __shared__ unsigned short T[32][33];
  int blk = blockIdx.x;
  if (blk < 2048) {                      // cast
    const int i = blk*256 + threadIdx.x;
    float4 v = *(const float4*)(x + (size_t)i * 4);
    ushort4 o;
    o.x = f2bf(v.x); o.y = f2bf(v.y); o.z = f2bf(v.z); o.w = f2bf(v.w);
    *(ushort4*)(xb + (size_t)i * 4) = o;
    return;
  }
  blk -= 2048;
  if (blk >= 6464) {                     // zero-pad xpwt rows 96..127
    blk -= 6464;
    const int i = blk*256 + threadIdx.x; // 16384 ushort4 total
    *(ushort4*)(xpwt + (size_t)96*DINNER + (size_t)i*4) = make_ushort4(0,0,0,0);
    return;
  }
  const float* w; unsigned short* wt; int K, N, nT, kT;
  if (blk < 4096) {                      // w1t: N=4096,K=1024 grid 128x32
    w = w1; wt = w1t; K = 1024; N = 4096;
    nT = (blk & 127) * 32; kT = (blk >> 7) * 32;
  } else if (blk < 6144) {               // w4t: N=1024,K=2048 grid 32x64
    blk -= 4096;
    w = w4; wt = w4t; K = 2048; N = 1024;
    nT = (blk & 31) * 32; kT = (blk >> 5) * 32;
  } else if (blk < 6272) {               // dtwt: N=2048,K=64 grid 64x2
    blk -= 6144;
    w = dtw; wt = dtwt; K = 64; N = 2048;
    nT = (blk & 63) * 32; kT = (blk >> 6) * 32;
  } else {                               // xpwt: N=96,K=2048 grid 3x64
    blk -= 6272;
    w = xpw; wt = xpwt; K = 2048; N = 96;
    nT = (blk % 3) * 32; kT = (blk / 3) * 32;
  }
  const int tx = threadIdx.x & 31, ty = threadIdx.x >> 5;
  #pragma unroll
  for (int i = 0; i < 4; i++)
    T[tx][ty + i*8] = f2bf(w[(size_t)(kT + ty + i*8) * N + nT + tx]);
  __syncthreads();
  #pragma unroll
  for (int i = 0; i < 4; i++)
    wt[(size_t)(nT + ty + i*8) * K + kT + tx] = T[ty + i*8][tx];
}

// ---------------------------------------------------------------------------
// GEMM1 (bf16 dual-output, BK2 superstep): one barrier pair per 64 K.
// Two 32-wide K-blocks staged into separate LDS buffers (proven 64-B rows),
// 8 global_load_lds in flight per wave, 32 MFMAs per superstep.
// MFMA order along K unchanged -> bitwise-identical accumulation.
// ---------------------------------------------------------------------------
__global__ __launch_bounds__(256) void gemm1_bf2_k(
    const unsigned short* __restrict__ A, int lda,
    const unsigned short* __restrict__ BT, int ldb,
    unsigned short* __restrict__ X0, unsigned short* __restrict__ X1,
    int splitN, int ldc, int K)
{
  constexpr int BM = 128, BN = 128, BK = 32;
  __shared__ unsigned short As[2][BM*BK];
  __shared__ unsigned short Bs[2][BN*BK];

  const int tid = threadIdx.x;
  const int w = tid >> 6, lane = tid & 63;
  const int quad = lane >> 4, lrow = lane & 15;
  const int mOff = (w & 1) * 64, nOff = (w >> 1) * 64;
  const int rowTile = blockIdx.y * BM, colTile = blockIdx.x * BN;

  f32x4 acc[4][4] = {};

  const int srow = lane >> 2;
  const int sbyte = (lane & 3) * 16;

  for (int k0 = 0; k0 < K; k0 += 2*BK) {
    #pragma unroll
    for (int hh = 0; hh < 2; hh++) {
      const int kk = k0 + hh*BK;
      const char* aSrc = (const char*)(A  + (size_t)(rowTile + w*32 + srow)*lda + kk) + sbyte;
      const char* bSrc = (const char*)(BT + (size_t)(colTile + w*32 + srow)*ldb + kk) + sbyte;
      gload16(aSrc,                    &As[hh][(w*32     )*32]);
      gload16(aSrc + 16*(size_t)lda*2, &As[hh][(w*32 + 16)*32]);
      gload16(bSrc,                    &Bs[hh][(w*32     )*32]);
      gload16(bSrc + 16*(size_t)ldb*2, &Bs[hh][(w*32 + 16)*32]);
    }
    __syncthreads();

    #pragma unroll
    for (int hh = 0; hh < 2; hh++) {
      bf16x8 af[4], bfr[4];
      #pragma unroll
      for (int mi = 0; mi < 4; mi++)
        af[mi] = *(const bf16x8*)&As[hh][(mOff + mi*16 + lrow)*32 + quad*8];
      #pragma unroll
      for (int ni = 0; ni < 4; ni++)
        bfr[ni] = *(const bf16x8*)&Bs[hh][(nOff + ni*16 + lrow)*32 + quad*8];
      #pragma unroll
      for (int mi = 0; mi < 4; mi++)
        #pragma unroll
        for (int ni = 0; ni < 4; ni++)
          acc[mi][ni] = __builtin_amdgcn_mfma_f32_16x16x32_bf16(
              af[mi], bfr[ni], acc[mi][ni], 0, 0, 0);
    }
    __syncthreads();
  }

  #pragma unroll
  for (int mi = 0; mi < 4; mi++) {
    #pragma unroll
    for (int ni = 0; ni < 4; ni++) {
      const int row = rowTile + mOff + mi*16 + quad*4;
      const int col = colTile + nOff + ni*16 + lrow;
      unsigned short* Cb = (col < splitN) ? X0 : X1;
      const int cc = (col < splitN) ? col : col - splitN;
      #pragma unroll
      for (int r = 0; r < 4; r++)
        Cb[(size_t)(row + r) * ldc + cc] = f2bf(acc[mi][ni][r]);
    }
  }
}

// ---------------------------------------------------------------------------
// GEMM2 (MFMA, split-K 16, atomic epilogue) — unchanged from R12.
// ---------------------------------------------------------------------------
__global__ __launch_bounds__(256) void gemm2_k(
    const unsigned short* __restrict__ A,    // ub: NROW x DINNER bf16
    const unsigned short* __restrict__ BT,   // xpwt: 128 x DINNER bf16
    float* __restrict__ xdbl)                // NROW x 96 f32 (atomic)
{
  constexpr int BM = 128, BK = 32;
  __shared__ unsigned short As[BM*BK];
  __shared__ unsigned short Bs[128*BK];

  const int tid = threadIdx.x;
  const int w = tid >> 6, lane = tid & 63;
  const int quad = lane >> 4, lrow = lane & 15;
  const int mOff = (w & 1) * 64, nOff = (w >> 1) * 64;
  const int rowTile = blockIdx.x * BM;
  const int kBeg = blockIdx.y * G2KLEN;

  f32x4 acc[4][4] = {};

  const int srow = lane >> 2;
  const int sbyte = (lane & 3) * 16;
  unsigned short* aB0 = &As[(w*32     )*32];
  unsigned short* aB1 = &As[(w*32 + 16)*32];
  unsigned short* bB0 = &Bs[(w*32     )*32];
  unsigned short* bB1 = &Bs[(w*32 + 16)*32];

  for (int k0 = kBeg; k0 < kBeg + G2KLEN; k0 += BK) {
    const char* aSrc = (const char*)(A  + (size_t)(rowTile + w*32 + srow)*DINNER + k0) + sbyte;
    const char* bSrc = (const char*)(BT + (size_t)(w*32 + srow)*DINNER + k0) + sbyte;
    gload16(aSrc,                       aB0);
    gload16(aSrc + 16*(size_t)DINNER*2, aB1);
    gload16(bSrc,                       bB0);
    gload16(bSrc + 16*(size_t)DINNER*2, bB1);
    __syncthreads();

    bf16x8 af[4], bfr[4];
    #pragma unroll
    for (int mi = 0; mi < 4; mi++)
      af[mi] = *(const bf16x8*)&As[(mOff + mi*16 + lrow)*32 + quad*8];
    #pragma unroll
    for (int ni = 0; ni < 4; ni++)
      bfr[ni] = *(const bf16x8*)&Bs[(nOff + ni*16 + lrow)*32 + quad*8];
    #pragma unroll
    for (int mi = 0; mi < 4; mi++)
      #pragma unroll
      for (int ni = 0; ni < 4; ni++)
        acc[mi][ni] = __builtin_amdgcn_mfma_f32_16x16x32_bf16(
            af[mi], bfr[ni], acc[mi][ni], 0, 0, 0);
    __syncthreads();
  }

  #pragma unroll
  for (int mi = 0; mi < 4; mi++) {
    #pragma unroll
    for (int ni = 0; ni < 4; ni++) {
      const int row = rowTile + mOff + mi*16 + quad*4;
      const int col = nOff + ni*16 + lrow;
      if (col >= NPROJ) continue;
      #pragma unroll
      for (int r = 0; r < 4; r++)
        atomicAdd(xdbl + (size_t)(row + r) * NPROJ + col, acc[mi][ni][r]);
    }
  }
}

// ---------------------------------------------------------------------------
// GEMM4 (MFMA, split-K 4, atomic epilogue, BK2 superstep).
// ---------------------------------------------------------------------------
__global__ __launch_bounds__(256) void gemm4_k(
    const unsigned short* __restrict__ A,   // yb: NROW x DINNER bf16
    const unsigned short* __restrict__ BT,  // w4t: DIMX x DINNER bf16
    float* __restrict__ outp)               // NROW x DIMX f32 (atomic)
{
  constexpr int BM = 128, BN = 128, BK = 32;
  constexpr int KCH = DINNER / G4SPLIT;
  __shared__ unsigned short As[2][BM*BK];
  __shared__ unsigned short Bs[2][BN*BK];

  const int tid = threadIdx.x;
  const int w = tid >> 6, lane = tid & 63;
  const int quad = lane >> 4, lrow = lane & 15;
  const int mOff = (w & 1) * 64, nOff = (w >> 1) * 64;
  const int rowTile = blockIdx.y * BM, colTile = blockIdx.x * BN;
  const int kBeg = blockIdx.z * KCH;

  f32x4 acc[4][4] = {};

  const int srow = lane >> 2;
  const int sbyte = (lane & 3) * 16;

  for (int k0 = kBeg; k0 < kBeg + KCH; k0 += 2*BK) {
    #pragma unroll
    for (int hh = 0; hh < 2; hh++) {
      const int kk = k0 + hh*BK;
      const char* aSrc = (const char*)(A  + (size_t)(rowTile + w*32 + srow)*DINNER + kk) + sbyte;
      const char* bSrc = (const char*)(BT + (size_t)(colTile + w*32 + srow)*DINNER + kk) + sbyte;
      gload16(aSrc,                       &As[hh][(w*32     )*32]);
      gload16(aSrc + 16*(size_t)DINNER*2, &As[hh][(w*32 + 16)*32]);
      gload16(bSrc,                       &Bs[hh][(w*32     )*32]);
      gload16(bSrc + 16*(size_t)DINNER*2, &Bs[hh][(w*32 + 16)*32]);
    }
    __syncthreads();

    #pragma unroll
    for (int hh = 0; hh < 2; hh++) {
      bf16x8 af[4], bfr[4];
      #pragma unroll
      for (int mi = 0; mi < 4; mi++)
        af[mi] = *(const bf16x8*)&As[hh][(mOff + mi*16 + lrow)*32 + quad*8];
      #pragma unroll
      for (int ni = 0; ni < 4; ni++)
        bfr[ni] = *(const bf16x8*)&Bs[hh][(nOff + ni*16 + lrow)*32 + quad*8];
      #pragma unroll
      for (int mi = 0; mi < 4; mi++)
        #pragma unroll
        for (int ni = 0; ni < 4; ni++)
          acc[mi][ni] = __builtin_amdgcn_mfma_f32_16x16x32_bf16(
              af[mi], bfr[ni], acc[mi][ni], 0, 0, 0);
    }
    __syncthreads();
  }

  #pragma unroll
  for (int mi = 0; mi < 4; mi++) {
    #pragma unroll
    for (int ni = 0; ni < 4; ni++) {
      const int row = rowTile + mOff + mi*16 + quad*4;
      const int col = colTile + nOff + ni*16 + lrow;
      #pragma unroll
      for (int r = 0; r < 4; r++)
        atomicAdd(outp + (size_t)(row + r) * DIMX + col, acc[mi][ni][r]);
    }
  }
}

// ---------------------------------------------------------------------------
// GEMM3 (VALU) — unchanged from R12.
// ---------------------------------------------------------------------------
__global__ __launch_bounds__(256) void gemm3_k(
    const float* __restrict__ xdbl,
    const unsigned short* __restrict__ dtwt,
    const float* __restrict__ bias,
    unsigned short* __restrict__ delta16)
{
  __shared__ float As[64][68];
  __shared__ float Bs[64][68];
  const int tid = threadIdx.x;
  const int tx = tid & 15, ty = tid >> 4;
  const int rowTile = blockIdx.y * 64;
  const int colTile = blockIdx.x * 64;

  const int ar = tid >> 2;
  const int ak = (tid & 3) * 4;

  #pragma unroll
  for (int kc = 0; kc < 4; kc++) {
    const int kk = kc*16 + ak;
    float4 av = *(const float4*)(xdbl + (size_t)(rowTile + ar) * NPROJ + kk);
    As[kk+0][ar] = av.x; As[kk+1][ar] = av.y;
    As[kk+2][ar] = av.z; As[kk+3][ar] = av.w;
    ushort4 bv = *(const ushort4*)(dtwt + (size_t)(colTile + ar) * DTRANK + kk);
    Bs[kk+0][ar] = bf2f(bv.x); Bs[kk+1][ar] = bf2f(bv.y);
    Bs[kk+2][ar] = bf2f(bv.z); Bs[kk+3][ar] = bf2f(bv.w);
  }
  __syncthreads();

  float acc[4][4] = {};
  #pragma unroll 8
  for (int k = 0; k < DTRANK; k++) {
    float4 a4 = *(const float4*)&As[k][ty*4];
    float4 b4 = *(const float4*)&Bs[k][tx*4];
    float a[4] = {a4.x, a4.y, a4.z, a4.w};
    float b[4] = {b4.x, b4.y, b4.z, b4.w};
    #pragma unroll
    for (int i = 0; i < 4; i++)
      #pragma unroll
      for (int j = 0; j < 4; j++)
        acc[i][j] += a[i] * b[j];
  }

  float4 bb = *(const float4*)(bias + colTile + tx*4);
  const float bvv[4] = {bb.x, bb.y, bb.z, bb.w};
  #pragma unroll
  for (int i = 0; i < 4; i++) {
    const int r = rowTile + ty*4 + i;
    ushort4 o;
    float vv[4];
    #pragma unroll
    for (int j = 0; j < 4; j++) {
      float v = acc[i][j] + bvv[j];
      vv[j] = (v > 20.f) ? v : log1pf(__expf(v));
    }
    o.x = f2bf(vv[0]); o.y = f2bf(vv[1]); o.z = f2bf(vv[2]); o.w = f2bf(vv[3]);
    *(ushort4*)(delta16 + (size_t)r * DINNER + colTile + tx*4) = o;
  }
}

// ---------------------------------------------------------------------------
// Conv (width 4) + SiLU, vectorized: 4 channels per thread, ushort4 I/O.
// ---------------------------------------------------------------------------
__global__ __launch_bounds__(256) void conv_silu_k(
    const unsigned short* __restrict__ xcb,
    const float* __restrict__ conv_w,
    const float* __restrict__ conv_b,
    unsigned short* __restrict__ ub)
{
  const int idx = blockIdx.x * 256 + threadIdx.x;   // over NROW*DINNER/4
  const int d4 = (idx & (DINNER/4 - 1)) * 4;
  const int row = idx >> 9;
  const int l = row & (SEQL - 1);

  float4 cb = *(const float4*)(conv_b + d4);
  float acc[4] = {cb.x, cb.y, cb.z, cb.w};
  float4 w0 = *(const float4*)(conv_w + (size_t)(d4+0)*4);
  float4 w1 = *(const float4*)(conv_w + (size_t)(d4+1)*4);
  float4 w2 = *(const float4*)(conv_w + (size_t)(d4+2)*4);
  float4 w3 = *(const float4*)(conv_w + (size_t)(d4+3)*4);
  const float* wp[4] = {(const float*)&w0, (const float*)&w1,
                        (const float*)&w2, (const float*)&w3};
  #pragma unroll
  for (int k = 0; k < DCONV; k++) {
    const int ls = l + k - (DCONV - 1);
    if (ls >= 0) {
      ushort4 xv = *(const ushort4*)(xcb + (size_t)(row + k - (DCONV - 1)) * DINNER + d4);
      acc[0] += bf2f(xv.x) * wp[0][k];
      acc[1] += bf2f(xv.y) * wp[1][k];
      acc[2] += bf2f(xv.z) * wp[2][k];
      acc[3] += bf2f(xv.w) * wp[3][k];
    }
  }
  ushort4 o;
  o.x = f2bf(acc[0] * sigmoidf_(acc[0]));
  o.y = f2bf(acc[1] * sigmoidf_(acc[1]));
  o.z = f2bf(acc[2] * sigmoidf_(acc[2]));
  o.w = f2bf(acc[3] * sigmoidf_(acc[3]));
  *(ushort4*)(ub + (size_t)row * DINNER + d4) = o;
}

// ---------------------------------------------------------------------------
// Scan (R11/R12-proven register-state version) — unchanged.
// ---------------------------------------------------------------------------
__global__ __launch_bounds__(256) void scan_a(
    const unsigned short* __restrict__ delta16,
    const unsigned short* __restrict__ ub,
    const float* __restrict__ xdbl,
    const float* __restrict__ A_log,
    float* __restrict__ S, float* __restrict__ sumd_g)
{
  const int bx = blockIdx.x;
  const int c  = bx & (NCH2-1);
  const int dg = (bx >> 6) & 7;
  const int b  = bx >> 9;
  const int d = dg * 256 + threadIdx.x;
  const size_t row0 = (size_t)(b*SEQL + c*CL2);

  __shared__ float bc_s[CL2][32];
  if (threadIdx.x < 128) {
    const int t = threadIdx.x >> 3;
    const int cc = (threadIdx.x & 7) * 4;
    *(float4*)&bc_s[t][cc] = *(const float4*)&xdbl[(row0 + t)*NPROJ + DTRANK + cc];
  }

  float A2[16];
  #pragma unroll
  for (int i = 0; i < 4; i++) {
    float4 al = *(const float4*)&A_log[(size_t)d*DSTATE + i*4];
    A2[i*4+0] = -__expf(al.x)*LOG2E; A2[i*4+1] = -__expf(al.y)*LOG2E;
    A2[i*4+2] = -__expf(al.z)*LOG2E; A2[i*4+3] = -__expf(al.w)*LOG2E;
  }

  float dlt[CL2], uu[CL2];
  #pragma unroll
  for (int t = 0; t < CL2; t++) {
    dlt[t] = bf2f(delta16[(row0 + t)*DINNER + d]);
    uu[t]  = bf2f(ub[(row0 + t)*DINNER + d]);
  }
  __syncthreads();

  float h[16];
  #pragma unroll
  for (int n = 0; n < 16; n++) h[n] = 0.f;
  float sd = 0.f;

  #pragma unroll
  for (int t = 0; t < CL2; t++) {
    const float du = dlt[t] * uu[t];
    sd += dlt[t];
    f32x4 bq[4];
    #pragma unroll
    for (int i = 0; i < 4; i++) bq[i] = *(const f32x4*)&bc_s[t][i*4];
    #pragma unroll
    for (int n = 0; n < 16; n++) {
      const float a = fexp2(dlt[t] * A2[n]);
      h[n] = a * h[n] + du * bq[n>>2][n&3];
    }
  }

  const size_t base = ((size_t)(b*NCH2 + c) * DINNER + d) * DSTATE;
  #pragma unroll
  for (int i = 0; i < 4; i++) {
    f32x4 hv; hv[0]=h[i*4+0]; hv[1]=h[i*4+1]; hv[2]=h[i*4+2]; hv[3]=h[i*4+3];
    *(f32x4*)&S[base + i*4] = hv;
  }
  sumd_g[(size_t)(b*NCH2 + c) * DINNER + d] = sd;
}

__global__ __launch_bounds__(256) void scan_b(
    const float* __restrict__ S, const float* __restrict__ sumd_g,
    const float* __restrict__ A_log, float* __restrict__ H)
{
  const int idx = blockIdx.x * 256 + threadIdx.x;   // (b,d,n): 65536
  const int n = idx & 15, d = (idx >> 4) & (DINNER-1), b = idx >> 15;
  const float A2 = -__expf(A_log[(size_t)d*DSTATE + n]) * LOG2E;
  float h = 0.f;
  for (int c = 0; c < NCH2; c++) {
    const size_t pos = ((size_t)(b*NCH2 + c) * DINNER + d) * DSTATE + n;
    const float sd = sumd_g[(size_t)(b*NCH2 + c) * DINNER + d];
    H[pos] = h;
    h = fexp2(A2 * sd) * h + S[pos];
  }
}

__global__ __launch_bounds__(256) void scan_c(
    const unsigned short* __restrict__ delta16,
    const unsigned short* __restrict__ ub,
    const unsigned short* __restrict__ zb,
    const float* __restrict__ xdbl,
    const float* __restrict__ A_log,
    const float* __restrict__ Dp,
    const float* __restrict__ H,
    unsigned short* __restrict__ Y)
{
  const int bx = blockIdx.x;
  const int c  = bx & (NCH2-1);
  const int dg = (bx >> 6) & 7;
  const int b  = bx >> 9;
  const int d = dg * 256 + threadIdx.x;
  const size_t row0 = (size_t)(b*SEQL + c*CL2);

  __shared__ float bc_s[CL2][32];
  if (threadIdx.x < 128) {
    const int t = threadIdx.x >> 3;
    const int cc = (threadIdx.x & 7) * 4;
    *(float4*)&bc_s[t][cc] = *(const float4*)&xdbl[(row0 + t)*NPROJ + DTRANK + cc];
  }

  float A2[16];
  #pragma unroll
  for (int i = 0; i < 4; i++) {
    float4 al = *(const float4*)&A_log[(size_t)d*DSTATE + i*4];
    A2[i*4+0] = -__expf(al.x)*LOG2E; A2[i*4+1] = -__expf(al.y)*LOG2E;
    A2[i*4+2] = -__expf(al.z)*LOG2E; A2[i*4+3] = -__expf(al.w)*LOG2E;
  }
  const float Dval = Dp[d];

  float dlt[CL2], uu[CL2], zz[CL2];
  #pragma unroll
  for (int t = 0; t < CL2; t++) {
    dlt[t] = bf2f(delta16[(row0 + t)*DINNER + d]);
    uu[t]  = bf2f(ub[(row0 + t)*DINNER + d]);
    zz[t]  = bf2f(zb[(row0 + t)*DINNER + d]);
  }

  float h[16];
  {
    const size_t hb = ((size_t)(b*NCH2 + c) * DINNER + d) * DSTATE;
    #pragma unroll
    for (int i = 0; i < 4; i++) {
      f32x4 hv = *(const f32x4*)&H[hb + i*4];
      h[i*4+0]=hv[0]; h[i*4+1]=hv[1]; h[i*4+2]=hv[2]; h[i*4+3]=hv[3];
    }
  }
  __syncthreads();

  #pragma unroll
  for (int t = 0; t < CL2; t++) {
    const float du = dlt[t] * uu[t];
    f32x4 bq[4], cq[4];
    #pragma unroll
    for (int i = 0; i < 4; i++) {
      bq[i] = *(const f32x4*)&bc_s[t][i*4];
      cq[i] = *(const f32x4*)&bc_s[t][16 + i*4];
    }
    float y = 0.f;
    #pragma unroll
    for (int n = 0; n < 16; n++) {
      const float a = fexp2(dlt[t] * A2[n]);
      h[n] = a * h[n] + du * bq[n>>2][n&3];
      y += h[n] * cq[n>>2][n&3];
    }
    const float yy = (y + uu[t]*Dval) * (zz[t] * sigmoidf_(zz[t]));
    Y[(row0 + t)*DINNER + d] = f2bf(yy);
  }
}

// ---------------------------------------------------------------------------
extern "C" void kernel_launch(void* const* d_in, const int* in_sizes, int n_in,
                              void* d_out, int out_size, void* d_ws, size_t ws_size,
                              hipStream_t stream) {
  const float* x         = (const float*)d_in[0];
  const float* in_proj_w = (const float*)d_in[2];
  const float* conv_w    = (const float*)d_in[3];
  const float* conv_b    = (const float*)d_in[4];
  const float* x_proj_w  = (const float*)d_in[5];
  const float* dt_proj_w = (const float*)d_in[6];
  const float* dt_proj_b = (const float*)d_in[7];
  const float* A_log     = (const float*)d_in[8];
  const float* Dp        = (const float*)d_in[9];
  const float* out_proj_w= (const float*)d_in[10];
  float* out = (float*)d_out;

  // ws: 256 MiB. Regions (only xcb/yb share [0,8.4M), sequentially dead):
  char* B = (char*)d_ws;
  unsigned short* xcb  = (unsigned short*)B;          // [0, 8.4M) GEMM1 out
  unsigned short* yb   = (unsigned short*)B;          // scan_c out (xcb dead)
  float* xdbl = (float*)(B + (34ll<<20));             // 0.79M (atomic target)
  unsigned short* delta16 = (unsigned short*)(B + (35ll<<20));
  unsigned short* w1t  = (unsigned short*)(B + (44ll<<20));
  unsigned short* w4t  = (unsigned short*)(B + (53ll<<20));
  unsigned short* dtwt = (unsigned short*)(B + (58ll<<20));
  unsigned short* xb   = (unsigned short*)(B + (59ll<<20));
  unsigned short* xpwt = (unsigned short*)(B + (64ll<<20));  // 128x2048 bf16
  float* S2   = (float*)(B + (72ll<<20));
  float* H2   = (float*)(B + (90ll<<20));
  float* sumd = (float*)(B + (108ll<<20));
  unsigned short* zb = (unsigned short*)(B + (110ll<<20));
  unsigned short* ub = (unsigned short*)(B + (119ll<<20));

  dim3 blk(256);

  // zero atomic targets (memset nodes; required every call — re-poisoned)
  hipMemsetAsync(xdbl, 0, (size_t)NROW * NPROJ * 4, stream);
  hipMemsetAsync(out, 0, (size_t)NROW * DIMX * 4, stream);

  // fused prep: cast x, transpose+cast w1/w4/dtw/xpw (+pad)
  prep_k<<<dim3(2048 + 4096 + 2048 + 128 + 192 + 64), blk, 0, stream>>>(
      x, xb, in_proj_w, w1t, out_proj_w, w4t, dt_proj_w, dtwt, x_proj_w, xpwt);

  // GEMM1 (MFMA, BK2 superstep): [xcb|zb] = x @ in_proj_w, bf16 out
  gemm1_bf2_k<<<dim3((2*DINNER)/128, NROW/128), blk, 0, stream>>>(
      xb, DIMX, w1t, DIMX, xcb, zb, DINNER, DINNER, DIMX);

  // conv + silu -> ub bf16 (vectorized)
  conv_silu_k<<<(NROW*DINNER/4)/256, blk, 0, stream>>>(xcb, conv_w, conv_b, ub);

  // GEMM2 (MFMA, split-K 16, atomic) -> xdbl
  gemm2_k<<<dim3(NROW/128, G2SPLIT), blk, 0, stream>>>(ub, xpwt, xdbl);

  // GEMM3 (VALU): delta16 = softplus(dtr @ dtwt^T + b), bf16
  gemm3_k<<<dim3(DINNER/64, NROW/64), blk, 0, stream>>>(
      xdbl, dtwt, dt_proj_b, delta16);

  // chunked selective scan
  scan_a<<<dim3(BSZ*NCH2*8), blk, 0, stream>>>(delta16, ub, xdbl, A_log, S2, sumd);
  scan_b<<<dim3((BSZ*DINNER*DSTATE)/256), blk, 0, stream>>>(S2, sumd, A_log, H2);
  scan_c<<<dim3(BSZ*NCH2*8), blk, 0, stream>>>(
      delta16, ub, zb, xdbl, A_log, Dp, H2, yb);

  // GEMM4 (MFMA, split-K 4, atomic, BK2 superstep) -> out
  gemm4_k<<<dim3(DIMX/128, NROW/128, G4SPLIT), blk, 0, stream>>>(yb, w4t, out);
}

// Round 14
// 260.857 us; speedup vs baseline: 1.3853x; 1.0163x over previous
//
#include <hip/hip_runtime.h>
#include <hip/hip_bf16.h>

#define DIMX 1024
#define DSTATE 16
#define DCONV 4
#define DINNER 2048
#define DTRANK 64
#define BSZ 2
#define SEQL 1024
#define NROW (BSZ*SEQL)              // 2048
#define NPROJ (DTRANK + 2*DSTATE)    // 96
#define NCH2 64                      // scan chunks
#define CL2 16                       // chunk length (SEQL/NCH2)
#define G2SPLIT 16                   // GEMM2 split-K factor
#define G2KLEN (DINNER / G2SPLIT)    // 128
#define G4SPLIT 4                    // GEMM4 split-K factor

typedef __bf16 bf16x8 __attribute__((ext_vector_type(8)));
typedef float f32x4 __attribute__((ext_vector_type(4)));
typedef unsigned short ushort8_t __attribute__((ext_vector_type(8)));

#define LOG2E 1.44269504088896340736f

__device__ __forceinline__ float sigmoidf_(float x){ return 1.0f/(1.0f+__expf(-x)); }
__device__ __forceinline__ float fexp2(float x){ return __builtin_amdgcn_exp2f(x); }
__device__ __forceinline__ unsigned short f2bf(float f){
  union { float f; unsigned int i; } c; c.f = f;
  unsigned int r = (c.i + 0x7FFFu + ((c.i >> 16) & 1u)) >> 16;
  return (unsigned short)r;
}
__device__ __forceinline__ float bf2f(unsigned short u){
  union { unsigned int i; float f; } c; c.i = ((unsigned int)u) << 16; return c.f;
}

// async global->LDS, 16 B per lane; LDS dest = base + lane*16 (wave-uniform base)
__device__ __forceinline__ void gload16(const void* g, void* l){
  __builtin_amdgcn_global_load_lds(
      (const __attribute__((address_space(1))) unsigned int*)g,
      (__attribute__((address_space(3))) unsigned int*)l, 16, 0, 0);
}

// ---------------------------------------------------------------------------
// Fused prep (grid-sectioned) — unchanged from R12/R13.
// ---------------------------------------------------------------------------
__global__ __launch_bounds__(256) void prep_k(
    const float* __restrict__ x, unsigned short* __restrict__ xb,
    const float* __restrict__ w1, unsigned short* __restrict__ w1t,
    const float* __restrict__ w4, unsigned short* __restrict__ w4t,
    const float* __restrict__ dtw, unsigned short* __restrict__ dtwt,
    const float* __restrict__ xpw, unsigned short* __restrict__ xpwt)
{
  __shared__ unsigned short T[32][33];
  int blk = blockIdx.x;
  if (blk < 2048) {                      // cast
    const int i = blk*256 + threadIdx.x;
    float4 v = *(const float4*)(x + (size_t)i * 4);
    ushort4 o;
    o.x = f2bf(v.x); o.y = f2bf(v.y); o.z = f2bf(v.z); o.w = f2bf(v.w);
    *(ushort4*)(xb + (size_t)i * 4) = o;
    return;
  }
  blk -= 2048;
  if (blk >= 6464) {                     // zero-pad xpwt rows 96..127
    blk -= 6464;
    const int i = blk*256 + threadIdx.x; // 16384 ushort4 total
    *(ushort4*)(xpwt + (size_t)96*DINNER + (size_t)i*4) = make_ushort4(0,0,0,0);
    return;
  }
  const float* w; unsigned short* wt; int K, N, nT, kT;
  if (blk < 4096) {                      // w1t: N=4096,K=1024 grid 128x32
    w = w1; wt = w1t; K = 1024; N = 4096;
    nT = (blk & 127) * 32; kT = (blk >> 7) * 32;
  } else if (blk < 6144) {               // w4t: N=1024,K=2048 grid 32x64
    blk -= 4096;
    w = w4; wt = w4t; K = 2048; N = 1024;
    nT = (blk & 31) * 32; kT = (blk >> 5) * 32;
  } else if (blk < 6272) {               // dtwt: N=2048,K=64 grid 64x2
    blk -= 6144;
    w = dtw; wt = dtwt; K = 64; N = 2048;
    nT = (blk & 63) * 32; kT = (blk >> 6) * 32;
  } else {                               // xpwt: N=96,K=2048 grid 3x64
    blk -= 6272;
    w = xpw; wt = xpwt; K = 2048; N = 96;
    nT = (blk % 3) * 32; kT = (blk / 3) * 32;
  }
  const int tx = threadIdx.x & 31, ty = threadIdx.x >> 5;
  #pragma unroll
  for (int i = 0; i < 4; i++)
    T[tx][ty + i*8] = f2bf(w[(size_t)(kT + ty + i*8) * N + nT + tx]);
  __syncthreads();
  #pragma unroll
  for (int i = 0; i < 4; i++)
    wt[(size_t)(nT + ty + i*8) * K + kT + tx] = T[ty + i*8][tx];
}

// ---------------------------------------------------------------------------
// GEMM1 (bf16 dual-output, BK4 superstep): one barrier pair per 128 K.
// Four 32-wide K-blocks in 4 LDS buffers (64 KB; grid 2 blocks/CU -> 128 KB
// LDS/CU <= 160 KB, occupancy unchanged). 16 global_load_lds in flight/wave,
// 64 MFMAs per superstep. K-order unchanged -> bitwise-identical acc.
// ---------------------------------------------------------------------------
__global__ __launch_bounds__(256) void gemm1_bf2_k(
    const unsigned short* __restrict__ A, int lda,
    const unsigned short* __restrict__ BT, int ldb,
    unsigned short* __restrict__ X0, unsigned short* __restrict__ X1,
    int splitN, int ldc, int K)
{
  constexpr int BM = 128, BN = 128, BK = 32, NB = 4;
  __shared__ unsigned short As[NB][BM*BK];
  __shared__ unsigned short Bs[NB][BN*BK];

  const int tid = threadIdx.x;
  const int w = tid >> 6, lane = tid & 63;
  const int quad = lane >> 4, lrow = lane & 15;
  const int mOff = (w & 1) * 64, nOff = (w >> 1) * 64;
  const int rowTile = blockIdx.y * BM, colTile = blockIdx.x * BN;

  f32x4 acc[4][4] = {};

  const int srow = lane >> 2;
  const int sbyte = (lane & 3) * 16;

  for (int k0 = 0; k0 < K; k0 += NB*BK) {
    #pragma unroll
    for (int hh = 0; hh < NB; hh++) {
      const int kk = k0 + hh*BK;
      const char* aSrc = (const char*)(A  + (size_t)(rowTile + w*32 + srow)*lda + kk) + sbyte;
      const char* bSrc = (const char*)(BT + (size_t)(colTile + w*32 + srow)*ldb + kk) + sbyte;
      gload16(aSrc,                    &As[hh][(w*32     )*32]);
      gload16(aSrc + 16*(size_t)lda*2, &As[hh][(w*32 + 16)*32]);
      gload16(bSrc,                    &Bs[hh][(w*32     )*32]);
      gload16(bSrc + 16*(size_t)ldb*2, &Bs[hh][(w*32 + 16)*32]);
    }
    __syncthreads();

    #pragma unroll
    for (int hh = 0; hh < NB; hh++) {
      bf16x8 af[4], bfr[4];
      #pragma unroll
      for (int mi = 0; mi < 4; mi++)
        af[mi] = *(const bf16x8*)&As[hh][(mOff + mi*16 + lrow)*32 + quad*8];
      #pragma unroll
      for (int ni = 0; ni < 4; ni++)
        bfr[ni] = *(const bf16x8*)&Bs[hh][(nOff + ni*16 + lrow)*32 + quad*8];
      #pragma unroll
      for (int mi = 0; mi < 4; mi++)
        #pragma unroll
        for (int ni = 0; ni < 4; ni++)
          acc[mi][ni] = __builtin_amdgcn_mfma_f32_16x16x32_bf16(
              af[mi], bfr[ni], acc[mi][ni], 0, 0, 0);
    }
    __syncthreads();
  }

  #pragma unroll
  for (int mi = 0; mi < 4; mi++) {
    #pragma unroll
    for (int ni = 0; ni < 4; ni++) {
      const int row = rowTile + mOff + mi*16 + quad*4;
      const int col = colTile + nOff + ni*16 + lrow;
      unsigned short* Cb = (col < splitN) ? X0 : X1;
      const int cc = (col < splitN) ? col : col - splitN;
      #pragma unroll
      for (int r = 0; r < 4; r++)
        Cb[(size_t)(row + r) * ldc + cc] = f2bf(acc[mi][ni][r]);
    }
  }
}

// ---------------------------------------------------------------------------
// GEMM2 (MFMA, split-K 16, atomic epilogue, BK2 superstep).
// ---------------------------------------------------------------------------
__global__ __launch_bounds__(256) void gemm2_k(
    const unsigned short* __restrict__ A,    // ub: NROW x DINNER bf16
    const unsigned short* __restrict__ BT,   // xpwt: 128 x DINNER bf16
    float* __restrict__ xdbl)                // NROW x 96 f32 (atomic)
{
  constexpr int BM = 128, BK = 32;
  __shared__ unsigned short As[2][BM*BK];
  __shared__ unsigned short Bs[2][128*BK];

  const int tid = threadIdx.x;
  const int w = tid >> 6, lane = tid & 63;
  const int quad = lane >> 4, lrow = lane & 15;
  const int mOff = (w & 1) * 64, nOff = (w >> 1) * 64;
  const int rowTile = blockIdx.x * BM;
  const int kBeg = blockIdx.y * G2KLEN;

  f32x4 acc[4][4] = {};

  const int srow = lane >> 2;
  const int sbyte = (lane & 3) * 16;

  for (int k0 = kBeg; k0 < kBeg + G2KLEN; k0 += 2*BK) {
    #pragma unroll
    for (int hh = 0; hh < 2; hh++) {
      const int kk = k0 + hh*BK;
      const char* aSrc = (const char*)(A  + (size_t)(rowTile + w*32 + srow)*DINNER + kk) + sbyte;
      const char* bSrc = (const char*)(BT + (size_t)(w*32 + srow)*DINNER + kk) + sbyte;
      gload16(aSrc,                       &As[hh][(w*32     )*32]);
      gload16(aSrc + 16*(size_t)DINNER*2, &As[hh][(w*32 + 16)*32]);
      gload16(bSrc,                       &Bs[hh][(w*32     )*32]);
      gload16(bSrc + 16*(size_t)DINNER*2, &Bs[hh][(w*32 + 16)*32]);
    }
    __syncthreads();

    #pragma unroll
    for (int hh = 0; hh < 2; hh++) {
      bf16x8 af[4], bfr[4];
      #pragma unroll
      for (int mi = 0; mi < 4; mi++)
        af[mi] = *(const bf16x8*)&As[hh][(mOff + mi*16 + lrow)*32 + quad*8];
      #pragma unroll
      for (int ni = 0; ni < 4; ni++)
        bfr[ni] = *(const bf16x8*)&Bs[hh][(nOff + ni*16 + lrow)*32 + quad*8];
      #pragma unroll
      for (int mi = 0; mi < 4; mi++)
        #pragma unroll
        for (int ni = 0; ni < 4; ni++)
          acc[mi][ni] = __builtin_amdgcn_mfma_f32_16x16x32_bf16(
              af[mi], bfr[ni], acc[mi][ni], 0, 0, 0);
    }
    __syncthreads();
  }

  #pragma unroll
  for (int mi = 0; mi < 4; mi++) {
    #pragma unroll
    for (int ni = 0; ni < 4; ni++) {
      const int row = rowTile + mOff + mi*16 + quad*4;
      const int col = nOff + ni*16 + lrow;
      if (col >= NPROJ) continue;
      #pragma unroll
      for (int r = 0; r < 4; r++)
        atomicAdd(xdbl + (size_t)(row + r) * NPROJ + col, acc[mi][ni][r]);
    }
  }
}

// ---------------------------------------------------------------------------
// GEMM4 (MFMA, split-K 4, atomic epilogue, BK4 superstep).
// ---------------------------------------------------------------------------
__global__ __launch_bounds__(256) void gemm4_k(
    const unsigned short* __restrict__ A,   // yb: NROW x DINNER bf16
    const unsigned short* __restrict__ BT,  // w4t: DIMX x DINNER bf16
    float* __restrict__ outp)               // NROW x DIMX f32 (atomic)
{
  constexpr int BM = 128, BN = 128, BK = 32, NB = 4;
  constexpr int KCH = DINNER / G4SPLIT;
  __shared__ unsigned short As[NB][BM*BK];
  __shared__ unsigned short Bs[NB][BN*BK];

  const int tid = threadIdx.x;
  const int w = tid >> 6, lane = tid & 63;
  const int quad = lane >> 4, lrow = lane & 15;
  const int mOff = (w & 1) * 64, nOff = (w >> 1) * 64;
  const int rowTile = blockIdx.y * BM, colTile = blockIdx.x * BN;
  const int kBeg = blockIdx.z * KCH;

  f32x4 acc[4][4] = {};

  const int srow = lane >> 2;
  const int sbyte = (lane & 3) * 16;

  for (int k0 = kBeg; k0 < kBeg + KCH; k0 += NB*BK) {
    #pragma unroll
    for (int hh = 0; hh < NB; hh++) {
      const int kk = k0 + hh*BK;
      const char* aSrc = (const char*)(A  + (size_t)(rowTile + w*32 + srow)*DINNER + kk) + sbyte;
      const char* bSrc = (const char*)(BT + (size_t)(colTile + w*32 + srow)*DINNER + kk) + sbyte;
      gload16(aSrc,                       &As[hh][(w*32     )*32]);
      gload16(aSrc + 16*(size_t)DINNER*2, &As[hh][(w*32 + 16)*32]);
      gload16(bSrc,                       &Bs[hh][(w*32     )*32]);
      gload16(bSrc + 16*(size_t)DINNER*2, &Bs[hh][(w*32 + 16)*32]);
    }
    __syncthreads();

    #pragma unroll
    for (int hh = 0; hh < NB; hh++) {
      bf16x8 af[4], bfr[4];
      #pragma unroll
      for (int mi = 0; mi < 4; mi++)
        af[mi] = *(const bf16x8*)&As[hh][(mOff + mi*16 + lrow)*32 + quad*8];
      #pragma unroll
      for (int ni = 0; ni < 4; ni++)
        bfr[ni] = *(const bf16x8*)&Bs[hh][(nOff + ni*16 + lrow)*32 + quad*8];
      #pragma unroll
      for (int mi = 0; mi < 4; mi++)
        #pragma unroll
        for (int ni = 0; ni < 4; ni++)
          acc[mi][ni] = __builtin_amdgcn_mfma_f32_16x16x32_bf16(
              af[mi], bfr[ni], acc[mi][ni], 0, 0, 0);
    }
    __syncthreads();
  }

  #pragma unroll
  for (int mi = 0; mi < 4; mi++) {
    #pragma unroll
    for (int ni = 0; ni < 4; ni++) {
      const int row = rowTile + mOff + mi*16 + quad*4;
      const int col = colTile + nOff + ni*16 + lrow;
      #pragma unroll
      for (int r = 0; r < 4; r++)
        atomicAdd(outp + (size_t)(row + r) * DIMX + col, acc[mi][ni][r]);
    }
  }
}

// ---------------------------------------------------------------------------
// GEMM3 (VALU) — unchanged.
// ---------------------------------------------------------------------------
__global__ __launch_bounds__(256) void gemm3_k(
    const float* __restrict__ xdbl,
    const unsigned short* __restrict__ dtwt,
    const float* __restrict__ bias,
    unsigned short* __restrict__ delta16)
{
  __shared__ float As[64][68];
  __shared__ float Bs[64][68];
  const int tid = threadIdx.x;
  const int tx = tid & 15, ty = tid >> 4;
  const int rowTile = blockIdx.y * 64;
  const int colTile = blockIdx.x * 64;

  const int ar = tid >> 2;
  const int ak = (tid & 3) * 4;

  #pragma unroll
  for (int kc = 0; kc < 4; kc++) {
    const int kk = kc*16 + ak;
    float4 av = *(const float4*)(xdbl + (size_t)(rowTile + ar) * NPROJ + kk);
    As[kk+0][ar] = av.x; As[kk+1][ar] = av.y;
    As[kk+2][ar] = av.z; As[kk+3][ar] = av.w;
    ushort4 bv = *(const ushort4*)(dtwt + (size_t)(colTile + ar) * DTRANK + kk);
    Bs[kk+0][ar] = bf2f(bv.x); Bs[kk+1][ar] = bf2f(bv.y);
    Bs[kk+2][ar] = bf2f(bv.z); Bs[kk+3][ar] = bf2f(bv.w);
  }
  __syncthreads();

  float acc[4][4] = {};
  #pragma unroll 8
  for (int k = 0; k < DTRANK; k++) {
    float4 a4 = *(const float4*)&As[k][ty*4];
    float4 b4 = *(const float4*)&Bs[k][tx*4];
    float a[4] = {a4.x, a4.y, a4.z, a4.w};
    float b[4] = {b4.x, b4.y, b4.z, b4.w};
    #pragma unroll
    for (int i = 0; i < 4; i++)
      #pragma unroll
      for (int j = 0; j < 4; j++)
        acc[i][j] += a[i] * b[j];
  }

  float4 bb = *(const float4*)(bias + colTile + tx*4);
  const float bvv[4] = {bb.x, bb.y, bb.z, bb.w};
  #pragma unroll
  for (int i = 0; i < 4; i++) {
    const int r = rowTile + ty*4 + i;
    ushort4 o;
    float vv[4];
    #pragma unroll
    for (int j = 0; j < 4; j++) {
      float v = acc[i][j] + bvv[j];
      vv[j] = (v > 20.f) ? v : log1pf(__expf(v));
    }
    o.x = f2bf(vv[0]); o.y = f2bf(vv[1]); o.z = f2bf(vv[2]); o.w = f2bf(vv[3]);
    *(ushort4*)(delta16 + (size_t)r * DINNER + colTile + tx*4) = o;
  }
}

// ---------------------------------------------------------------------------
// Conv (width 4) + SiLU, vectorized — unchanged from R13.
// ---------------------------------------------------------------------------
__global__ __launch_bounds__(256) void conv_silu_k(
    const unsigned short* __restrict__ xcb,
    const float* __restrict__ conv_w,
    const float* __restrict__ conv_b,
    unsigned short* __restrict__ ub)
{
  const int idx = blockIdx.x * 256 + threadIdx.x;   // over NROW*DINNER/4
  const int d4 = (idx & (DINNER/4 - 1)) * 4;
  const int row = idx >> 9;
  const int l = row & (SEQL - 1);

  float4 cb = *(const float4*)(conv_b + d4);
  float acc[4] = {cb.x, cb.y, cb.z, cb.w};
  float4 w0 = *(const float4*)(conv_w + (size_t)(d4+0)*4);
  float4 w1 = *(const float4*)(conv_w + (size_t)(d4+1)*4);
  float4 w2 = *(const float4*)(conv_w + (size_t)(d4+2)*4);
  float4 w3 = *(const float4*)(conv_w + (size_t)(d4+3)*4);
  const float* wp[4] = {(const float*)&w0, (const float*)&w1,
                        (const float*)&w2, (const float*)&w3};
  #pragma unroll
  for (int k = 0; k < DCONV; k++) {
    const int ls = l + k - (DCONV - 1);
    if (ls >= 0) {
      ushort4 xv = *(const ushort4*)(xcb + (size_t)(row + k - (DCONV - 1)) * DINNER + d4);
      acc[0] += bf2f(xv.x) * wp[0][k];
      acc[1] += bf2f(xv.y) * wp[1][k];
      acc[2] += bf2f(xv.z) * wp[2][k];
      acc[3] += bf2f(xv.w) * wp[3][k];
    }
  }
  ushort4 o;
  o.x = f2bf(acc[0] * sigmoidf_(acc[0]));
  o.y = f2bf(acc[1] * sigmoidf_(acc[1]));
  o.z = f2bf(acc[2] * sigmoidf_(acc[2]));
  o.w = f2bf(acc[3] * sigmoidf_(acc[3]));
  *(ushort4*)(ub + (size_t)row * DINNER + d4) = o;
}

// ---------------------------------------------------------------------------
// Scan (proven register-state version) — unchanged.
// ---------------------------------------------------------------------------
__global__ __launch_bounds__(256) void scan_a(
    const unsigned short* __restrict__ delta16,
    const unsigned short* __restrict__ ub,
    const float* __restrict__ xdbl,
    const float* __restrict__ A_log,
    float* __restrict__ S, float* __restrict__ sumd_g)
{
  const int bx = blockIdx.x;
  const int c  = bx & (NCH2-1);
  const int dg = (bx >> 6) & 7;
  const int b  = bx >> 9;
  const int d = dg * 256 + threadIdx.x;
  const size_t row0 = (size_t)(b*SEQL + c*CL2);

  __shared__ float bc_s[CL2][32];
  if (threadIdx.x < 128) {
    const int t = threadIdx.x >> 3;
    const int cc = (threadIdx.x & 7) * 4;
    *(float4*)&bc_s[t][cc] = *(const float4*)&xdbl[(row0 + t)*NPROJ + DTRANK + cc];
  }

  float A2[16];
  #pragma unroll
  for (int i = 0; i < 4; i++) {
    float4 al = *(const float4*)&A_log[(size_t)d*DSTATE + i*4];
    A2[i*4+0] = -__expf(al.x)*LOG2E; A2[i*4+1] = -__expf(al.y)*LOG2E;
    A2[i*4+2] = -__expf(al.z)*LOG2E; A2[i*4+3] = -__expf(al.w)*LOG2E;
  }

  float dlt[CL2], uu[CL2];
  #pragma unroll
  for (int t = 0; t < CL2; t++) {
    dlt[t] = bf2f(delta16[(row0 + t)*DINNER + d]);
    uu[t]  = bf2f(ub[(row0 + t)*DINNER + d]);
  }
  __syncthreads();

  float h[16];
  #pragma unroll
  for (int n = 0; n < 16; n++) h[n] = 0.f;
  float sd = 0.f;

  #pragma unroll
  for (int t = 0; t < CL2; t++) {
    const float du = dlt[t] * uu[t];
    sd += dlt[t];
    f32x4 bq[4];
    #pragma unroll
    for (int i = 0; i < 4; i++) bq[i] = *(const f32x4*)&bc_s[t][i*4];
    #pragma unroll
    for (int n = 0; n < 16; n++) {
      const float a = fexp2(dlt[t] * A2[n]);
      h[n] = a * h[n] + du * bq[n>>2][n&3];
    }
  }

  const size_t base = ((size_t)(b*NCH2 + c) * DINNER + d) * DSTATE;
  #pragma unroll
  for (int i = 0; i < 4; i++) {
    f32x4 hv; hv[0]=h[i*4+0]; hv[1]=h[i*4+1]; hv[2]=h[i*4+2]; hv[3]=h[i*4+3];
    *(f32x4*)&S[base + i*4] = hv;
  }
  sumd_g[(size_t)(b*NCH2 + c) * DINNER + d] = sd;
}

__global__ __launch_bounds__(256) void scan_b(
    const float* __restrict__ S, const float* __restrict__ sumd_g,
    const float* __restrict__ A_log, float* __restrict__ H)
{
  const int idx = blockIdx.x * 256 + threadIdx.x;   // (b,d,n): 65536
  const int n = idx & 15, d = (idx >> 4) & (DINNER-1), b = idx >> 15;
  const float A2 = -__expf(A_log[(size_t)d*DSTATE + n]) * LOG2E;
  float h = 0.f;
  for (int c = 0; c < NCH2; c++) {
    const size_t pos = ((size_t)(b*NCH2 + c) * DINNER + d) * DSTATE + n;
    const float sd = sumd_g[(size_t)(b*NCH2 + c) * DINNER + d];
    H[pos] = h;
    h = fexp2(A2 * sd) * h + S[pos];
  }
}

__global__ __launch_bounds__(256) void scan_c(
    const unsigned short* __restrict__ delta16,
    const unsigned short* __restrict__ ub,
    const unsigned short* __restrict__ zb,
    const float* __restrict__ xdbl,
    const float* __restrict__ A_log,
    const float* __restrict__ Dp,
    const float* __restrict__ H,
    unsigned short* __restrict__ Y)
{
  const int bx = blockIdx.x;
  const int c  = bx & (NCH2-1);
  const int dg = (bx >> 6) & 7;
  const int b  = bx >> 9;
  const int d = dg * 256 + threadIdx.x;
  const size_t row0 = (size_t)(b*SEQL + c*CL2);

  __shared__ float bc_s[CL2][32];
  if (threadIdx.x < 128) {
    const int t = threadIdx.x >> 3;
    const int cc = (threadIdx.x & 7) * 4;
    *(float4*)&bc_s[t][cc] = *(const float4*)&xdbl[(row0 + t)*NPROJ + DTRANK + cc];
  }

  float A2[16];
  #pragma unroll
  for (int i = 0; i < 4; i++) {
    float4 al = *(const float4*)&A_log[(size_t)d*DSTATE + i*4];
    A2[i*4+0] = -__expf(al.x)*LOG2E; A2[i*4+1] = -__expf(al.y)*LOG2E;
    A2[i*4+2] = -__expf(al.z)*LOG2E; A2[i*4+3] = -__expf(al.w)*LOG2E;
  }
  const float Dval = Dp[d];

  float dlt[CL2], uu[CL2], zz[CL2];
  #pragma unroll
  for (int t = 0; t < CL2; t++) {
    dlt[t] = bf2f(delta16[(row0 + t)*DINNER + d]);
    uu[t]  = bf2f(ub[(row0 + t)*DINNER + d]);
    zz[t]  = bf2f(zb[(row0 + t)*DINNER + d]);
  }

  float h[16];
  {
    const size_t hb = ((size_t)(b*NCH2 + c) * DINNER + d) * DSTATE;
    #pragma unroll
    for (int i = 0; i < 4; i++) {
      f32x4 hv = *(const f32x4*)&H[hb + i*4];
      h[i*4+0]=hv[0]; h[i*4+1]=hv[1]; h[i*4+2]=hv[2]; h[i*4+3]=hv[3];
    }
  }
  __syncthreads();

  #pragma unroll
  for (int t = 0; t < CL2; t++) {
    const float du = dlt[t] * uu[t];
    f32x4 bq[4], cq[4];
    #pragma unroll
    for (int i = 0; i < 4; i++) {
      bq[i] = *(const f32x4*)&bc_s[t][i*4];
      cq[i] = *(const f32x4*)&bc_s[t][16 + i*4];
    }
    float y = 0.f;
    #pragma unroll
    for (int n = 0; n < 16; n++) {
      const float a = fexp2(dlt[t] * A2[n]);
      h[n] = a * h[n] + du * bq[n>>2][n&3];
      y += h[n] * cq[n>>2][n&3];
    }
    const float yy = (y + uu[t]*Dval) * (zz[t] * sigmoidf_(zz[t]));
    Y[(row0 + t)*DINNER + d] = f2bf(yy);
  }
}

// ---------------------------------------------------------------------------
extern "C" void kernel_launch(void* const* d_in, const int* in_sizes, int n_in,
                              void* d_out, int out_size, void* d_ws, size_t ws_size,
                              hipStream_t stream) {
  const float* x         = (const float*)d_in[0];
  const float* in_proj_w = (const float*)d_in[2];
  const float* conv_w    = (const float*)d_in[3];
  const float* conv_b    = (const float*)d_in[4];
  const float* x_proj_w  = (const float*)d_in[5];
  const float* dt_proj_w = (const float*)d_in[6];
  const float* dt_proj_b = (const float*)d_in[7];
  const float* A_log     = (const float*)d_in[8];
  const float* Dp        = (const float*)d_in[9];
  const float* out_proj_w= (const float*)d_in[10];
  float* out = (float*)d_out;

  // ws: 256 MiB. Regions (only xcb/yb share [0,8.4M), sequentially dead):
  char* B = (char*)d_ws;
  unsigned short* xcb  = (unsigned short*)B;          // [0, 8.4M) GEMM1 out
  unsigned short* yb   = (unsigned short*)B;          // scan_c out (xcb dead)
  float* xdbl = (float*)(B + (34ll<<20));             // 0.79M (atomic target)
  unsigned short* delta16 = (unsigned short*)(B + (35ll<<20));
  unsigned short* w1t  = (unsigned short*)(B + (44ll<<20));
  unsigned short* w4t  = (unsigned short*)(B + (53ll<<20));
  unsigned short* dtwt = (unsigned short*)(B + (58ll<<20));
  unsigned short* xb   = (unsigned short*)(B + (59ll<<20));
  unsigned short* xpwt = (unsigned short*)(B + (64ll<<20));  // 128x2048 bf16
  float* S2   = (float*)(B + (72ll<<20));
  float* H2   = (float*)(B + (90ll<<20));
  float* sumd = (float*)(B + (108ll<<20));
  unsigned short* zb = (unsigned short*)(B + (110ll<<20));
  unsigned short* ub = (unsigned short*)(B + (119ll<<20));

  dim3 blk(256);

  // zero atomic targets (memset nodes; required every call — re-poisoned)
  hipMemsetAsync(xdbl, 0, (size_t)NROW * NPROJ * 4, stream);
  hipMemsetAsync(out, 0, (size_t)NROW * DIMX * 4, stream);

  // fused prep: cast x, transpose+cast w1/w4/dtw/xpw (+pad)
  prep_k<<<dim3(2048 + 4096 + 2048 + 128 + 192 + 64), blk, 0, stream>>>(
      x, xb, in_proj_w, w1t, out_proj_w, w4t, dt_proj_w, dtwt, x_proj_w, xpwt);

  // GEMM1 (MFMA, BK4 superstep): [xcb|zb] = x @ in_proj_w, bf16 out
  gemm1_bf2_k<<<dim3((2*DINNER)/128, NROW/128), blk, 0, stream>>>(
      xb, DIMX, w1t, DIMX, xcb, zb, DINNER, DINNER, DIMX);

  // conv + silu -> ub bf16 (vectorized)
  conv_silu_k<<<(NROW*DINNER/4)/256, blk, 0, stream>>>(xcb, conv_w, conv_b, ub);

  // GEMM2 (MFMA, split-K 16, atomic, BK2) -> xdbl
  gemm2_k<<<dim3(NROW/128, G2SPLIT), blk, 0, stream>>>(ub, xpwt, xdbl);

  // GEMM3 (VALU): delta16 = softplus(dtr @ dtwt^T + b), bf16
  gemm3_k<<<dim3(DINNER/64, NROW/64), blk, 0, stream>>>(
      xdbl, dtwt, dt_proj_b, delta16);

  // chunked selective scan
  scan_a<<<dim3(BSZ*NCH2*8), blk, 0, stream>>>(delta16, ub, xdbl, A_log, S2, sumd);
  scan_b<<<dim3((BSZ*DINNER*DSTATE)/256), blk, 0, stream>>>(S2, sumd, A_log, H2);
  scan_c<<<dim3(BSZ*NCH2*8), blk, 0, stream>>>(
      delta16, ub, zb, xdbl, A_log, Dp, H2, yb);

  // GEMM4 (MFMA, split-K 4, atomic, BK4 superstep) -> out
  gemm4_k<<<dim3(DIMX/128, NROW/128, G4SPLIT), blk, 0, stream>>>(yb, w4t, out);
}

// Round 16
// 259.540 us; speedup vs baseline: 1.3923x; 1.0051x over previous
//
#include <hip/hip_runtime.h>
#include <hip/hip_bf16.h>

#define DIMX 1024
#define DSTATE 16
#define DCONV 4
#define DINNER 2048
#define DTRANK 64
#define BSZ 2
#define SEQL 1024
#define NROW (BSZ*SEQL)              // 2048
#define NPROJ (DTRANK + 2*DSTATE)    // 96
#define NCH2 64                      // scan chunks
#define CL2 16                       // chunk length (SEQL/NCH2)
#define G2SPLIT 16                   // GEMM2 split-K factor
#define G2KLEN (DINNER / G2SPLIT)    // 128
#define G4SPLIT 4                    // GEMM4 split-K factor

typedef __bf16 bf16x8 __attribute__((ext_vector_type(8)));
typedef float f32x4 __attribute__((ext_vector_type(4)));
typedef unsigned short ushort8_t __attribute__((ext_vector_type(8)));

#define LOG2E 1.44269504088896340736f

__device__ __forceinline__ float sigmoidf_(float x){ return 1.0f/(1.0f+__expf(-x)); }
__device__ __forceinline__ float fexp2(float x){ return __builtin_amdgcn_exp2f(x); }
__device__ __forceinline__ unsigned short f2bf(float f){
  union { float f; unsigned int i; } c; c.f = f;
  unsigned int r = (c.i + 0x7FFFu + ((c.i >> 16) & 1u)) >> 16;
  return (unsigned short)r;
}
__device__ __forceinline__ float bf2f(unsigned short u){
  union { unsigned int i; float f; } c; c.i = ((unsigned int)u) << 16; return c.f;
}

// async global->LDS, 16 B per lane; LDS dest = base + lane*16 (wave-uniform base)
__device__ __forceinline__ void gload16(const void* g, void* l){
  __builtin_amdgcn_global_load_lds(
      (const __attribute__((address_space(1))) unsigned int*)g,
      (__attribute__((address_space(3))) unsigned int*)l, 16, 0, 0);
}

// ---------------------------------------------------------------------------
// Fused prep (grid-sectioned) — R12-proven.
// ---------------------------------------------------------------------------
__global__ __launch_bounds__(256) void prep_k(
    const float* __restrict__ x, unsigned short* __restrict__ xb,
    const float* __restrict__ w1, unsigned short* __restrict__ w1t,
    const float* __restrict__ w4, unsigned short* __restrict__ w4t,
    const float* __restrict__ dtw, unsigned short* __restrict__ dtwt,
    const float* __restrict__ xpw, unsigned short* __restrict__ xpwt)
{
  __shared__ unsigned short T[32][33];
  int blk = blockIdx.x;
  if (blk < 2048) {                      // cast
    const int i = blk*256 + threadIdx.x;
    float4 v = *(const float4*)(x + (size_t)i * 4);
    ushort4 o;
    o.x = f2bf(v.x); o.y = f2bf(v.y); o.z = f2bf(v.z); o.w = f2bf(v.w);
    *(ushort4*)(xb + (size_t)i * 4) = o;
    return;
  }
  blk -= 2048;
  if (blk >= 6464) {                     // zero-pad xpwt rows 96..127
    blk -= 6464;
    const int i = blk*256 + threadIdx.x; // 16384 ushort4 total
    *(ushort4*)(xpwt + (size_t)96*DINNER + (size_t)i*4) = make_ushort4(0,0,0,0);
    return;
  }
  const float* w; unsigned short* wt; int K, N, nT, kT;
  if (blk < 4096) {                      // w1t: N=4096,K=1024 grid 128x32
    w = w1; wt = w1t; K = 1024; N = 4096;
    nT = (blk & 127) * 32; kT = (blk >> 7) * 32;
  } else if (blk < 6144) {               // w4t: N=1024,K=2048 grid 32x64
    blk -= 4096;
    w = w4; wt = w4t; K = 2048; N = 1024;
    nT = (blk & 31) * 32; kT = (blk >> 5) * 32;
  } else if (blk < 6272) {               // dtwt: N=2048,K=64 grid 64x2
    blk -= 6144;
    w = dtw; wt = dtwt; K = 64; N = 2048;
    nT = (blk & 63) * 32; kT = (blk >> 6) * 32;
  } else {                               // xpwt: N=96,K=2048 grid 3x64
    blk -= 6272;
    w = xpw; wt = xpwt; K = 2048; N = 96;
    nT = (blk % 3) * 32; kT = (blk / 3) * 32;
  }
  const int tx = threadIdx.x & 31, ty = threadIdx.x >> 5;
  #pragma unroll
  for (int i = 0; i < 4; i++)
    T[tx][ty + i*8] = f2bf(w[(size_t)(kT + ty + i*8) * N + nT + tx]);
  __syncthreads();
  #pragma unroll
  for (int i = 0; i < 4; i++)
    wt[(size_t)(nT + ty + i*8) * K + kT + tx] = T[ty + i*8][tx];
}

// ---------------------------------------------------------------------------
// GEMM1 (bf16 dual-output, BK4 superstep) — R14-proven.
// ---------------------------------------------------------------------------
__global__ __launch_bounds__(256) void gemm1_bf2_k(
    const unsigned short* __restrict__ A, int lda,
    const unsigned short* __restrict__ BT, int ldb,
    unsigned short* __restrict__ X0, unsigned short* __restrict__ X1,
    int splitN, int ldc, int K)
{
  constexpr int BM = 128, BN = 128, BK = 32, NB = 4;
  __shared__ unsigned short As[NB][BM*BK];
  __shared__ unsigned short Bs[NB][BN*BK];

  const int tid = threadIdx.x;
  const int w = tid >> 6, lane = tid & 63;
  const int quad = lane >> 4, lrow = lane & 15;
  const int mOff = (w & 1) * 64, nOff = (w >> 1) * 64;
  const int rowTile = blockIdx.y * BM, colTile = blockIdx.x * BN;

  f32x4 acc[4][4] = {};

  const int srow = lane >> 2;
  const int sbyte = (lane & 3) * 16;

  for (int k0 = 0; k0 < K; k0 += NB*BK) {
    #pragma unroll
    for (int hh = 0; hh < NB; hh++) {
      const int kk = k0 + hh*BK;
      const char* aSrc = (const char*)(A  + (size_t)(rowTile + w*32 + srow)*lda + kk) + sbyte;
      const char* bSrc = (const char*)(BT + (size_t)(colTile + w*32 + srow)*ldb + kk) + sbyte;
      gload16(aSrc,                    &As[hh][(w*32     )*32]);
      gload16(aSrc + 16*(size_t)lda*2, &As[hh][(w*32 + 16)*32]);
      gload16(bSrc,                    &Bs[hh][(w*32     )*32]);
      gload16(bSrc + 16*(size_t)ldb*2, &Bs[hh][(w*32 + 16)*32]);
    }
    __syncthreads();

    #pragma unroll
    for (int hh = 0; hh < NB; hh++) {
      bf16x8 af[4], bfr[4];
      #pragma unroll
      for (int mi = 0; mi < 4; mi++)
        af[mi] = *(const bf16x8*)&As[hh][(mOff + mi*16 + lrow)*32 + quad*8];
      #pragma unroll
      for (int ni = 0; ni < 4; ni++)
        bfr[ni] = *(const bf16x8*)&Bs[hh][(nOff + ni*16 + lrow)*32 + quad*8];
      #pragma unroll
      for (int mi = 0; mi < 4; mi++)
        #pragma unroll
        for (int ni = 0; ni < 4; ni++)
          acc[mi][ni] = __builtin_amdgcn_mfma_f32_16x16x32_bf16(
              af[mi], bfr[ni], acc[mi][ni], 0, 0, 0);
    }
    __syncthreads();
  }

  #pragma unroll
  for (int mi = 0; mi < 4; mi++) {
    #pragma unroll
    for (int ni = 0; ni < 4; ni++) {
      const int row = rowTile + mOff + mi*16 + quad*4;
      const int col = colTile + nOff + ni*16 + lrow;
      unsigned short* Cb = (col < splitN) ? X0 : X1;
      const int cc = (col < splitN) ? col : col - splitN;
      #pragma unroll
      for (int r = 0; r < 4; r++)
        Cb[(size_t)(row + r) * ldc + cc] = f2bf(acc[mi][ni][r]);
    }
  }
}

// ---------------------------------------------------------------------------
// GEMM2 (MFMA, split-K 16, atomic epilogue, BK2 superstep) — R14-proven.
// ---------------------------------------------------------------------------
__global__ __launch_bounds__(256) void gemm2_k(
    const unsigned short* __restrict__ A,    // ub: NROW x DINNER bf16
    const unsigned short* __restrict__ BT,   // xpwt: 128 x DINNER bf16
    float* __restrict__ xdbl)                // NROW x 96 f32 (atomic)
{
  constexpr int BM = 128, BK = 32;
  __shared__ unsigned short As[2][BM*BK];
  __shared__ unsigned short Bs[2][128*BK];

  const int tid = threadIdx.x;
  const int w = tid >> 6, lane = tid & 63;
  const int quad = lane >> 4, lrow = lane & 15;
  const int mOff = (w & 1) * 64, nOff = (w >> 1) * 64;
  const int rowTile = blockIdx.x * BM;
  const int kBeg = blockIdx.y * G2KLEN;

  f32x4 acc[4][4] = {};

  const int srow = lane >> 2;
  const int sbyte = (lane & 3) * 16;

  for (int k0 = kBeg; k0 < kBeg + G2KLEN; k0 += 2*BK) {
    #pragma unroll
    for (int hh = 0; hh < 2; hh++) {
      const int kk = k0 + hh*BK;
      const char* aSrc = (const char*)(A  + (size_t)(rowTile + w*32 + srow)*DINNER + kk) + sbyte;
      const char* bSrc = (const char*)(BT + (size_t)(w*32 + srow)*DINNER + kk) + sbyte;
      gload16(aSrc,                       &As[hh][(w*32     )*32]);
      gload16(aSrc + 16*(size_t)DINNER*2, &As[hh][(w*32 + 16)*32]);
      gload16(bSrc,                       &Bs[hh][(w*32     )*32]);
      gload16(bSrc + 16*(size_t)DINNER*2, &Bs[hh][(w*32 + 16)*32]);
    }
    __syncthreads();

    #pragma unroll
    for (int hh = 0; hh < 2; hh++) {
      bf16x8 af[4], bfr[4];
      #pragma unroll
      for (int mi = 0; mi < 4; mi++)
        af[mi] = *(const bf16x8*)&As[hh][(mOff + mi*16 + lrow)*32 + quad*8];
      #pragma unroll
      for (int ni = 0; ni < 4; ni++)
        bfr[ni] = *(const bf16x8*)&Bs[hh][(nOff + ni*16 + lrow)*32 + quad*8];
      #pragma unroll
      for (int mi = 0; mi < 4; mi++)
        #pragma unroll
        for (int ni = 0; ni < 4; ni++)
          acc[mi][ni] = __builtin_amdgcn_mfma_f32_16x16x32_bf16(
              af[mi], bfr[ni], acc[mi][ni], 0, 0, 0);
    }
    __syncthreads();
  }

  #pragma unroll
  for (int mi = 0; mi < 4; mi++) {
    #pragma unroll
    for (int ni = 0; ni < 4; ni++) {
      const int row = rowTile + mOff + mi*16 + quad*4;
      const int col = nOff + ni*16 + lrow;
      if (col >= NPROJ) continue;
      #pragma unroll
      for (int r = 0; r < 4; r++)
        atomicAdd(xdbl + (size_t)(row + r) * NPROJ + col, acc[mi][ni][r]);
    }
  }
}

// ---------------------------------------------------------------------------
// GEMM4 (MFMA, split-K 4, atomic epilogue, BK4 superstep) — R14-proven.
// ---------------------------------------------------------------------------
__global__ __launch_bounds__(256) void gemm4_k(
    const unsigned short* __restrict__ A,   // yb: NROW x DINNER bf16
    const unsigned short* __restrict__ BT,  // w4t: DIMX x DINNER bf16
    float* __restrict__ outp)               // NROW x DIMX f32 (atomic)
{
  constexpr int BM = 128, BN = 128, BK = 32, NB = 4;
  constexpr int KCH = DINNER / G4SPLIT;
  __shared__ unsigned short As[NB][BM*BK];
  __shared__ unsigned short Bs[NB][BN*BK];

  const int tid = threadIdx.x;
  const int w = tid >> 6, lane = tid & 63;
  const int quad = lane >> 4, lrow = lane & 15;
  const int mOff = (w & 1) * 64, nOff = (w >> 1) * 64;
  const int rowTile = blockIdx.y * BM, colTile = blockIdx.x * BN;
  const int kBeg = blockIdx.z * KCH;

  f32x4 acc[4][4] = {};

  const int srow = lane >> 2;
  const int sbyte = (lane & 3) * 16;

  for (int k0 = kBeg; k0 < kBeg + KCH; k0 += NB*BK) {
    #pragma unroll
    for (int hh = 0; hh < NB; hh++) {
      const int kk = k0 + hh*BK;
      const char* aSrc = (const char*)(A  + (size_t)(rowTile + w*32 + srow)*DINNER + kk) + sbyte;
      const char* bSrc = (const char*)(BT + (size_t)(colTile + w*32 + srow)*DINNER + kk) + sbyte;
      gload16(aSrc,                       &As[hh][(w*32     )*32]);
      gload16(aSrc + 16*(size_t)DINNER*2, &As[hh][(w*32 + 16)*32]);
      gload16(bSrc,                       &Bs[hh][(w*32     )*32]);
      gload16(bSrc + 16*(size_t)DINNER*2, &Bs[hh][(w*32 + 16)*32]);
    }
    __syncthreads();

    #pragma unroll
    for (int hh = 0; hh < NB; hh++) {
      bf16x8 af[4], bfr[4];
      #pragma unroll
      for (int mi = 0; mi < 4; mi++)
        af[mi] = *(const bf16x8*)&As[hh][(mOff + mi*16 + lrow)*32 + quad*8];
      #pragma unroll
      for (int ni = 0; ni < 4; ni++)
        bfr[ni] = *(const bf16x8*)&Bs[hh][(nOff + ni*16 + lrow)*32 + quad*8];
      #pragma unroll
      for (int mi = 0; mi < 4; mi++)
        #pragma unroll
        for (int ni = 0; ni < 4; ni++)
          acc[mi][ni] = __builtin_amdgcn_mfma_f32_16x16x32_bf16(
              af[mi], bfr[ni], acc[mi][ni], 0, 0, 0);
    }
    __syncthreads();
  }

  #pragma unroll
  for (int mi = 0; mi < 4; mi++) {
    #pragma unroll
    for (int ni = 0; ni < 4; ni++) {
      const int row = rowTile + mOff + mi*16 + quad*4;
      const int col = colTile + nOff + ni*16 + lrow;
      #pragma unroll
      for (int r = 0; r < 4; r++)
        atomicAdd(outp + (size_t)(row + r) * DIMX + col, acc[mi][ni][r]);
    }
  }
}

// ---------------------------------------------------------------------------
// GEMM3 (VALU) — R10-proven.
// ---------------------------------------------------------------------------
__global__ __launch_bounds__(256) void gemm3_k(
    const float* __restrict__ xdbl,
    const unsigned short* __restrict__ dtwt,
    const float* __restrict__ bias,
    unsigned short* __restrict__ delta16)
{
  __shared__ float As[64][68];
  __shared__ float Bs[64][68];
  const int tid = threadIdx.x;
  const int tx = tid & 15, ty = tid >> 4;
  const int rowTile = blockIdx.y * 64;
  const int colTile = blockIdx.x * 64;

  const int ar = tid >> 2;
  const int ak = (tid & 3) * 4;

  #pragma unroll
  for (int kc = 0; kc < 4; kc++) {
    const int kk = kc*16 + ak;
    float4 av = *(const float4*)(xdbl + (size_t)(rowTile + ar) * NPROJ + kk);
    As[kk+0][ar] = av.x; As[kk+1][ar] = av.y;
    As[kk+2][ar] = av.z; As[kk+3][ar] = av.w;
    ushort4 bv = *(const ushort4*)(dtwt + (size_t)(colTile + ar) * DTRANK + kk);
    Bs[kk+0][ar] = bf2f(bv.x); Bs[kk+1][ar] = bf2f(bv.y);
    Bs[kk+2][ar] = bf2f(bv.z); Bs[kk+3][ar] = bf2f(bv.w);
  }
  __syncthreads();

  float acc[4][4] = {};
  #pragma unroll 8
  for (int k = 0; k < DTRANK; k++) {
    float4 a4 = *(const float4*)&As[k][ty*4];
    float4 b4 = *(const float4*)&Bs[k][tx*4];
    float a[4] = {a4.x, a4.y, a4.z, a4.w};
    float b[4] = {b4.x, b4.y, b4.z, b4.w};
    #pragma unroll
    for (int i = 0; i < 4; i++)
      #pragma unroll
      for (int j = 0; j < 4; j++)
        acc[i][j] += a[i] * b[j];
  }

  float4 bb = *(const float4*)(bias + colTile + tx*4);
  const float bvv[4] = {bb.x, bb.y, bb.z, bb.w};
  #pragma unroll
  for (int i = 0; i < 4; i++) {
    const int r = rowTile + ty*4 + i;
    ushort4 o;
    float vv[4];
    #pragma unroll
    for (int j = 0; j < 4; j++) {
      float v = acc[i][j] + bvv[j];
      vv[j] = (v > 20.f) ? v : log1pf(__expf(v));
    }
    o.x = f2bf(vv[0]); o.y = f2bf(vv[1]); o.z = f2bf(vv[2]); o.w = f2bf(vv[3]);
    *(ushort4*)(delta16 + (size_t)r * DINNER + colTile + tx*4) = o;
  }
}

// ---------------------------------------------------------------------------
// Conv (width 4) + SiLU, vectorized — R13-proven.
// ---------------------------------------------------------------------------
__global__ __launch_bounds__(256) void conv_silu_k(
    const unsigned short* __restrict__ xcb,
    const float* __restrict__ conv_w,
    const float* __restrict__ conv_b,
    unsigned short* __restrict__ ub)
{
  const int idx = blockIdx.x * 256 + threadIdx.x;   // over NROW*DINNER/4
  const int d4 = (idx & (DINNER/4 - 1)) * 4;
  const int row = idx >> 9;
  const int l = row & (SEQL - 1);

  float4 cb = *(const float4*)(conv_b + d4);
  float acc[4] = {cb.x, cb.y, cb.z, cb.w};
  float4 w0 = *(const float4*)(conv_w + (size_t)(d4+0)*4);
  float4 w1 = *(const float4*)(conv_w + (size_t)(d4+1)*4);
  float4 w2 = *(const float4*)(conv_w + (size_t)(d4+2)*4);
  float4 w3 = *(const float4*)(conv_w + (size_t)(d4+3)*4);
  const float* wp[4] = {(const float*)&w0, (const float*)&w1,
                        (const float*)&w2, (const float*)&w3};
  #pragma unroll
  for (int k = 0; k < DCONV; k++) {
    const int ls = l + k - (DCONV - 1);
    if (ls >= 0) {
      ushort4 xv = *(const ushort4*)(xcb + (size_t)(row + k - (DCONV - 1)) * DINNER + d4);
      acc[0] += bf2f(xv.x) * wp[0][k];
      acc[1] += bf2f(xv.y) * wp[1][k];
      acc[2] += bf2f(xv.z) * wp[2][k];
      acc[3] += bf2f(xv.w) * wp[3][k];
    }
  }
  ushort4 o;
  o.x = f2bf(acc[0] * sigmoidf_(acc[0]));
  o.y = f2bf(acc[1] * sigmoidf_(acc[1]));
  o.z = f2bf(acc[2] * sigmoidf_(acc[2]));
  o.w = f2bf(acc[3] * sigmoidf_(acc[3]));
  *(ushort4*)(ub + (size_t)row * DINNER + d4) = o;
}

// ---------------------------------------------------------------------------
// Scan (proven 3-kernel register-state version) — R11..R14-proven.
// ---------------------------------------------------------------------------
__global__ __launch_bounds__(256) void scan_a(
    const unsigned short* __restrict__ delta16,
    const unsigned short* __restrict__ ub,
    const float* __restrict__ xdbl,
    const float* __restrict__ A_log,
    float* __restrict__ S, float* __restrict__ sumd_g)
{
  const int bx = blockIdx.x;
  const int c  = bx & (NCH2-1);
  const int dg = (bx >> 6) & 7;
  const int b  = bx >> 9;
  const int d = dg * 256 + threadIdx.x;
  const size_t row0 = (size_t)(b*SEQL + c*CL2);

  __shared__ float bc_s[CL2][32];
  if (threadIdx.x < 128) {
    const int t = threadIdx.x >> 3;
    const int cc = (threadIdx.x & 7) * 4;
    *(float4*)&bc_s[t][cc] = *(const float4*)&xdbl[(row0 + t)*NPROJ + DTRANK + cc];
  }

  float A2[16];
  #pragma unroll
  for (int i = 0; i < 4; i++) {
    float4 al = *(const float4*)&A_log[(size_t)d*DSTATE + i*4];
    A2[i*4+0] = -__expf(al.x)*LOG2E; A2[i*4+1] = -__expf(al.y)*LOG2E;
    A2[i*4+2] = -__expf(al.z)*LOG2E; A2[i*4+3] = -__expf(al.w)*LOG2E;
  }

  float dlt[CL2], uu[CL2];
  #pragma unroll
  for (int t = 0; t < CL2; t++) {
    dlt[t] = bf2f(delta16[(row0 + t)*DINNER + d]);
    uu[t]  = bf2f(ub[(row0 + t)*DINNER + d]);
  }
  __syncthreads();

  float h[16];
  #pragma unroll
  for (int n = 0; n < 16; n++) h[n] = 0.f;
  float sd = 0.f;

  #pragma unroll
  for (int t = 0; t < CL2; t++) {
    const float du = dlt[t] * uu[t];
    sd += dlt[t];
    f32x4 bq[4];
    #pragma unroll
    for (int i = 0; i < 4; i++) bq[i] = *(const f32x4*)&bc_s[t][i*4];
    #pragma unroll
    for (int n = 0; n < 16; n++) {
      const float a = fexp2(dlt[t] * A2[n]);
      h[n] = a * h[n] + du * bq[n>>2][n&3];
    }
  }

  const size_t base = ((size_t)(b*NCH2 + c) * DINNER + d) * DSTATE;
  #pragma unroll
  for (int i = 0; i < 4; i++) {
    f32x4 hv; hv[0]=h[i*4+0]; hv[1]=h[i*4+1]; hv[2]=h[i*4+2]; hv[3]=h[i*4+3];
    *(f32x4*)&S[base + i*4] = hv;
  }
  sumd_g[(size_t)(b*NCH2 + c) * DINNER + d] = sd;
}

__global__ __launch_bounds__(256) void scan_b(
    const float* __restrict__ S, const float* __restrict__ sumd_g,
    const float* __restrict__ A_log, float* __restrict__ H)
{
  const int idx = blockIdx.x * 256 + threadIdx.x;   // (b,d,n): 65536
  const int n = idx & 15, d = (idx >> 4) & (DINNER-1), b = idx >> 15;
  const float A2 = -__expf(A_log[(size_t)d*DSTATE + n]) * LOG2E;
  float h = 0.f;
  for (int c = 0; c < NCH2; c++) {
    const size_t pos = ((size_t)(b*NCH2 + c) * DINNER + d) * DSTATE + n;
    const float sd = sumd_g[(size_t)(b*NCH2 + c) * DINNER + d];
    H[pos] = h;
    h = fexp2(A2 * sd) * h + S[pos];
  }
}

__global__ __launch_bounds__(256) void scan_c(
    const unsigned short* __restrict__ delta16,
    const unsigned short* __restrict__ ub,
    const unsigned short* __restrict__ zb,
    const float* __restrict__ xdbl,
    const float* __restrict__ A_log,
    const float* __restrict__ Dp,
    const float* __restrict__ H,
    unsigned short* __restrict__ Y)
{
  const int bx = blockIdx.x;
  const int c  = bx & (NCH2-1);
  const int dg = (bx >> 6) & 7;
  const int b  = bx >> 9;
  const int d = dg * 256 + threadIdx.x;
  const size_t row0 = (size_t)(b*SEQL + c*CL2);

  __shared__ float bc_s[CL2][32];
  if (threadIdx.x < 128) {
    const int t = threadIdx.x >> 3;
    const int cc = (threadIdx.x & 7) * 4;
    *(float4*)&bc_s[t][cc] = *(const float4*)&xdbl[(row0 + t)*NPROJ + DTRANK + cc];
  }

  float A2[16];
  #pragma unroll
  for (int i = 0; i < 4; i++) {
    float4 al = *(const float4*)&A_log[(size_t)d*DSTATE + i*4];
    A2[i*4+0] = -__expf(al.x)*LOG2E; A2[i*4+1] = -__expf(al.y)*LOG2E;
    A2[i*4+2] = -__expf(al.z)*LOG2E; A2[i*4+3] = -__expf(al.w)*LOG2E;
  }
  const float Dval = Dp[d];

  float dlt[CL2], uu[CL2], zz[CL2];
  #pragma unroll
  for (int t = 0; t < CL2; t++) {
    dlt[t] = bf2f(delta16[(row0 + t)*DINNER + d]);
    uu[t]  = bf2f(ub[(row0 + t)*DINNER + d]);
    zz[t]  = bf2f(zb[(row0 + t)*DINNER + d]);
  }

  float h[16];
  {
    const size_t hb = ((size_t)(b*NCH2 + c) * DINNER + d) * DSTATE;
    #pragma unroll
    for (int i = 0; i < 4; i++) {
      f32x4 hv = *(const f32x4*)&H[hb + i*4];
      h[i*4+0]=hv[0]; h[i*4+1]=hv[1]; h[i*4+2]=hv[2]; h[i*4+3]=hv[3];
    }
  }
  __syncthreads();

  #pragma unroll
  for (int t = 0; t < CL2; t++) {
    const float du = dlt[t] * uu[t];
    f32x4 bq[4], cq[4];
    #pragma unroll
    for (int i = 0; i < 4; i++) {
      bq[i] = *(const f32x4*)&bc_s[t][i*4];
      cq[i] = *(const f32x4*)&bc_s[t][16 + i*4];
    }
    float y = 0.f;
    #pragma unroll
    for (int n = 0; n < 16; n++) {
      const float a = fexp2(dlt[t] * A2[n]);
      h[n] = a * h[n] + du * bq[n>>2][n&3];
      y += h[n] * cq[n>>2][n&3];
    }
    const float yy = (y + uu[t]*Dval) * (zz[t] * sigmoidf_(zz[t]));
    Y[(row0 + t)*DINNER + d] = f2bf(yy);
  }
}

// ---------------------------------------------------------------------------
extern "C" void kernel_launch(void* const* d_in, const int* in_sizes, int n_in,
                              void* d_out, int out_size, void* d_ws, size_t ws_size,
                              hipStream_t stream) {
  const float* x         = (const float*)d_in[0];
  const float* in_proj_w = (const float*)d_in[2];
  const float* conv_w    = (const float*)d_in[3];
  const float* conv_b    = (const float*)d_in[4];
  const float* x_proj_w  = (const float*)d_in[5];
  const float* dt_proj_w = (const float*)d_in[6];
  const float* dt_proj_b = (const float*)d_in[7];
  const float* A_log     = (const float*)d_in[8];
  const float* Dp        = (const float*)d_in[9];
  const float* out_proj_w= (const float*)d_in[10];
  float* out = (float*)d_out;

  // ws: 256 MiB. Regions (only xcb/yb share [0,8.4M), sequentially dead):
  char* B = (char*)d_ws;
  unsigned short* xcb  = (unsigned short*)B;          // [0, 8.4M) GEMM1 out
  unsigned short* yb   = (unsigned short*)B;          // scan_c out (xcb dead)
  float* xdbl = (float*)(B + (34ll<<20));             // 0.79M (atomic target)
  unsigned short* delta16 = (unsigned short*)(B + (35ll<<20));
  unsigned short* w1t  = (unsigned short*)(B + (44ll<<20));
  unsigned short* w4t  = (unsigned short*)(B + (53ll<<20));
  unsigned short* dtwt = (unsigned short*)(B + (58ll<<20));
  unsigned short* xb   = (unsigned short*)(B + (59ll<<20));
  unsigned short* xpwt = (unsigned short*)(B + (64ll<<20));  // 128x2048 bf16
  float* S2   = (float*)(B + (72ll<<20));
  float* H2   = (float*)(B + (90ll<<20));
  float* sumd = (float*)(B + (108ll<<20));
  unsigned short* zb = (unsigned short*)(B + (110ll<<20));
  unsigned short* ub = (unsigned short*)(B + (119ll<<20));

  dim3 blk(256);

  // zero atomic targets (memset nodes; required every call — re-poisoned)
  hipMemsetAsync(xdbl, 0, (size_t)NROW * NPROJ * 4, stream);
  hipMemsetAsync(out, 0, (size_t)NROW * DIMX * 4, stream);

  // fused prep: cast x, transpose+cast w1/w4/dtw/xpw (+pad)
  prep_k<<<dim3(2048 + 4096 + 2048 + 128 + 192 + 64), blk, 0, stream>>>(
      x, xb, in_proj_w, w1t, out_proj_w, w4t, dt_proj_w, dtwt, x_proj_w, xpwt);

  // GEMM1 (MFMA, BK4 superstep): [xcb|zb] = x @ in_proj_w, bf16 out
  gemm1_bf2_k<<<dim3((2*DINNER)/128, NROW/128), blk, 0, stream>>>(
      xb, DIMX, w1t, DIMX, xcb, zb, DINNER, DINNER, DIMX);

  // conv + silu -> ub bf16 (vectorized)
  conv_silu_k<<<(NROW*DINNER/4)/256, blk, 0, stream>>>(xcb, conv_w, conv_b, ub);

  // GEMM2 (MFMA, split-K 16, atomic, BK2) -> xdbl
  gemm2_k<<<dim3(NROW/128, G2SPLIT), blk, 0, stream>>>(ub, xpwt, xdbl);

  // GEMM3 (VALU): delta16 = softplus(dtr @ dtwt^T + b), bf16
  gemm3_k<<<dim3(DINNER/64, NROW/64), blk, 0, stream>>>(
      xdbl, dtwt, dt_proj_b, delta16);

  // chunked selective scan (proven 3-kernel version)
  scan_a<<<dim3(BSZ*NCH2*8), blk, 0, stream>>>(delta16, ub, xdbl, A_log, S2, sumd);
  scan_b<<<dim3((BSZ*DINNER*DSTATE)/256), blk, 0, stream>>>(S2, sumd, A_log, H2);
  scan_c<<<dim3(BSZ*NCH2*8), blk, 0, stream>>>(
      delta16, ub, zb, xdbl, A_log, Dp, H2, yb);

  // GEMM4 (MFMA, split-K 4, atomic, BK4 superstep) -> out
  gemm4_k<<<dim3(DIMX/128, NROW/128, G4SPLIT), blk, 0, stream>>>(yb, w4t, out);
}